// Round 3
// baseline (1125.134 us; speedup 1.0000x reference)
//
#include <hip/hip_runtime.h>
#include <math.h>

// Problem dims
constexpr int Bb   = 4;
constexpr int Cch  = 512;
constexpr int HW   = 961;      // 31*31
constexpr int THW  = 3844;     // 4*961
constexpr int NCMP = 126;      // 3*42 compare channels
constexpr int NPIX = Bb * Cch * THW;  // 7,872,512
constexpr int Hp = 31, Wp = 31, H0c = 63, W0c = 63;
constexpr int VP = 1024;       // padded keys/frame for Vbf
#define BN_EPS 1e-5f

typedef __attribute__((ext_vector_type(4))) float floatx4;
typedef __attribute__((ext_vector_type(8))) __bf16 bf16x8;
typedef __attribute__((ext_vector_type(8))) unsigned short ushort8;
typedef __attribute__((ext_vector_type(4))) unsigned short ushort4v;

static __device__ __forceinline__ unsigned short f2bf(float x) {
    unsigned int u = __builtin_bit_cast(unsigned int, x);
    u += 0x7fff + ((u >> 16) & 1);   // RNE
    return (unsigned short)(u >> 16);
}
static __device__ __forceinline__ float bf2f(unsigned short u) {
    return __builtin_bit_cast(float, ((unsigned int)u) << 16);
}

// ---------------- K0: pack weights to bf16 (+ zero Vbf key pad) ----------------
__global__ __launch_bounds__(256) void k_prep_w(
    const float* __restrict__ Wcat, const float* __restrict__ Wsub,
    const float* __restrict__ Wmul, const float* __restrict__ Wagg,
    unsigned short* __restrict__ Wpk, unsigned short* __restrict__ Wab,
    unsigned short* __restrict__ Vbf) {
    int idx = blockIdx.x * 256 + threadIdx.x;
    if (idx < 24576) {                       // cat
        int row = idx >> 9, k = idx & 511;
        Wpk[idx] = (row < 42) ? f2bf(Wcat[row * 512 + k]) : 0;
    } else if (idx < 36864) {                // sub
        int i = idx - 24576;
        int row = i >> 8, k = i & 255;
        Wpk[idx] = (row < 42) ? f2bf(Wsub[row * 256 + k]) : 0;
    } else if (idx < 49152) {                // mul
        int i = idx - 36864;
        int row = i >> 8, k = i & 255;
        Wpk[idx] = (row < 42) ? f2bf(Wmul[row * 256 + k]) : 0;
    } else if (idx < 49152 + 524288) {       // agg
        int i = idx - 49152;
        int row = i >> 10, k = i & 1023;
        Wab[i] = (k < 1016) ? f2bf(Wagg[(size_t)row * 1016 + k]) : 0;
    } else if (idx < 573440 + 258048) {      // Vbf pad keys [961,1024) := 0
        int i = idx - 573440;
        int row = i / 63, k = i - row * 63;  // row < 4096 = 16bm*256ch
        Vbf[(size_t)row * VP + 961 + k] = 0;
    }
}

// ---------------- K1: maxpool (1,3,3)/(1,2,2) ----------------
__global__ __launch_bounds__(256) void k_pool(const float* __restrict__ x,
                                              float* __restrict__ xp) {
    int idx = blockIdx.x * 256 + threadIdx.x;
    if (idx >= NPIX) return;
    int w = idx % Wp;
    int h = (idx / Wp) % Hp;
    int bct = idx / HW;
    const float* src = x + (size_t)bct * (H0c * W0c) + (2 * h) * W0c + 2 * w;
    float m = -INFINITY;
    #pragma unroll
    for (int i = 0; i < 3; ++i) {
        m = fmaxf(m, src[i * W0c + 0]);
        m = fmaxf(m, src[i * W0c + 1]);
        m = fmaxf(m, src[i * W0c + 2]);
    }
    xp[idx] = m;
}

// ---------------- K1b: transpose xp -> channel-last bf16 hi/lo split ----------------
// xp [b][512][THW] fp32  ->  Xh/Xl [b][THW][512] bf16 (hi + residual-lo)
__global__ __launch_bounds__(256) void k_xpose(const float* __restrict__ xp,
                                               unsigned short* __restrict__ Xh,
                                               unsigned short* __restrict__ Xl) {
    __shared__ float T[64][65];   // +1 pad: conflict-free column reads
    const int p0 = blockIdx.x * 64;
    const int c0 = blockIdx.y * 64;
    const int b  = blockIdx.z;
    const int tid = threadIdx.x;
    // load 64c x 64px, float4 along px (coalesced)
    {
        int px4 = (tid & 15) * 4;
        int cb = tid >> 4;          // 0..15
        #pragma unroll
        for (int i = 0; i < 4; ++i) {
            int c = cb + i * 16;
            int p = p0 + px4;
            const float* src = xp + ((size_t)(b * Cch + c0 + c)) * THW + p;
            float4 v;
            if (p + 3 < THW) {
                v = *(const float4*)src;
            } else {
                v.x = (p     < THW) ? src[0] : 0.f;
                v.y = (p + 1 < THW) ? src[1] : 0.f;
                v.z = (p + 2 < THW) ? src[2] : 0.f;
                v.w = (p + 3 < THW) ? src[3] : 0.f;
            }
            T[c][px4] = v.x; T[c][px4 + 1] = v.y;
            T[c][px4 + 2] = v.z; T[c][px4 + 3] = v.w;
        }
    }
    __syncthreads();
    {
        int px = tid >> 2;
        int cs = (tid & 3) * 16;
        int p = p0 + px;
        if (p < THW) {
            ushort8 hi[2], lo[2];
            #pragma unroll
            for (int j = 0; j < 16; ++j) {
                float v = T[cs + j][px];
                unsigned short h = f2bf(v);
                hi[j >> 3][j & 7] = h;
                lo[j >> 3][j & 7] = f2bf(v - bf2f(h));
            }
            size_t base = ((size_t)b * THW + p) * 512 + c0 + cs;
            *(ushort8*)&Xh[base]     = hi[0];
            *(ushort8*)&Xh[base + 8] = hi[1];
            *(ushort8*)&Xl[base]     = lo[0];
            *(ushort8*)&Xl[base + 8] = lo[1];
        }
    }
}

// ---------------- K2: Q/M/V projections via split-bf16 MFMA ----------------
// grid (31 px-tiles, 6 oc-tiles, B). BM=128 oc, BN=128 px, K-step 64.
// acc = Whi*Xhi + Whi*Xlo + Wlo*Xhi  (~fp32 accuracy, 3x bf16 MFMA rate)
__global__ __launch_bounds__(256) void k_qmv_mfma(
    const unsigned short* __restrict__ Xh, const unsigned short* __restrict__ Xl,
    const float* __restrict__ Wq, const float* __restrict__ Wm,
    const float* __restrict__ Wv,
    unsigned short* __restrict__ Qbf, unsigned short* __restrict__ Mbf,
    float* __restrict__ Vcl, unsigned short* __restrict__ Vbf) {
    __shared__ unsigned short Whs[128 * 64] __attribute__((aligned(16)));
    __shared__ unsigned short Wls[128 * 64] __attribute__((aligned(16)));
    const int p0  = blockIdx.x * 128;
    const int sel = blockIdx.y >> 1;            // 0:Q 1:M 2:V
    const int ocr = (blockIdx.y & 1) * 128;     // row offset within the 256-row matrix
    const int b   = blockIdx.z;
    const float* Wbase = ((sel == 0) ? Wq : (sel == 1) ? Wm : Wv) + (size_t)ocr * 512;
    const int tid = threadIdx.x;
    const int wv = tid >> 6, lane = tid & 63;
    const int l15 = lane & 15, quad = lane >> 4;

    floatx4 acc[8][2];
    #pragma unroll
    for (int i = 0; i < 8; ++i)
        #pragma unroll
        for (int h = 0; h < 2; ++h) acc[i][h] = (floatx4){0.f, 0.f, 0.f, 0.f};

    for (int kc = 0; kc < 512; kc += 64) {
        __syncthreads();
        // stage W tile [128oc][64k] hi+lo, XOR chunk swizzle (conflict-free b128)
        #pragma unroll
        for (int i = 0; i < 4; ++i) {
            int t = i * 256 + tid;              // 0..1023
            int row = t >> 3, c8 = t & 7;       // row 0..127, chunk 0..7
            const float* wr = Wbase + (size_t)row * 512 + kc + c8 * 8;
            float v[8];
            *(float4*)&v[0] = *(const float4*)wr;
            *(float4*)&v[4] = *(const float4*)(wr + 4);
            ushort8 hi, lo;
            #pragma unroll
            for (int j = 0; j < 8; ++j) {
                unsigned short h = f2bf(v[j]);
                hi[j] = h;
                lo[j] = f2bf(v[j] - bf2f(h));
            }
            int addr = row * 64 + ((c8 ^ (row & 7)) << 3);
            *(ushort8*)&Whs[addr] = hi;
            *(ushort8*)&Wls[addr] = lo;
        }
        __syncthreads();
        #pragma unroll
        for (int half = 0; half < 2; ++half) {
            int px = p0 + (wv * 2 + half) * 16 + l15;
            int pxc = min(px, THW - 1);
            const unsigned short* xh = Xh + ((size_t)b * THW + pxc) * 512 + kc;
            const unsigned short* xl = Xl + ((size_t)b * THW + pxc) * 512 + kc;
            #pragma unroll
            for (int ks = 0; ks < 2; ++ks) {
                ushort8 bh = *(const ushort8*)&xh[ks * 32 + quad * 8];
                ushort8 bl = *(const ushort8*)&xl[ks * 32 + quad * 8];
                #pragma unroll
                for (int oct = 0; oct < 8; ++oct) {
                    int row = oct * 16 + l15;
                    int ca = row * 64 + (((ks * 4 + quad) ^ (row & 7)) << 3);
                    ushort8 ah = *(const ushort8*)&Whs[ca];
                    ushort8 al = *(const ushort8*)&Wls[ca];
                    acc[oct][half] = __builtin_amdgcn_mfma_f32_16x16x32_bf16(
                        __builtin_bit_cast(bf16x8, ah),
                        __builtin_bit_cast(bf16x8, bh), acc[oct][half], 0, 0, 0);
                    acc[oct][half] = __builtin_amdgcn_mfma_f32_16x16x32_bf16(
                        __builtin_bit_cast(bf16x8, ah),
                        __builtin_bit_cast(bf16x8, bl), acc[oct][half], 0, 0, 0);
                    acc[oct][half] = __builtin_amdgcn_mfma_f32_16x16x32_bf16(
                        __builtin_bit_cast(bf16x8, al),
                        __builtin_bit_cast(bf16x8, bh), acc[oct][half], 0, 0, 0);
                }
            }
        }
    }
    // epilogue: C row = ocr+oct*16+quad*4+r, col px = p0+(wv*2+half)*16+l15
    if (sel < 2) {
        unsigned short* outbf = sel ? Mbf : Qbf;
        const float scale = sel ? 1.0f : 0.0625f;
        #pragma unroll
        for (int half = 0; half < 2; ++half) {
            int px = p0 + (wv * 2 + half) * 16 + l15;
            if (px < THW) {
                #pragma unroll
                for (int oct = 0; oct < 8; ++oct) {
                    int ch = ocr + oct * 16 + quad * 4;
                    ushort4v v;
                    #pragma unroll
                    for (int r = 0; r < 4; ++r) v[r] = f2bf(acc[oct][half][r] * scale);
                    *(ushort4v*)&outbf[((size_t)b * THW + px) * 256 + ch] = v;
                }
            }
        }
    } else {
        #pragma unroll
        for (int half = 0; half < 2; ++half) {
            int px = p0 + (wv * 2 + half) * 16 + l15;
            if (px < THW) {
                int m = px / HW;
                int key = px - m * HW;
                size_t vbbase = (size_t)(b * 4 + m) * 256;
                #pragma unroll
                for (int oct = 0; oct < 8; ++oct) {
                    int ch = ocr + oct * 16 + quad * 4;
                    float4 fv = make_float4(acc[oct][half][0], acc[oct][half][1],
                                            acc[oct][half][2], acc[oct][half][3]);
                    *(float4*)&Vcl[((size_t)b * THW + px) * 256 + ch] = fv;
                    #pragma unroll
                    for (int r = 0; r < 4; ++r)
                        Vbf[(vbbase + ch + r) * VP + key] = f2bf(acc[oct][half][r]);
                }
            }
        }
    }
}

// ---------------- K3: flash attention, wave-owns-queries + register-prefetch ---
// grid (16, 61). Each wave owns 16 queries (Q in regs). M/V time-share one
// 32KB LDS region; M(kt+1)/V(kt+1) prefetched into REGISTERS right after the
// QK barrier (latency hides under softmax+PV), committed via ds_write in the
// phase where the region is dead. 4 barriers/iter. LDS 41KB -> 3 blocks/CU.
__global__ __launch_bounds__(256, 3) void k_attn_mfma(
    const unsigned short* __restrict__ Qbf, const unsigned short* __restrict__ Mbf,
    const unsigned short* __restrict__ Vbf, unsigned short* __restrict__ Rbf) {
    __shared__ unsigned short KV[16384] __attribute__((aligned(16)));  // 32KB M|V
    __shared__ unsigned short Ps[4096] __attribute__((aligned(16)));   // 8KB P
    __shared__ float alpha_s[64];
    __shared__ float l_s[64];

    const int bm = blockIdx.x;
    const int b = bm >> 2, m = bm & 3;
    const int q0 = blockIdx.y * 64;
    const int tid = threadIdx.x;
    const int wv = tid >> 6, lane = tid & 63;
    const int l15 = lane & 15, quad = lane >> 4;
    const int x7 = l15 & 7;

    const size_t mbase = ((size_t)b * THW + m * HW) * 256;
    const size_t vb = (size_t)bm * 256 * VP;

    // Q fragments in registers: this lane is column q = q0 + wv*16 + l15
    const int qg = min(q0 + wv * 16 + l15, THW - 1);
    const unsigned short* qp = Qbf + ((size_t)b * THW + qg) * 256 + quad * 8;
    ushort8 qreg[8];
    #pragma unroll
    for (int kci = 0; kci < 8; ++kci)
        qreg[kci] = *(const ushort8*)&qp[kci * 32];

    // prefetch M(0) into regs (tile 0 is always full: HW > 64)
    ushort8 mpre[8];
    #pragma unroll
    for (int it = 0; it < 8; ++it) {
        int v = it * 256 + tid;
        int key = v >> 5, ck = v & 31;
        mpre[it] = *(const ushort8*)&Mbf[mbase + (size_t)key * 256 + ck * 8];
    }
    // prefetch V(0) into regs
    ushort8 vpre[8];
    #pragma unroll
    for (int it = 0; it < 8; ++it) {
        int u = it * 256 + tid;
        int ch = u >> 3, k8 = (u & 7) << 3;
        vpre[it] = *(const ushort8*)&Vbf[vb + (size_t)ch * VP + k8];
    }

    floatx4 o[4][4];
    #pragma unroll
    for (int mt = 0; mt < 4; ++mt)
        #pragma unroll
        for (int nt = 0; nt < 4; ++nt) o[mt][nt] = (floatx4){0.f, 0.f, 0.f, 0.f};
    float m_run = -1e30f, l_run = 0.f;

    // commit M(0): KV[key][256ch], content chunk ck at slot ck^(key&7)
    #pragma unroll
    for (int it = 0; it < 8; ++it) {
        int v = it * 256 + tid;
        int key = v >> 5, ck = v & 31;
        *(ushort8*)&KV[key * 256 + ((ck ^ (key & 7)) << 3)] = mpre[it];
    }
    __syncthreads();   // M(0) visible

    for (int kt = 0; kt < 16; ++kt) {
        const int k0 = kt * 64;
        const int nv = min(64, HW - k0);
        // QK: C[key_local][q], A = M frags from LDS, B = Q regs
        floatx4 sc[4];
        #pragma unroll
        for (int kb = 0; kb < 4; ++kb) sc[kb] = (floatx4){0.f, 0.f, 0.f, 0.f};
        #pragma unroll
        for (int kb = 0; kb < 4; ++kb) {
            const int key = kb * 16 + l15;
            #pragma unroll
            for (int kci = 0; kci < 8; ++kci) {
                ushort8 mf = *(const ushort8*)&KV[key * 256 +
                    ((((kci << 2) + quad) ^ x7) << 3)];
                sc[kb] = __builtin_amdgcn_mfma_f32_16x16x32_bf16(
                    __builtin_bit_cast(bf16x8, mf),
                    __builtin_bit_cast(bf16x8, qreg[kci]), sc[kb], 0, 0, 0);
            }
        }
        __syncthreads();   // C: all M reads done
        // commit V(kt) from regs: KV[ch][64keys], chunk c at slot c^(ch&7)
        #pragma unroll
        for (int it = 0; it < 8; ++it) {
            int u = it * 256 + tid;
            int ch = u >> 3, k8 = (u & 7) << 3;
            *(ushort8*)&KV[ch * 64 + (((k8 >> 3) ^ (ch & 7)) << 3)] = vpre[it];
        }
        // prefetch M(kt+1) and V(kt+1) (fly during softmax + PV)
        if (kt < 15) {
            int k0n = k0 + 64;
            int nvn = min(64, HW - k0n);
            #pragma unroll
            for (int it = 0; it < 8; ++it) {
                int v = it * 256 + tid;
                int key = v >> 5, ck = v & 31;
                ushort8 val = {0, 0, 0, 0, 0, 0, 0, 0};
                if (key < nvn)
                    val = *(const ushort8*)&Mbf[mbase + (size_t)(k0n + key) * 256 + ck * 8];
                mpre[it] = val;
            }
            #pragma unroll
            for (int it = 0; it < 8; ++it) {
                int u = it * 256 + tid;
                int ch = u >> 3, k8 = (u & 7) << 3;
                vpre[it] = *(const ushort8*)&Vbf[vb + (size_t)ch * VP + k0n + k8];
            }
        }
        // wave-local softmax for q = l15 (keys spread over kb regs + quad lanes)
        #pragma unroll
        for (int kb = 0; kb < 4; ++kb) {
            #pragma unroll
            for (int r = 0; r < 4; ++r)
                if (kb * 16 + quad * 4 + r >= nv) sc[kb][r] = -1e30f;
        }
        float mx = -1e30f;
        #pragma unroll
        for (int kb = 0; kb < 4; ++kb)
            mx = fmaxf(mx, fmaxf(fmaxf(sc[kb][0], sc[kb][1]),
                                 fmaxf(sc[kb][2], sc[kb][3])));
        mx = fmaxf(mx, __shfl_xor(mx, 16));
        mx = fmaxf(mx, __shfl_xor(mx, 32));
        float m_new = fmaxf(m_run, mx);
        float al = __expf(m_run - m_new);
        float sm = 0.f;
        #pragma unroll
        for (int kb = 0; kb < 4; ++kb) {
            #pragma unroll
            for (int r = 0; r < 4; ++r) {
                float p = __expf(sc[kb][r] - m_new);
                sc[kb][r] = p;
                sm += p;
            }
        }
        sm += __shfl_xor(sm, 16);
        sm += __shfl_xor(sm, 32);
        l_run = l_run * al + sm;
        m_run = m_new;
        if (quad == 0) alpha_s[wv * 16 + l15] = al;
        // write P bf16 -> Ps[q][64keys] swizzled (4 keys packed per write)
        {
            const int prow = wv * 16 + l15;
            #pragma unroll
            for (int kb = 0; kb < 4; ++kb) {
                ushort4v pk;
                #pragma unroll
                for (int r = 0; r < 4; ++r) pk[r] = f2bf(sc[kb][r]);
                int cW = ((kb << 1) + (quad >> 1)) ^ x7;
                *(ushort4v*)&Ps[prow * 64 + (cW << 3) + ((quad & 1) << 2)] = pk;
            }
        }
        __syncthreads();   // D: V committed, Ps + alpha visible
        // rescale O, then PV (wave owns ch slice wv*64..+63, all 64 q)
        #pragma unroll
        for (int mt = 0; mt < 4; ++mt) {
            float alq[4];
            #pragma unroll
            for (int r = 0; r < 4; ++r) alq[r] = alpha_s[mt * 16 + quad * 4 + r];
            #pragma unroll
            for (int nt = 0; nt < 4; ++nt)
                #pragma unroll
                for (int r = 0; r < 4; ++r) o[mt][nt][r] *= alq[r];
        }
        #pragma unroll
        for (int ks = 0; ks < 2; ++ks) {
            ushort8 af[4];
            #pragma unroll
            for (int mt = 0; mt < 4; ++mt)
                af[mt] = *(const ushort8*)&Ps[(mt * 16 + l15) * 64 +
                    ((((ks << 2) + quad) ^ x7) << 3)];
            #pragma unroll
            for (int nt = 0; nt < 4; ++nt) {
                int ch = wv * 64 + nt * 16 + l15;
                ushort8 bv = *(const ushort8*)&KV[ch * 64 +
                    ((((ks << 2) + quad) ^ x7) << 3)];
                #pragma unroll
                for (int mt = 0; mt < 4; ++mt)
                    o[mt][nt] = __builtin_amdgcn_mfma_f32_16x16x32_bf16(
                        __builtin_bit_cast(bf16x8, af[mt]),
                        __builtin_bit_cast(bf16x8, bv), o[mt][nt], 0, 0, 0);
            }
        }
        __syncthreads();   // E: all V/Ps reads done
        if (kt < 15) {
            // commit M(kt+1)
            #pragma unroll
            for (int it = 0; it < 8; ++it) {
                int v = it * 256 + tid;
                int key = v >> 5, ck = v & 31;
                *(ushort8*)&KV[key * 256 + ((ck ^ (key & 7)) << 3)] = mpre[it];
            }
        }
        __syncthreads();   // F: M(kt+1) visible
    }
    if (quad == 0) l_s[wv * 16 + l15] = l_run;
    __syncthreads();
    // normalize + stage O (bf16) into KV as [q_local][256ch]
    #pragma unroll
    for (int mt = 0; mt < 4; ++mt) {
        float invl[4];
        #pragma unroll
        for (int r = 0; r < 4; ++r) invl[r] = 1.f / l_s[mt * 16 + quad * 4 + r];
        #pragma unroll
        for (int nt = 0; nt < 4; ++nt) {
            int ch = wv * 64 + nt * 16 + l15;
            #pragma unroll
            for (int r = 0; r < 4; ++r) {
                int qrow = mt * 16 + quad * 4 + r;
                KV[qrow * 256 + ch] = f2bf(o[mt][nt][r] * invl[r]);
            }
        }
    }
    __syncthreads();
    // coalesced nontemporal store: 8 chunks/thread, 16B/lane
    #pragma unroll
    for (int k = 0; k < 8; ++k) {
        int idx = k * 256 + tid;
        int qrow = idx >> 5, c = idx & 31;
        int q = q0 + qrow;
        if (q < THW) {
            ushort8 v = *(const ushort8*)&KV[qrow * 256 + c * 8];
            __builtin_nontemporal_store(v,
                (ushort8*)&Rbf[((size_t)bm * THW + q) * 256 + c * 8]);
        }
    }
}

// ---------------- K5: compare convs via MFMA (R now bf16) ----------------
__global__ __launch_bounds__(256) void k_cmp(
    const unsigned short* __restrict__ Rbf, const float* __restrict__ Vcl,
    const unsigned short* __restrict__ Wpk, float* __restrict__ Pc) {
    __shared__ unsigned short Ws[24576] __attribute__((aligned(16)));  // 48 KB
    const int strip = blockIdx.x;
    const int s = blockIdx.y;
    const int b = blockIdx.z >> 1, kind = blockIdx.z & 1;
    const int m = s >> 2, tq = s & 3;
    const int tid = threadIdx.x;
    const int wv = tid >> 6, lane = tid & 63;
    const int l15 = lane & 15, quad = lane >> 4;

    const unsigned short* wsrc = Wpk + (kind ? 24576 : 0);
    for (int i = tid; i < 3072; i += 256) {
        int row, ch, stride_us;
        if (kind == 0) { row = i >> 6; ch = i & 63; stride_us = 512; }
        else           { row = i >> 5; ch = i & 31; stride_us = 256; }
        ushort8 v = *(const ushort8*)&wsrc[i * 8];
        *(ushort8*)&Ws[row * stride_us + ((ch ^ (row & 7)) << 3)] = v;
    }
    __syncthreads();

    const size_t rbase = ((size_t)(b * 4 + m) * THW + tq * HW) * 256;
    const size_t vbase = ((size_t)b * THW + m * HW) * 256;

    #pragma unroll
    for (int half = 0; half < 2; ++half) {
        int pxt = wv * 2 + half;
        int hw = strip * 128 + pxt * 16 + l15;
        int hwc = min(hw, HW - 1);
        const unsigned short* rrow = Rbf + rbase + (size_t)hwc * 256;
        const float* vrow = Vcl + vbase + (size_t)hwc * 256;
        bf16x8 fr[8], fs[8];   // kind0: R,V ; kind1: D,P
        #pragma unroll
        for (int ks = 0; ks < 8; ++ks) {
            ushort8 r8 = *(const ushort8*)&rrow[ks * 32 + quad * 8];
            float vv[8];
            *(float4*)&vv[0] = *(const float4*)&vrow[ks * 32 + quad * 8];
            *(float4*)&vv[4] = *(const float4*)&vrow[ks * 32 + quad * 8 + 4];
            bf16x8 a, c;
            if (kind == 0) {
                a = __builtin_bit_cast(bf16x8, r8);
                #pragma unroll
                for (int j = 0; j < 8; ++j) c[j] = (__bf16)vv[j];
            } else {
                #pragma unroll
                for (int j = 0; j < 8; ++j) {
                    float rj = bf2f(r8[j]);
                    a[j] = (__bf16)(rj - vv[j]);
                    c[j] = (__bf16)(rj * vv[j]);
                }
            }
            fr[ks] = a; fs[ks] = c;
        }
        floatx4 acc[6];
        #pragma unroll
        for (int i = 0; i < 6; ++i) acc[i] = (floatx4){0.f, 0.f, 0.f, 0.f};
        if (kind == 0) {
            #pragma unroll
            for (int ks = 0; ks < 16; ++ks) {
                bf16x8 bfr = (ks < 8) ? fr[ks] : fs[ks - 8];
                #pragma unroll
                for (int cit = 0; cit < 3; ++cit) {
                    int row = cit * 16 + l15;
                    ushort8 aw = *(const ushort8*)&Ws[row * 512 + (((ks * 4 + quad) ^ (row & 7)) << 3)];
                    acc[cit] = __builtin_amdgcn_mfma_f32_16x16x32_bf16(
                        __builtin_bit_cast(bf16x8, aw), bfr, acc[cit], 0, 0, 0);
                }
            }
        } else {
            #pragma unroll
            for (int ks = 0; ks < 8; ++ks) {
                #pragma unroll
                for (int cit = 0; cit < 6; ++cit) {
                    int row = cit * 16 + l15;
                    ushort8 aw = *(const ushort8*)&Ws[row * 256 + (((ks * 4 + quad) ^ (row & 7)) << 3)];
                    bf16x8 bfr = (cit < 3) ? fr[ks] : fs[ks];
                    acc[cit] = __builtin_amdgcn_mfma_f32_16x16x32_bf16(
                        __builtin_bit_cast(bf16x8, aw), bfr, acc[cit], 0, 0, 0);
                }
            }
        }
        if (hw < HW) {
            if (kind == 0) {
                #pragma unroll
                for (int cit = 0; cit < 3; ++cit)
                    #pragma unroll
                    for (int r = 0; r < 4; ++r) {
                        int ci = cit * 16 + quad * 4 + r;
                        if (ci < 42)
                            Pc[((size_t)(b * NCMP + ci) * 16 + s) * HW + hw] = acc[cit][r];
                    }
            } else {
                #pragma unroll
                for (int cit = 0; cit < 6; ++cit)
                    #pragma unroll
                    for (int r = 0; r < 4; ++r) {
                        int cl = (cit % 3) * 16 + quad * 4 + r;
                        if (cl < 42) {
                            int ci = (cit < 3 ? 42 : 84) + cl;
                            Pc[((size_t)(b * NCMP + ci) * 16 + s) * HW + hw] = acc[cit][r];
                        }
                    }
            }
        }
    }
}

// ---------------- K6: BN stats for compare ----------------
__global__ __launch_bounds__(256) void k_stats_cmp(
    const float* __restrict__ Pc, const float* __restrict__ g_cat,
    const float* __restrict__ b_cat, const float* __restrict__ g_sub,
    const float* __restrict__ b_sub, const float* __restrict__ g_mul,
    const float* __restrict__ b_mul, float* __restrict__ bnc) {
    const int c = blockIdx.x, tid = threadIdx.x;
    float s = 0.f, q = 0.f;
    for (int i = tid; i < 4 * 16 * HW; i += 256) {
        int bb = i / (16 * HW), r = i - bb * (16 * HW);
        float v = Pc[(size_t)(bb * NCMP + c) * (16 * HW) + r];
        s += v; q += v * v;
    }
    __shared__ float rs[256], rq[256];
    rs[tid] = s; rq[tid] = q;
    __syncthreads();
    for (int off = 128; off > 0; off >>= 1) {
        if (tid < off) { rs[tid] += rs[tid + off]; rq[tid] += rq[tid + off]; }
        __syncthreads();
    }
    if (tid == 0) {
        const float n = 4.f * 16.f * HW;
        float mean = rs[0] / n;
        float var = rq[0] / n - mean * mean;
        float g, bt;
        if (c < 42)       { g = g_cat[c];      bt = b_cat[c]; }
        else if (c < 84)  { g = g_sub[c - 42]; bt = b_sub[c - 42]; }
        else              { g = g_mul[c - 84]; bt = b_mul[c - 84]; }
        float sc = g * rsqrtf(var + BN_EPS);
        bnc[c] = sc;
        bnc[NCMP + c] = bt - mean * sc;
    }
}

// ---------------- K7: build Y channel-last bf16 [b][p][1024] ----------------
__global__ __launch_bounds__(256) void k_build_y(
    const unsigned short* __restrict__ Rbf, const float* __restrict__ Vcl,
    const float* __restrict__ Pc, const float* __restrict__ bnc,
    unsigned short* __restrict__ Ybf) {
    const int strip = blockIdx.x, t = blockIdx.y, b = blockIdx.z;
    const int tid = threadIdx.x;
    const int chl = tid & 31;
    const int hwl = tid >> 5;
    for (int pass = 0; pass < 8; ++pass) {
        int hw = strip * 64 + pass * 8 + hwl;
        if (hw >= HW) continue;
        size_t ybase = ((size_t)b * THW + t * HW + hw) * 1024;
        for (int cb = 0; cb < 8; ++cb) {
            int ch = cb * 128 + chl * 4;
            float v[4];
            if (ch < 256) {
                v[0] = v[1] = v[2] = v[3] = 0.f;
                #pragma unroll
                for (int tq = 0; tq < 4; ++tq) {
                    ushort4v rv = *(const ushort4v*)&Rbf[
                        (((size_t)(b * 4 + t)) * THW + tq * HW + hw) * 256 + ch];
                    v[0] += bf2f(rv[0]); v[1] += bf2f(rv[1]);
                    v[2] += bf2f(rv[2]); v[3] += bf2f(rv[3]);
                }
                v[0] *= 0.25f; v[1] *= 0.25f; v[2] *= 0.25f; v[3] *= 0.25f;
            } else if (ch < 512) {
                float4 vv = *(const float4*)&Vcl[((size_t)b * THW + t * HW + hw) * 256 + (ch - 256)];
                v[0] = vv.x; v[1] = vv.y; v[2] = vv.z; v[3] = vv.w;
            } else if (ch < 1016) {
                int ci = (ch - 512) >> 2;
                float sc = bnc[ci], sh = bnc[NCMP + ci];
                #pragma unroll
                for (int mm = 0; mm < 4; ++mm) {
                    float pv = Pc[(((size_t)(b * NCMP + ci)) * 16 + mm * 4 + t) * HW + hw];
                    v[mm] = fmaxf(fmaf(pv, sc, sh), 0.f);
                }
            } else {
                v[0] = v[1] = v[2] = v[3] = 0.f;
            }
            ushort4v ov;
            #pragma unroll
            for (int i = 0; i < 4; ++i) ov[i] = f2bf(v[i]);
            *(ushort4v*)&Ybf[ybase + ch] = ov;
        }
    }
}

// ---------------- K8: aggregate GEMM via MFMA ----------------
__global__ __launch_bounds__(256) void k_aggm(
    const unsigned short* __restrict__ Wab, const unsigned short* __restrict__ Ybf,
    float* __restrict__ Z) {
    __shared__ unsigned short Wt[16384] __attribute__((aligned(16)));
    const int p0 = blockIdx.x * 128;
    const int oc0 = blockIdx.y * 128;
    const int b = blockIdx.z;
    const int tid = threadIdx.x;
    const int wv = tid >> 6, lane = tid & 63;
    const int l15 = lane & 15, quad = lane >> 4;
    floatx4 acc[8][2];
    #pragma unroll
    for (int i = 0; i < 8; ++i)
        #pragma unroll
        for (int h = 0; h < 2; ++h) acc[i][h] = (floatx4){0.f, 0.f, 0.f, 0.f};
    for (int kc = 0; kc < 8; ++kc) {
        __syncthreads();
        for (int i = tid; i < 2048; i += 256) {
            int row = i >> 4, ch = i & 15;
            ushort8 v = *(const ushort8*)&Wab[(size_t)(oc0 + row) * 1024 + kc * 128 + ch * 8];
            *(ushort8*)&Wt[row * 128 + ((ch ^ (row & 7)) << 3)] = v;
        }
        __syncthreads();
        #pragma unroll
        for (int half = 0; half < 2; ++half) {
            int px = p0 + (wv * 2 + half) * 16 + l15;
            int pxc = min(px, THW - 1);
            const unsigned short* yrow = Ybf + ((size_t)b * THW + pxc) * 1024 + kc * 128;
            #pragma unroll
            for (int ks = 0; ks < 4; ++ks) {
                ushort8 bf = *(const ushort8*)&yrow[ks * 32 + quad * 8];
                #pragma unroll
                for (int oct = 0; oct < 8; ++oct) {
                    int row = oct * 16 + l15;
                    ushort8 af = *(const ushort8*)&Wt[row * 128 + ((((ks * 4 + quad) ^ (row & 7))) << 3)];
                    acc[oct][half] = __builtin_amdgcn_mfma_f32_16x16x32_bf16(
                        __builtin_bit_cast(bf16x8, af),
                        __builtin_bit_cast(bf16x8, bf), acc[oct][half], 0, 0, 0);
                }
            }
        }
    }
    #pragma unroll
    for (int half = 0; half < 2; ++half) {
        int px = p0 + (wv * 2 + half) * 16 + l15;
        if (px < THW) {
            #pragma unroll
            for (int oct = 0; oct < 8; ++oct) {
                int oc = oc0 + oct * 16 + quad * 4;
                #pragma unroll
                for (int r = 0; r < 4; ++r)
                    Z[((size_t)(b * Cch + oc + r)) * THW + px] = acc[oct][half][r];
            }
        }
    }
}

// ---------------- K9: BN stats for aggregate ----------------
__global__ __launch_bounds__(256) void k_stats_agg(
    const float* __restrict__ Z, const float* __restrict__ g_agg,
    const float* __restrict__ b_agg, float* __restrict__ bna) {
    const int c = blockIdx.x, tid = threadIdx.x;
    float s = 0.f, q = 0.f;
    for (int i = tid; i < 4 * THW; i += 256) {
        int bb = i / THW, p = i - bb * THW;
        float v = Z[((size_t)bb * Cch + c) * THW + p];
        s += v; q += v * v;
    }
    __shared__ float rs[256], rq[256];
    rs[tid] = s; rq[tid] = q;
    __syncthreads();
    for (int off = 128; off > 0; off >>= 1) {
        if (tid < off) { rs[tid] += rs[tid + off]; rq[tid] += rq[tid + off]; }
        __syncthreads();
    }
    if (tid == 0) {
        const float n = 4.f * THW;
        float mean = rs[0] / n;
        float var = rq[0] / n - mean * mean;
        float sc = g_agg[c] * rsqrtf(var + BN_EPS);
        bna[c] = sc;
        bna[Cch + c] = b_agg[c] - mean * sc;
    }
}

// ---------------- K10: out = relu(xp + BN(Z)) ----------------
__global__ __launch_bounds__(256) void k_final(const float* __restrict__ xp,
                                               const float* __restrict__ Z,
                                               const float* __restrict__ bna,
                                               float* __restrict__ out) {
    int idx = blockIdx.x * 256 + threadIdx.x;
    if (idx >= NPIX) return;
    int c = (idx / THW) & 511;
    out[idx] = fmaxf(fmaf(Z[idx], bna[c], bna[Cch + c]) + xp[idx], 0.f);
}

extern "C" void kernel_launch(void* const* d_in, const int* in_sizes, int n_in,
                              void* d_out, int out_size, void* d_ws, size_t ws_size,
                              hipStream_t stream) {
    const float* x     = (const float*)d_in[0];
    const float* Wq    = (const float*)d_in[1];
    const float* Wm    = (const float*)d_in[2];
    const float* Wv    = (const float*)d_in[3];
    const float* Wcat  = (const float*)d_in[4];
    const float* Wsub  = (const float*)d_in[5];
    const float* Wmul  = (const float*)d_in[6];
    const float* g_cat = (const float*)d_in[7];
    const float* b_cat = (const float*)d_in[8];
    const float* g_sub = (const float*)d_in[9];
    const float* b_sub = (const float*)d_in[10];
    const float* g_mul = (const float*)d_in[11];
    const float* b_mul = (const float*)d_in[12];
    const float* Wagg  = (const float*)d_in[13];
    const float* g_agg = (const float*)d_in[14];
    const float* b_agg = (const float*)d_in[15];
    float* out = (float*)d_out;
    float* ws  = (float*)d_ws;

    // workspace layout (float offsets); total 35,714,560 fl = 142.9 MB
    float* xp  = ws;                          // 7,872,512
    float* Vcl = xp + 7872512;                // 3,936,256  -> 11,808,768
    float* bnc = Vcl + 3936256;               // 512        -> 11,809,280
    float* bna = bnc + 512;                   // 1024       -> 11,810,304
    unsigned short* Wpk = (unsigned short*)(bna + 1024);   // 49,152 us = 24,576 fl
    unsigned short* Wab = Wpk + 49152;                     // 524,288 us = 262,144 fl
    float* bfreg = (float*)(Wab + 524288);    // 7,872,512 fl -> Qbf/Mbf/Vbf; later Ybf
    unsigned short* Qbf = (unsigned short*)bfreg;          // 3,936,256 us
    unsigned short* Mbf = Qbf + 3936256;                   // 3,936,256 us
    unsigned short* Vbf = Mbf + 3936256;                   // 4,194,304 us
    unsigned short* Ybf = (unsigned short*)bfreg;          // alias (Q/M/V dead)
    unsigned short* Rbf = (unsigned short*)(bfreg + 7872512);  // 15,745,024 us = 7,872,512 fl
    float* Pc = (float*)(Rbf + 15745024);     // 7,750,656 fl (+121,856 pad for Z tail)
    float* Z  = (float*)Rbf;                  // alias: Rbf+Pc dead after build_y
    // Xh/Xl (split-bf16 channel-last xp) alias the Rbf region: live only
    // between k_xpose and k_qmv_mfma; k_attn overwrites Rbf afterwards.
    unsigned short* Xh = Rbf;                 // 7,872,512 us
    unsigned short* Xl = Xh + 7872512;        // 7,872,512 us (fills Rbf region exactly)

    k_prep_w<<<dim3(3248), dim3(256), 0, stream>>>(Wcat, Wsub, Wmul, Wagg, Wpk, Wab, Vbf);
    k_pool<<<dim3((NPIX + 255) / 256), dim3(256), 0, stream>>>(x, xp);
    k_xpose<<<dim3(61, 8, Bb), dim3(256), 0, stream>>>(xp, Xh, Xl);
    k_qmv_mfma<<<dim3(31, 6, Bb), dim3(256), 0, stream>>>(Xh, Xl, Wq, Wm, Wv,
                                                          Qbf, Mbf, Vcl, Vbf);
    k_attn_mfma<<<dim3(16, 61), dim3(256), 0, stream>>>(Qbf, Mbf, Vbf, Rbf);
    k_cmp<<<dim3(8, 16, 8), dim3(256), 0, stream>>>(Rbf, Vcl, Wpk, Pc);
    k_stats_cmp<<<dim3(NCMP), dim3(256), 0, stream>>>(Pc, g_cat, b_cat, g_sub, b_sub,
                                                      g_mul, b_mul, bnc);
    k_build_y<<<dim3(16, 4, Bb), dim3(256), 0, stream>>>(Rbf, Vcl, Pc, bnc, Ybf);
    k_aggm<<<dim3(31, 4, Bb), dim3(256), 0, stream>>>(Wab, Ybf, Z);
    k_stats_agg<<<dim3(Cch), dim3(256), 0, stream>>>(Z, g_agg, b_agg, bna);
    k_final<<<dim3((NPIX + 255) / 256), dim3(256), 0, stream>>>(xp, Z, bna, out);
}

// Round 5
// 733.294 us; speedup vs baseline: 1.5344x; 1.5344x over previous
//
#include <hip/hip_runtime.h>
#include <math.h>

// Problem dims
constexpr int Bb   = 4;
constexpr int Cch  = 512;
constexpr int HW   = 961;      // 31*31
constexpr int THW  = 3844;     // 4*961
constexpr int NCMP = 126;      // 3*42 compare channels
constexpr int NPIX = Bb * Cch * THW;  // 7,872,512
constexpr int Hp = 31, Wp = 31, H0c = 63, W0c = 63;
constexpr int VP = 1024;       // padded keys/frame for Vbf
#define BN_EPS 1e-5f

typedef __attribute__((ext_vector_type(4))) float floatx4;
typedef __attribute__((ext_vector_type(8))) __bf16 bf16x8;
typedef __attribute__((ext_vector_type(8))) unsigned short ushort8;
typedef __attribute__((ext_vector_type(4))) unsigned short ushort4v;

static __device__ __forceinline__ unsigned short f2bf(float x) {
    unsigned int u = __builtin_bit_cast(unsigned int, x);
    u += 0x7fff + ((u >> 16) & 1);   // RNE
    return (unsigned short)(u >> 16);
}
static __device__ __forceinline__ float bf2f(unsigned short u) {
    return __builtin_bit_cast(float, ((unsigned int)u) << 16);
}

// ---------------- K0: pack weights to bf16 (+ zero Vbf key pad) ----------------
__global__ __launch_bounds__(256) void k_prep_w(
    const float* __restrict__ Wcat, const float* __restrict__ Wsub,
    const float* __restrict__ Wmul, const float* __restrict__ Wagg,
    unsigned short* __restrict__ Wpk, unsigned short* __restrict__ Wab,
    unsigned short* __restrict__ Vbf) {
    int idx = blockIdx.x * 256 + threadIdx.x;
    if (idx < 24576) {                       // cat
        int row = idx >> 9, k = idx & 511;
        Wpk[idx] = (row < 42) ? f2bf(Wcat[row * 512 + k]) : 0;
    } else if (idx < 36864) {                // sub
        int i = idx - 24576;
        int row = i >> 8, k = i & 255;
        Wpk[idx] = (row < 42) ? f2bf(Wsub[row * 256 + k]) : 0;
    } else if (idx < 49152) {                // mul
        int i = idx - 36864;
        int row = i >> 8, k = i & 255;
        Wpk[idx] = (row < 42) ? f2bf(Wmul[row * 256 + k]) : 0;
    } else if (idx < 49152 + 524288) {       // agg
        int i = idx - 49152;
        int row = i >> 10, k = i & 1023;
        Wab[i] = (k < 1016) ? f2bf(Wagg[(size_t)row * 1016 + k]) : 0;
    } else if (idx < 573440 + 258048) {      // Vbf pad keys [961,1024) := 0
        int i = idx - 573440;
        int row = i / 63, k = i - row * 63;  // row < 4096 = 16bm*256ch
        Vbf[(size_t)row * VP + 961 + k] = 0;
    }
}

// ---------------- K1: maxpool (1,3,3)/(1,2,2) ----------------
__global__ __launch_bounds__(256) void k_pool(const float* __restrict__ x,
                                              float* __restrict__ xp) {
    int idx = blockIdx.x * 256 + threadIdx.x;
    if (idx >= NPIX) return;
    int w = idx % Wp;
    int h = (idx / Wp) % Hp;
    int bct = idx / HW;
    const float* src = x + (size_t)bct * (H0c * W0c) + (2 * h) * W0c + 2 * w;
    float m = -INFINITY;
    #pragma unroll
    for (int i = 0; i < 3; ++i) {
        m = fmaxf(m, src[i * W0c + 0]);
        m = fmaxf(m, src[i * W0c + 1]);
        m = fmaxf(m, src[i * W0c + 2]);
    }
    xp[idx] = m;
}

// ---------------- K1b: transpose xp -> channel-last bf16 hi/lo split ----------------
// xp [b][512][THW] fp32  ->  Xh/Xl [b][THW][512] bf16 (hi + residual-lo)
__global__ __launch_bounds__(256) void k_xpose(const float* __restrict__ xp,
                                               unsigned short* __restrict__ Xh,
                                               unsigned short* __restrict__ Xl) {
    __shared__ float T[64][65];   // +1 pad: conflict-free column reads
    const int p0 = blockIdx.x * 64;
    const int c0 = blockIdx.y * 64;
    const int b  = blockIdx.z;
    const int tid = threadIdx.x;
    // load 64c x 64px, float4 along px (coalesced)
    {
        int px4 = (tid & 15) * 4;
        int cb = tid >> 4;          // 0..15
        #pragma unroll
        for (int i = 0; i < 4; ++i) {
            int c = cb + i * 16;
            int p = p0 + px4;
            const float* src = xp + ((size_t)(b * Cch + c0 + c)) * THW + p;
            float4 v;
            if (p + 3 < THW) {
                v = *(const float4*)src;
            } else {
                v.x = (p     < THW) ? src[0] : 0.f;
                v.y = (p + 1 < THW) ? src[1] : 0.f;
                v.z = (p + 2 < THW) ? src[2] : 0.f;
                v.w = (p + 3 < THW) ? src[3] : 0.f;
            }
            T[c][px4] = v.x; T[c][px4 + 1] = v.y;
            T[c][px4 + 2] = v.z; T[c][px4 + 3] = v.w;
        }
    }
    __syncthreads();
    {
        int px = tid >> 2;
        int cs = (tid & 3) * 16;
        int p = p0 + px;
        if (p < THW) {
            ushort8 hi[2], lo[2];
            #pragma unroll
            for (int j = 0; j < 16; ++j) {
                float v = T[cs + j][px];
                unsigned short h = f2bf(v);
                hi[j >> 3][j & 7] = h;
                lo[j >> 3][j & 7] = f2bf(v - bf2f(h));
            }
            size_t base = ((size_t)b * THW + p) * 512 + c0 + cs;
            *(ushort8*)&Xh[base]     = hi[0];
            *(ushort8*)&Xh[base + 8] = hi[1];
            *(ushort8*)&Xl[base]     = lo[0];
            *(ushort8*)&Xl[base + 8] = lo[1];
        }
    }
}

// ---------------- K2: Q/M/V projections via split-bf16 MFMA ----------------
// grid (31 px-tiles, 6 oc-tiles, B). BM=128 oc, BN=128 px, K-step 64.
// acc = Whi*Xhi + Whi*Xlo + Wlo*Xhi  (~fp32 accuracy, 3x bf16 MFMA rate)
__global__ __launch_bounds__(256) void k_qmv_mfma(
    const unsigned short* __restrict__ Xh, const unsigned short* __restrict__ Xl,
    const float* __restrict__ Wq, const float* __restrict__ Wm,
    const float* __restrict__ Wv,
    unsigned short* __restrict__ Qbf, unsigned short* __restrict__ Mbf,
    float* __restrict__ Vcl, unsigned short* __restrict__ Vbf) {
    __shared__ unsigned short Whs[128 * 64] __attribute__((aligned(16)));
    __shared__ unsigned short Wls[128 * 64] __attribute__((aligned(16)));
    const int p0  = blockIdx.x * 128;
    const int sel = blockIdx.y >> 1;            // 0:Q 1:M 2:V
    const int ocr = (blockIdx.y & 1) * 128;     // row offset within the 256-row matrix
    const int b   = blockIdx.z;
    const float* Wbase = ((sel == 0) ? Wq : (sel == 1) ? Wm : Wv) + (size_t)ocr * 512;
    const int tid = threadIdx.x;
    const int wv = tid >> 6, lane = tid & 63;
    const int l15 = lane & 15, quad = lane >> 4;

    floatx4 acc[8][2];
    #pragma unroll
    for (int i = 0; i < 8; ++i)
        #pragma unroll
        for (int h = 0; h < 2; ++h) acc[i][h] = (floatx4){0.f, 0.f, 0.f, 0.f};

    for (int kc = 0; kc < 512; kc += 64) {
        __syncthreads();
        // stage W tile [128oc][64k] hi+lo, XOR chunk swizzle (conflict-free b128)
        #pragma unroll
        for (int i = 0; i < 4; ++i) {
            int t = i * 256 + tid;              // 0..1023
            int row = t >> 3, c8 = t & 7;       // row 0..127, chunk 0..7
            const float* wr = Wbase + (size_t)row * 512 + kc + c8 * 8;
            float v[8];
            *(float4*)&v[0] = *(const float4*)wr;
            *(float4*)&v[4] = *(const float4*)(wr + 4);
            ushort8 hi, lo;
            #pragma unroll
            for (int j = 0; j < 8; ++j) {
                unsigned short h = f2bf(v[j]);
                hi[j] = h;
                lo[j] = f2bf(v[j] - bf2f(h));
            }
            int addr = row * 64 + ((c8 ^ (row & 7)) << 3);
            *(ushort8*)&Whs[addr] = hi;
            *(ushort8*)&Wls[addr] = lo;
        }
        __syncthreads();
        #pragma unroll
        for (int half = 0; half < 2; ++half) {
            int px = p0 + (wv * 2 + half) * 16 + l15;
            int pxc = min(px, THW - 1);
            const unsigned short* xh = Xh + ((size_t)b * THW + pxc) * 512 + kc;
            const unsigned short* xl = Xl + ((size_t)b * THW + pxc) * 512 + kc;
            #pragma unroll
            for (int ks = 0; ks < 2; ++ks) {
                ushort8 bh = *(const ushort8*)&xh[ks * 32 + quad * 8];
                ushort8 bl = *(const ushort8*)&xl[ks * 32 + quad * 8];
                #pragma unroll
                for (int oct = 0; oct < 8; ++oct) {
                    int row = oct * 16 + l15;
                    int ca = row * 64 + (((ks * 4 + quad) ^ (row & 7)) << 3);
                    ushort8 ah = *(const ushort8*)&Whs[ca];
                    ushort8 al = *(const ushort8*)&Wls[ca];
                    acc[oct][half] = __builtin_amdgcn_mfma_f32_16x16x32_bf16(
                        __builtin_bit_cast(bf16x8, ah),
                        __builtin_bit_cast(bf16x8, bh), acc[oct][half], 0, 0, 0);
                    acc[oct][half] = __builtin_amdgcn_mfma_f32_16x16x32_bf16(
                        __builtin_bit_cast(bf16x8, ah),
                        __builtin_bit_cast(bf16x8, bl), acc[oct][half], 0, 0, 0);
                    acc[oct][half] = __builtin_amdgcn_mfma_f32_16x16x32_bf16(
                        __builtin_bit_cast(bf16x8, al),
                        __builtin_bit_cast(bf16x8, bh), acc[oct][half], 0, 0, 0);
                }
            }
        }
    }
    // epilogue: C row = ocr+oct*16+quad*4+r, col px = p0+(wv*2+half)*16+l15
    if (sel < 2) {
        unsigned short* outbf = sel ? Mbf : Qbf;
        const float scale = sel ? 1.0f : 0.0625f;
        #pragma unroll
        for (int half = 0; half < 2; ++half) {
            int px = p0 + (wv * 2 + half) * 16 + l15;
            if (px < THW) {
                #pragma unroll
                for (int oct = 0; oct < 8; ++oct) {
                    int ch = ocr + oct * 16 + quad * 4;
                    ushort4v v;
                    #pragma unroll
                    for (int r = 0; r < 4; ++r) v[r] = f2bf(acc[oct][half][r] * scale);
                    *(ushort4v*)&outbf[((size_t)b * THW + px) * 256 + ch] = v;
                }
            }
        }
    } else {
        #pragma unroll
        for (int half = 0; half < 2; ++half) {
            int px = p0 + (wv * 2 + half) * 16 + l15;
            if (px < THW) {
                int m = px / HW;
                int key = px - m * HW;
                size_t vbbase = (size_t)(b * 4 + m) * 256;
                #pragma unroll
                for (int oct = 0; oct < 8; ++oct) {
                    int ch = ocr + oct * 16 + quad * 4;
                    float4 fv = make_float4(acc[oct][half][0], acc[oct][half][1],
                                            acc[oct][half][2], acc[oct][half][3]);
                    *(float4*)&Vcl[((size_t)b * THW + px) * 256 + ch] = fv;
                    #pragma unroll
                    for (int r = 0; r < 4; ++r)
                        Vbf[(vbbase + ch + r) * VP + key] = f2bf(acc[oct][half][r]);
                }
            }
        }
    }
}

// ---------------- K3: flash attention, wave-owns-queries + register-prefetch ---
// grid (16, 61). Each wave owns 16 queries (Q in regs). M/V time-share one
// 32KB LDS region; M(kt+1)/V(kt+1) prefetched into REGISTERS right after the
// QK barrier (latency hides under softmax+PV), committed via ds_write in the
// phase where the region is dead. 4 barriers/iter. LDS 41KB.
// __launch_bounds__(256,2): VGPR cap 256 -> ~200-reg working set fits with
// ZERO spill (R3 post-mortem: (256,3) capped at ~170 and spilled prefetch
// arrays to scratch -> 830MB FETCH). 2 blocks/CU.
__global__ __launch_bounds__(256, 2) void k_attn_mfma(
    const unsigned short* __restrict__ Qbf, const unsigned short* __restrict__ Mbf,
    const unsigned short* __restrict__ Vbf, unsigned short* __restrict__ Rbf) {
    __shared__ unsigned short KV[16384] __attribute__((aligned(16)));  // 32KB M|V
    __shared__ unsigned short Ps[4096] __attribute__((aligned(16)));   // 8KB P
    __shared__ float alpha_s[64];
    __shared__ float l_s[64];

    const int bm = blockIdx.x;
    const int b = bm >> 2, m = bm & 3;
    const int q0 = blockIdx.y * 64;
    const int tid = threadIdx.x;
    const int wv = tid >> 6, lane = tid & 63;
    const int l15 = lane & 15, quad = lane >> 4;
    const int x7 = l15 & 7;

    const size_t mbase = ((size_t)b * THW + m * HW) * 256;
    const size_t vb = (size_t)bm * 256 * VP;

    // Q fragments in registers: this lane is column q = q0 + wv*16 + l15
    const int qg = min(q0 + wv * 16 + l15, THW - 1);
    const unsigned short* qp = Qbf + ((size_t)b * THW + qg) * 256 + quad * 8;
    ushort8 qreg[8];
    #pragma unroll
    for (int kci = 0; kci < 8; ++kci)
        qreg[kci] = *(const ushort8*)&qp[kci * 32];

    // prefetch M(0) into regs (tile 0 is always full: HW > 64)
    ushort8 mpre[8];
    #pragma unroll
    for (int it = 0; it < 8; ++it) {
        int v = it * 256 + tid;
        int key = v >> 5, ck = v & 31;
        mpre[it] = *(const ushort8*)&Mbf[mbase + (size_t)key * 256 + ck * 8];
    }
    // prefetch V(0) into regs
    ushort8 vpre[8];
    #pragma unroll
    for (int it = 0; it < 8; ++it) {
        int u = it * 256 + tid;
        int ch = u >> 3, k8 = (u & 7) << 3;
        vpre[it] = *(const ushort8*)&Vbf[vb + (size_t)ch * VP + k8];
    }

    floatx4 o[4][4];
    #pragma unroll
    for (int mt = 0; mt < 4; ++mt)
        #pragma unroll
        for (int nt = 0; nt < 4; ++nt) o[mt][nt] = (floatx4){0.f, 0.f, 0.f, 0.f};
    float m_run = -1e30f, l_run = 0.f;

    // commit M(0): KV[key][256ch], content chunk ck at slot ck^(key&7)
    #pragma unroll
    for (int it = 0; it < 8; ++it) {
        int v = it * 256 + tid;
        int key = v >> 5, ck = v & 31;
        *(ushort8*)&KV[key * 256 + ((ck ^ (key & 7)) << 3)] = mpre[it];
    }
    __syncthreads();   // M(0) visible

    for (int kt = 0; kt < 16; ++kt) {
        const int k0 = kt * 64;
        const int nv = min(64, HW - k0);
        // QK: C[key_local][q], A = M frags from LDS, B = Q regs
        floatx4 sc[4];
        #pragma unroll
        for (int kb = 0; kb < 4; ++kb) sc[kb] = (floatx4){0.f, 0.f, 0.f, 0.f};
        #pragma unroll
        for (int kb = 0; kb < 4; ++kb) {
            const int key = kb * 16 + l15;
            #pragma unroll
            for (int kci = 0; kci < 8; ++kci) {
                ushort8 mf = *(const ushort8*)&KV[key * 256 +
                    ((((kci << 2) + quad) ^ x7) << 3)];
                sc[kb] = __builtin_amdgcn_mfma_f32_16x16x32_bf16(
                    __builtin_bit_cast(bf16x8, mf),
                    __builtin_bit_cast(bf16x8, qreg[kci]), sc[kb], 0, 0, 0);
            }
        }
        __syncthreads();   // C: all M reads done
        // commit V(kt) from regs: KV[ch][64keys], chunk c at slot c^(ch&7)
        #pragma unroll
        for (int it = 0; it < 8; ++it) {
            int u = it * 256 + tid;
            int ch = u >> 3, k8 = (u & 7) << 3;
            *(ushort8*)&KV[ch * 64 + (((k8 >> 3) ^ (ch & 7)) << 3)] = vpre[it];
        }
        // prefetch M(kt+1) and V(kt+1) (fly during softmax + PV)
        if (kt < 15) {
            int k0n = k0 + 64;
            int nvn = min(64, HW - k0n);
            #pragma unroll
            for (int it = 0; it < 8; ++it) {
                int v = it * 256 + tid;
                int key = v >> 5, ck = v & 31;
                ushort8 val = {0, 0, 0, 0, 0, 0, 0, 0};
                if (key < nvn)
                    val = *(const ushort8*)&Mbf[mbase + (size_t)(k0n + key) * 256 + ck * 8];
                mpre[it] = val;
            }
            #pragma unroll
            for (int it = 0; it < 8; ++it) {
                int u = it * 256 + tid;
                int ch = u >> 3, k8 = (u & 7) << 3;
                vpre[it] = *(const ushort8*)&Vbf[vb + (size_t)ch * VP + k0n + k8];
            }
        }
        // wave-local softmax for q = l15 (keys spread over kb regs + quad lanes)
        #pragma unroll
        for (int kb = 0; kb < 4; ++kb) {
            #pragma unroll
            for (int r = 0; r < 4; ++r)
                if (kb * 16 + quad * 4 + r >= nv) sc[kb][r] = -1e30f;
        }
        float mx = -1e30f;
        #pragma unroll
        for (int kb = 0; kb < 4; ++kb)
            mx = fmaxf(mx, fmaxf(fmaxf(sc[kb][0], sc[kb][1]),
                                 fmaxf(sc[kb][2], sc[kb][3])));
        mx = fmaxf(mx, __shfl_xor(mx, 16));
        mx = fmaxf(mx, __shfl_xor(mx, 32));
        float m_new = fmaxf(m_run, mx);
        float al = __expf(m_run - m_new);
        float sm = 0.f;
        #pragma unroll
        for (int kb = 0; kb < 4; ++kb) {
            #pragma unroll
            for (int r = 0; r < 4; ++r) {
                float p = __expf(sc[kb][r] - m_new);
                sc[kb][r] = p;
                sm += p;
            }
        }
        sm += __shfl_xor(sm, 16);
        sm += __shfl_xor(sm, 32);
        l_run = l_run * al + sm;
        m_run = m_new;
        if (quad == 0) alpha_s[wv * 16 + l15] = al;
        // write P bf16 -> Ps[q][64keys] swizzled (4 keys packed per write)
        {
            const int prow = wv * 16 + l15;
            #pragma unroll
            for (int kb = 0; kb < 4; ++kb) {
                ushort4v pk;
                #pragma unroll
                for (int r = 0; r < 4; ++r) pk[r] = f2bf(sc[kb][r]);
                int cW = ((kb << 1) + (quad >> 1)) ^ x7;
                *(ushort4v*)&Ps[prow * 64 + (cW << 3) + ((quad & 1) << 2)] = pk;
            }
        }
        __syncthreads();   // D: V committed, Ps + alpha visible
        // rescale O, then PV (wave owns ch slice wv*64..+63, all 64 q)
        #pragma unroll
        for (int mt = 0; mt < 4; ++mt) {
            float alq[4];
            #pragma unroll
            for (int r = 0; r < 4; ++r) alq[r] = alpha_s[mt * 16 + quad * 4 + r];
            #pragma unroll
            for (int nt = 0; nt < 4; ++nt)
                #pragma unroll
                for (int r = 0; r < 4; ++r) o[mt][nt][r] *= alq[r];
        }
        #pragma unroll
        for (int ks = 0; ks < 2; ++ks) {
            ushort8 af[4];
            #pragma unroll
            for (int mt = 0; mt < 4; ++mt)
                af[mt] = *(const ushort8*)&Ps[(mt * 16 + l15) * 64 +
                    ((((ks << 2) + quad) ^ x7) << 3)];
            #pragma unroll
            for (int nt = 0; nt < 4; ++nt) {
                int ch = wv * 64 + nt * 16 + l15;
                ushort8 bv = *(const ushort8*)&KV[ch * 64 +
                    ((((ks << 2) + quad) ^ x7) << 3)];
                #pragma unroll
                for (int mt = 0; mt < 4; ++mt)
                    o[mt][nt] = __builtin_amdgcn_mfma_f32_16x16x32_bf16(
                        __builtin_bit_cast(bf16x8, af[mt]),
                        __builtin_bit_cast(bf16x8, bv), o[mt][nt], 0, 0, 0);
            }
        }
        __syncthreads();   // E: all V/Ps reads done
        if (kt < 15) {
            // commit M(kt+1)
            #pragma unroll
            for (int it = 0; it < 8; ++it) {
                int v = it * 256 + tid;
                int key = v >> 5, ck = v & 31;
                *(ushort8*)&KV[key * 256 + ((ck ^ (key & 7)) << 3)] = mpre[it];
            }
        }
        __syncthreads();   // F: M(kt+1) visible
    }
    if (quad == 0) l_s[wv * 16 + l15] = l_run;
    __syncthreads();
    // normalize + stage O (bf16) into KV as [q_local][256ch]
    #pragma unroll
    for (int mt = 0; mt < 4; ++mt) {
        float invl[4];
        #pragma unroll
        for (int r = 0; r < 4; ++r) invl[r] = 1.f / l_s[mt * 16 + quad * 4 + r];
        #pragma unroll
        for (int nt = 0; nt < 4; ++nt) {
            int ch = wv * 64 + nt * 16 + l15;
            #pragma unroll
            for (int r = 0; r < 4; ++r) {
                int qrow = mt * 16 + quad * 4 + r;
                KV[qrow * 256 + ch] = f2bf(o[mt][nt][r] * invl[r]);
            }
        }
    }
    __syncthreads();
    // coalesced nontemporal store: 8 chunks/thread, 16B/lane
    #pragma unroll
    for (int k = 0; k < 8; ++k) {
        int idx = k * 256 + tid;
        int qrow = idx >> 5, c = idx & 31;
        int q = q0 + qrow;
        if (q < THW) {
            ushort8 v = *(const ushort8*)&KV[qrow * 256 + c * 8];
            __builtin_nontemporal_store(v,
                (ushort8*)&Rbf[((size_t)bm * THW + q) * 256 + c * 8]);
        }
    }
}

// ---------------- K5: compare convs via MFMA (R now bf16) ----------------
__global__ __launch_bounds__(256) void k_cmp(
    const unsigned short* __restrict__ Rbf, const float* __restrict__ Vcl,
    const unsigned short* __restrict__ Wpk, float* __restrict__ Pc) {
    __shared__ unsigned short Ws[24576] __attribute__((aligned(16)));  // 48 KB
    const int strip = blockIdx.x;
    const int s = blockIdx.y;
    const int b = blockIdx.z >> 1, kind = blockIdx.z & 1;
    const int m = s >> 2, tq = s & 3;
    const int tid = threadIdx.x;
    const int wv = tid >> 6, lane = tid & 63;
    const int l15 = lane & 15, quad = lane >> 4;

    const unsigned short* wsrc = Wpk + (kind ? 24576 : 0);
    for (int i = tid; i < 3072; i += 256) {
        int row, ch, stride_us;
        if (kind == 0) { row = i >> 6; ch = i & 63; stride_us = 512; }
        else           { row = i >> 5; ch = i & 31; stride_us = 256; }
        ushort8 v = *(const ushort8*)&wsrc[i * 8];
        *(ushort8*)&Ws[row * stride_us + ((ch ^ (row & 7)) << 3)] = v;
    }
    __syncthreads();

    const size_t rbase = ((size_t)(b * 4 + m) * THW + tq * HW) * 256;
    const size_t vbase = ((size_t)b * THW + m * HW) * 256;

    #pragma unroll
    for (int half = 0; half < 2; ++half) {
        int pxt = wv * 2 + half;
        int hw = strip * 128 + pxt * 16 + l15;
        int hwc = min(hw, HW - 1);
        const unsigned short* rrow = Rbf + rbase + (size_t)hwc * 256;
        const float* vrow = Vcl + vbase + (size_t)hwc * 256;
        bf16x8 fr[8], fs[8];   // kind0: R,V ; kind1: D,P
        #pragma unroll
        for (int ks = 0; ks < 8; ++ks) {
            ushort8 r8 = *(const ushort8*)&rrow[ks * 32 + quad * 8];
            float vv[8];
            *(float4*)&vv[0] = *(const float4*)&vrow[ks * 32 + quad * 8];
            *(float4*)&vv[4] = *(const float4*)&vrow[ks * 32 + quad * 8 + 4];
            bf16x8 a, c;
            if (kind == 0) {
                a = __builtin_bit_cast(bf16x8, r8);
                #pragma unroll
                for (int j = 0; j < 8; ++j) c[j] = (__bf16)vv[j];
            } else {
                #pragma unroll
                for (int j = 0; j < 8; ++j) {
                    float rj = bf2f(r8[j]);
                    a[j] = (__bf16)(rj - vv[j]);
                    c[j] = (__bf16)(rj * vv[j]);
                }
            }
            fr[ks] = a; fs[ks] = c;
        }
        floatx4 acc[6];
        #pragma unroll
        for (int i = 0; i < 6; ++i) acc[i] = (floatx4){0.f, 0.f, 0.f, 0.f};
        if (kind == 0) {
            #pragma unroll
            for (int ks = 0; ks < 16; ++ks) {
                bf16x8 bfr = (ks < 8) ? fr[ks] : fs[ks - 8];
                #pragma unroll
                for (int cit = 0; cit < 3; ++cit) {
                    int row = cit * 16 + l15;
                    ushort8 aw = *(const ushort8*)&Ws[row * 512 + (((ks * 4 + quad) ^ (row & 7)) << 3)];
                    acc[cit] = __builtin_amdgcn_mfma_f32_16x16x32_bf16(
                        __builtin_bit_cast(bf16x8, aw), bfr, acc[cit], 0, 0, 0);
                }
            }
        } else {
            #pragma unroll
            for (int ks = 0; ks < 8; ++ks) {
                #pragma unroll
                for (int cit = 0; cit < 6; ++cit) {
                    int row = cit * 16 + l15;
                    ushort8 aw = *(const ushort8*)&Ws[row * 256 + (((ks * 4 + quad) ^ (row & 7)) << 3)];
                    bf16x8 bfr = (cit < 3) ? fr[ks] : fs[ks];
                    acc[cit] = __builtin_amdgcn_mfma_f32_16x16x32_bf16(
                        __builtin_bit_cast(bf16x8, aw), bfr, acc[cit], 0, 0, 0);
                }
            }
        }
        if (hw < HW) {
            if (kind == 0) {
                #pragma unroll
                for (int cit = 0; cit < 3; ++cit)
                    #pragma unroll
                    for (int r = 0; r < 4; ++r) {
                        int ci = cit * 16 + quad * 4 + r;
                        if (ci < 42)
                            Pc[((size_t)(b * NCMP + ci) * 16 + s) * HW + hw] = acc[cit][r];
                    }
            } else {
                #pragma unroll
                for (int cit = 0; cit < 6; ++cit)
                    #pragma unroll
                    for (int r = 0; r < 4; ++r) {
                        int cl = (cit % 3) * 16 + quad * 4 + r;
                        if (cl < 42) {
                            int ci = (cit < 3 ? 42 : 84) + cl;
                            Pc[((size_t)(b * NCMP + ci) * 16 + s) * HW + hw] = acc[cit][r];
                        }
                    }
            }
        }
    }
}

// ---------------- K6: BN stats for compare ----------------
__global__ __launch_bounds__(256) void k_stats_cmp(
    const float* __restrict__ Pc, const float* __restrict__ g_cat,
    const float* __restrict__ b_cat, const float* __restrict__ g_sub,
    const float* __restrict__ b_sub, const float* __restrict__ g_mul,
    const float* __restrict__ b_mul, float* __restrict__ bnc) {
    const int c = blockIdx.x, tid = threadIdx.x;
    float s = 0.f, q = 0.f;
    for (int i = tid; i < 4 * 16 * HW; i += 256) {
        int bb = i / (16 * HW), r = i - bb * (16 * HW);
        float v = Pc[(size_t)(bb * NCMP + c) * (16 * HW) + r];
        s += v; q += v * v;
    }
    __shared__ float rs[256], rq[256];
    rs[tid] = s; rq[tid] = q;
    __syncthreads();
    for (int off = 128; off > 0; off >>= 1) {
        if (tid < off) { rs[tid] += rs[tid + off]; rq[tid] += rq[tid + off]; }
        __syncthreads();
    }
    if (tid == 0) {
        const float n = 4.f * 16.f * HW;
        float mean = rs[0] / n;
        float var = rq[0] / n - mean * mean;
        float g, bt;
        if (c < 42)       { g = g_cat[c];      bt = b_cat[c]; }
        else if (c < 84)  { g = g_sub[c - 42]; bt = b_sub[c - 42]; }
        else              { g = g_mul[c - 84]; bt = b_mul[c - 84]; }
        float sc = g * rsqrtf(var + BN_EPS);
        bnc[c] = sc;
        bnc[NCMP + c] = bt - mean * sc;
    }
}

// ---------------- K7: build Y channel-last bf16 [b][p][1024] ----------------
__global__ __launch_bounds__(256) void k_build_y(
    const unsigned short* __restrict__ Rbf, const float* __restrict__ Vcl,
    const float* __restrict__ Pc, const float* __restrict__ bnc,
    unsigned short* __restrict__ Ybf) {
    const int strip = blockIdx.x, t = blockIdx.y, b = blockIdx.z;
    const int tid = threadIdx.x;
    const int chl = tid & 31;
    const int hwl = tid >> 5;
    for (int pass = 0; pass < 8; ++pass) {
        int hw = strip * 64 + pass * 8 + hwl;
        if (hw >= HW) continue;
        size_t ybase = ((size_t)b * THW + t * HW + hw) * 1024;
        for (int cb = 0; cb < 8; ++cb) {
            int ch = cb * 128 + chl * 4;
            float v[4];
            if (ch < 256) {
                v[0] = v[1] = v[2] = v[3] = 0.f;
                #pragma unroll
                for (int tq = 0; tq < 4; ++tq) {
                    ushort4v rv = *(const ushort4v*)&Rbf[
                        (((size_t)(b * 4 + t)) * THW + tq * HW + hw) * 256 + ch];
                    v[0] += bf2f(rv[0]); v[1] += bf2f(rv[1]);
                    v[2] += bf2f(rv[2]); v[3] += bf2f(rv[3]);
                }
                v[0] *= 0.25f; v[1] *= 0.25f; v[2] *= 0.25f; v[3] *= 0.25f;
            } else if (ch < 512) {
                float4 vv = *(const float4*)&Vcl[((size_t)b * THW + t * HW + hw) * 256 + (ch - 256)];
                v[0] = vv.x; v[1] = vv.y; v[2] = vv.z; v[3] = vv.w;
            } else if (ch < 1016) {
                int ci = (ch - 512) >> 2;
                float sc = bnc[ci], sh = bnc[NCMP + ci];
                #pragma unroll
                for (int mm = 0; mm < 4; ++mm) {
                    float pv = Pc[(((size_t)(b * NCMP + ci)) * 16 + mm * 4 + t) * HW + hw];
                    v[mm] = fmaxf(fmaf(pv, sc, sh), 0.f);
                }
            } else {
                v[0] = v[1] = v[2] = v[3] = 0.f;
            }
            ushort4v ov;
            #pragma unroll
            for (int i = 0; i < 4; ++i) ov[i] = f2bf(v[i]);
            *(ushort4v*)&Ybf[ybase + ch] = ov;
        }
    }
}

// ---------------- K8: aggregate GEMM via MFMA ----------------
__global__ __launch_bounds__(256) void k_aggm(
    const unsigned short* __restrict__ Wab, const unsigned short* __restrict__ Ybf,
    float* __restrict__ Z) {
    __shared__ unsigned short Wt[16384] __attribute__((aligned(16)));
    const int p0 = blockIdx.x * 128;
    const int oc0 = blockIdx.y * 128;
    const int b = blockIdx.z;
    const int tid = threadIdx.x;
    const int wv = tid >> 6, lane = tid & 63;
    const int l15 = lane & 15, quad = lane >> 4;
    floatx4 acc[8][2];
    #pragma unroll
    for (int i = 0; i < 8; ++i)
        #pragma unroll
        for (int h = 0; h < 2; ++h) acc[i][h] = (floatx4){0.f, 0.f, 0.f, 0.f};
    for (int kc = 0; kc < 8; ++kc) {
        __syncthreads();
        for (int i = tid; i < 2048; i += 256) {
            int row = i >> 4, ch = i & 15;
            ushort8 v = *(const ushort8*)&Wab[(size_t)(oc0 + row) * 1024 + kc * 128 + ch * 8];
            *(ushort8*)&Wt[row * 128 + ((ch ^ (row & 7)) << 3)] = v;
        }
        __syncthreads();
        #pragma unroll
        for (int half = 0; half < 2; ++half) {
            int px = p0 + (wv * 2 + half) * 16 + l15;
            int pxc = min(px, THW - 1);
            const unsigned short* yrow = Ybf + ((size_t)b * THW + pxc) * 1024 + kc * 128;
            #pragma unroll
            for (int ks = 0; ks < 4; ++ks) {
                ushort8 bf = *(const ushort8*)&yrow[ks * 32 + quad * 8];
                #pragma unroll
                for (int oct = 0; oct < 8; ++oct) {
                    int row = oct * 16 + l15;
                    ushort8 af = *(const ushort8*)&Wt[row * 128 + ((((ks * 4 + quad) ^ (row & 7))) << 3)];
                    acc[oct][half] = __builtin_amdgcn_mfma_f32_16x16x32_bf16(
                        __builtin_bit_cast(bf16x8, af),
                        __builtin_bit_cast(bf16x8, bf), acc[oct][half], 0, 0, 0);
                }
            }
        }
    }
    #pragma unroll
    for (int half = 0; half < 2; ++half) {
        int px = p0 + (wv * 2 + half) * 16 + l15;
        if (px < THW) {
            #pragma unroll
            for (int oct = 0; oct < 8; ++oct) {
                int oc = oc0 + oct * 16 + quad * 4;
                #pragma unroll
                for (int r = 0; r < 4; ++r)
                    Z[((size_t)(b * Cch + oc + r)) * THW + px] = acc[oct][half][r];
            }
        }
    }
}

// ---------------- K9: BN stats for aggregate ----------------
__global__ __launch_bounds__(256) void k_stats_agg(
    const float* __restrict__ Z, const float* __restrict__ g_agg,
    const float* __restrict__ b_agg, float* __restrict__ bna) {
    const int c = blockIdx.x, tid = threadIdx.x;
    float s = 0.f, q = 0.f;
    for (int i = tid; i < 4 * THW; i += 256) {
        int bb = i / THW, p = i - bb * THW;
        float v = Z[((size_t)bb * Cch + c) * THW + p];
        s += v; q += v * v;
    }
    __shared__ float rs[256], rq[256];
    rs[tid] = s; rq[tid] = q;
    __syncthreads();
    for (int off = 128; off > 0; off >>= 1) {
        if (tid < off) { rs[tid] += rs[tid + off]; rq[tid] += rq[tid + off]; }
        __syncthreads();
    }
    if (tid == 0) {
        const float n = 4.f * THW;
        float mean = rs[0] / n;
        float var = rq[0] / n - mean * mean;
        float sc = g_agg[c] * rsqrtf(var + BN_EPS);
        bna[c] = sc;
        bna[Cch + c] = b_agg[c] - mean * sc;
    }
}

// ---------------- K10: out = relu(xp + BN(Z)) ----------------
__global__ __launch_bounds__(256) void k_final(const float* __restrict__ xp,
                                               const float* __restrict__ Z,
                                               const float* __restrict__ bna,
                                               float* __restrict__ out) {
    int idx = blockIdx.x * 256 + threadIdx.x;
    if (idx >= NPIX) return;
    int c = (idx / THW) & 511;
    out[idx] = fmaxf(fmaf(Z[idx], bna[c], bna[Cch + c]) + xp[idx], 0.f);
}

extern "C" void kernel_launch(void* const* d_in, const int* in_sizes, int n_in,
                              void* d_out, int out_size, void* d_ws, size_t ws_size,
                              hipStream_t stream) {
    const float* x     = (const float*)d_in[0];
    const float* Wq    = (const float*)d_in[1];
    const float* Wm    = (const float*)d_in[2];
    const float* Wv    = (const float*)d_in[3];
    const float* Wcat  = (const float*)d_in[4];
    const float* Wsub  = (const float*)d_in[5];
    const float* Wmul  = (const float*)d_in[6];
    const float* g_cat = (const float*)d_in[7];
    const float* b_cat = (const float*)d_in[8];
    const float* g_sub = (const float*)d_in[9];
    const float* b_sub = (const float*)d_in[10];
    const float* g_mul = (const float*)d_in[11];
    const float* b_mul = (const float*)d_in[12];
    const float* Wagg  = (const float*)d_in[13];
    const float* g_agg = (const float*)d_in[14];
    const float* b_agg = (const float*)d_in[15];
    float* out = (float*)d_out;
    float* ws  = (float*)d_ws;

    // workspace layout (float offsets); total 35,714,560 fl = 142.9 MB
    float* xp  = ws;                          // 7,872,512
    float* Vcl = xp + 7872512;                // 3,936,256  -> 11,808,768
    float* bnc = Vcl + 3936256;               // 512        -> 11,809,280
    float* bna = bnc + 512;                   // 1024       -> 11,810,304
    unsigned short* Wpk = (unsigned short*)(bna + 1024);   // 49,152 us = 24,576 fl
    unsigned short* Wab = Wpk + 49152;                     // 524,288 us = 262,144 fl
    float* bfreg = (float*)(Wab + 524288);    // 7,872,512 fl -> Qbf/Mbf/Vbf; later Ybf
    unsigned short* Qbf = (unsigned short*)bfreg;          // 3,936,256 us
    unsigned short* Mbf = Qbf + 3936256;                   // 3,936,256 us
    unsigned short* Vbf = Mbf + 3936256;                   // 4,194,304 us
    unsigned short* Ybf = (unsigned short*)bfreg;          // alias (Q/M/V dead)
    unsigned short* Rbf = (unsigned short*)(bfreg + 7872512);  // 15,745,024 us = 7,872,512 fl
    float* Pc = (float*)(Rbf + 15745024);     // 7,750,656 fl (+121,856 pad for Z tail)
    float* Z  = (float*)Rbf;                  // alias: Rbf+Pc dead after build_y
    // Xh/Xl (split-bf16 channel-last xp) alias the Rbf region: live only
    // between k_xpose and k_qmv_mfma; k_attn overwrites Rbf afterwards.
    unsigned short* Xh = Rbf;                 // 7,872,512 us
    unsigned short* Xl = Xh + 7872512;        // 7,872,512 us (fills Rbf region exactly)

    k_prep_w<<<dim3(3248), dim3(256), 0, stream>>>(Wcat, Wsub, Wmul, Wagg, Wpk, Wab, Vbf);
    k_pool<<<dim3((NPIX + 255) / 256), dim3(256), 0, stream>>>(x, xp);
    k_xpose<<<dim3(61, 8, Bb), dim3(256), 0, stream>>>(xp, Xh, Xl);
    k_qmv_mfma<<<dim3(31, 6, Bb), dim3(256), 0, stream>>>(Xh, Xl, Wq, Wm, Wv,
                                                          Qbf, Mbf, Vcl, Vbf);
    k_attn_mfma<<<dim3(16, 61), dim3(256), 0, stream>>>(Qbf, Mbf, Vbf, Rbf);
    k_cmp<<<dim3(8, 16, 8), dim3(256), 0, stream>>>(Rbf, Vcl, Wpk, Pc);
    k_stats_cmp<<<dim3(NCMP), dim3(256), 0, stream>>>(Pc, g_cat, b_cat, g_sub, b_sub,
                                                      g_mul, b_mul, bnc);
    k_build_y<<<dim3(16, 4, Bb), dim3(256), 0, stream>>>(Rbf, Vcl, Pc, bnc, Ybf);
    k_aggm<<<dim3(31, 4, Bb), dim3(256), 0, stream>>>(Wab, Ybf, Z);
    k_stats_agg<<<dim3(Cch), dim3(256), 0, stream>>>(Z, g_agg, b_agg, bna);
    k_final<<<dim3((NPIX + 255) / 256), dim3(256), 0, stream>>>(xp, Z, bna, out);
}

// Round 6
// 702.374 us; speedup vs baseline: 1.6019x; 1.0440x over previous
//
#include <hip/hip_runtime.h>
#include <math.h>

// Problem dims
constexpr int Bb   = 4;
constexpr int Cch  = 512;
constexpr int HW   = 961;      // 31*31
constexpr int THW  = 3844;     // 4*961
constexpr int NCMP = 126;      // 3*42 compare channels
constexpr int NPIX = Bb * Cch * THW;  // 7,872,512
constexpr int Hp = 31, Wp = 31, H0c = 63, W0c = 63;
constexpr int VP = 1024;       // padded keys/frame for Vbf
#define BN_EPS 1e-5f

typedef __attribute__((ext_vector_type(4))) float floatx4;
typedef __attribute__((ext_vector_type(8))) __bf16 bf16x8;
typedef __attribute__((ext_vector_type(8))) unsigned short ushort8;
typedef __attribute__((ext_vector_type(4))) unsigned short ushort4v;

static __device__ __forceinline__ unsigned short f2bf(float x) {
    unsigned int u = __builtin_bit_cast(unsigned int, x);
    u += 0x7fff + ((u >> 16) & 1);   // RNE
    return (unsigned short)(u >> 16);
}
static __device__ __forceinline__ float bf2f(unsigned short u) {
    return __builtin_bit_cast(float, ((unsigned int)u) << 16);
}

// ---------------- K0: pack weights to bf16 (+ zero Vbf key pad) ----------------
__global__ __launch_bounds__(256) void k_prep_w(
    const float* __restrict__ Wcat, const float* __restrict__ Wsub,
    const float* __restrict__ Wmul, const float* __restrict__ Wagg,
    unsigned short* __restrict__ Wpk, unsigned short* __restrict__ Wab,
    unsigned short* __restrict__ Vbf) {
    int idx = blockIdx.x * 256 + threadIdx.x;
    if (idx < 24576) {                       // cat
        int row = idx >> 9, k = idx & 511;
        Wpk[idx] = (row < 42) ? f2bf(Wcat[row * 512 + k]) : 0;
    } else if (idx < 36864) {                // sub
        int i = idx - 24576;
        int row = i >> 8, k = i & 255;
        Wpk[idx] = (row < 42) ? f2bf(Wsub[row * 256 + k]) : 0;
    } else if (idx < 49152) {                // mul
        int i = idx - 36864;
        int row = i >> 8, k = i & 255;
        Wpk[idx] = (row < 42) ? f2bf(Wmul[row * 256 + k]) : 0;
    } else if (idx < 49152 + 524288) {       // agg
        int i = idx - 49152;
        int row = i >> 10, k = i & 1023;
        Wab[i] = (k < 1016) ? f2bf(Wagg[(size_t)row * 1016 + k]) : 0;
    } else if (idx < 573440 + 258048) {      // Vbf pad keys [961,1024) := 0
        int i = idx - 573440;
        int row = i / 63, k = i - row * 63;  // row < 4096 = 16bm*256ch
        Vbf[(size_t)row * VP + 961 + k] = 0;
    }
}

// ---------------- K1: maxpool (1,3,3)/(1,2,2) ----------------
__global__ __launch_bounds__(256) void k_pool(const float* __restrict__ x,
                                              float* __restrict__ xp) {
    int idx = blockIdx.x * 256 + threadIdx.x;
    if (idx >= NPIX) return;
    int w = idx % Wp;
    int h = (idx / Wp) % Hp;
    int bct = idx / HW;
    const float* src = x + (size_t)bct * (H0c * W0c) + (2 * h) * W0c + 2 * w;
    float m = -INFINITY;
    #pragma unroll
    for (int i = 0; i < 3; ++i) {
        m = fmaxf(m, src[i * W0c + 0]);
        m = fmaxf(m, src[i * W0c + 1]);
        m = fmaxf(m, src[i * W0c + 2]);
    }
    xp[idx] = m;
}

// ---------------- K1b: transpose xp -> channel-last bf16 hi/lo split ----------------
// xp [b][512][THW] fp32  ->  Xh/Xl [b][THW][512] bf16 (hi + residual-lo)
__global__ __launch_bounds__(256) void k_xpose(const float* __restrict__ xp,
                                               unsigned short* __restrict__ Xh,
                                               unsigned short* __restrict__ Xl) {
    __shared__ float T[64][65];   // +1 pad: conflict-free column reads
    const int p0 = blockIdx.x * 64;
    const int c0 = blockIdx.y * 64;
    const int b  = blockIdx.z;
    const int tid = threadIdx.x;
    // load 64c x 64px, float4 along px (coalesced)
    {
        int px4 = (tid & 15) * 4;
        int cb = tid >> 4;          // 0..15
        #pragma unroll
        for (int i = 0; i < 4; ++i) {
            int c = cb + i * 16;
            int p = p0 + px4;
            const float* src = xp + ((size_t)(b * Cch + c0 + c)) * THW + p;
            float4 v;
            if (p + 3 < THW) {
                v = *(const float4*)src;
            } else {
                v.x = (p     < THW) ? src[0] : 0.f;
                v.y = (p + 1 < THW) ? src[1] : 0.f;
                v.z = (p + 2 < THW) ? src[2] : 0.f;
                v.w = (p + 3 < THW) ? src[3] : 0.f;
            }
            T[c][px4] = v.x; T[c][px4 + 1] = v.y;
            T[c][px4 + 2] = v.z; T[c][px4 + 3] = v.w;
        }
    }
    __syncthreads();
    {
        int px = tid >> 2;
        int cs = (tid & 3) * 16;
        int p = p0 + px;
        if (p < THW) {
            ushort8 hi[2], lo[2];
            #pragma unroll
            for (int j = 0; j < 16; ++j) {
                float v = T[cs + j][px];
                unsigned short h = f2bf(v);
                hi[j >> 3][j & 7] = h;
                lo[j >> 3][j & 7] = f2bf(v - bf2f(h));
            }
            size_t base = ((size_t)b * THW + p) * 512 + c0 + cs;
            *(ushort8*)&Xh[base]     = hi[0];
            *(ushort8*)&Xh[base + 8] = hi[1];
            *(ushort8*)&Xl[base]     = lo[0];
            *(ushort8*)&Xl[base + 8] = lo[1];
        }
    }
}

// ---------------- K2: Q/M/V projections via split-bf16 MFMA ----------------
// grid (31 px-tiles, 6 oc-tiles, B). BM=128 oc, BN=128 px, K-step 64.
// acc = Whi*Xhi + Whi*Xlo + Wlo*Xhi  (~fp32 accuracy, 3x bf16 MFMA rate)
__global__ __launch_bounds__(256) void k_qmv_mfma(
    const unsigned short* __restrict__ Xh, const unsigned short* __restrict__ Xl,
    const float* __restrict__ Wq, const float* __restrict__ Wm,
    const float* __restrict__ Wv,
    unsigned short* __restrict__ Qbf, unsigned short* __restrict__ Mbf,
    float* __restrict__ Vcl, unsigned short* __restrict__ Vbf) {
    __shared__ unsigned short Whs[128 * 64] __attribute__((aligned(16)));
    __shared__ unsigned short Wls[128 * 64] __attribute__((aligned(16)));
    const int p0  = blockIdx.x * 128;
    const int sel = blockIdx.y >> 1;            // 0:Q 1:M 2:V
    const int ocr = (blockIdx.y & 1) * 128;     // row offset within the 256-row matrix
    const int b   = blockIdx.z;
    const float* Wbase = ((sel == 0) ? Wq : (sel == 1) ? Wm : Wv) + (size_t)ocr * 512;
    const int tid = threadIdx.x;
    const int wv = tid >> 6, lane = tid & 63;
    const int l15 = lane & 15, quad = lane >> 4;

    floatx4 acc[8][2];
    #pragma unroll
    for (int i = 0; i < 8; ++i)
        #pragma unroll
        for (int h = 0; h < 2; ++h) acc[i][h] = (floatx4){0.f, 0.f, 0.f, 0.f};

    for (int kc = 0; kc < 512; kc += 64) {
        __syncthreads();
        // stage W tile [128oc][64k] hi+lo, XOR chunk swizzle (conflict-free b128)
        #pragma unroll
        for (int i = 0; i < 4; ++i) {
            int t = i * 256 + tid;              // 0..1023
            int row = t >> 3, c8 = t & 7;       // row 0..127, chunk 0..7
            const float* wr = Wbase + (size_t)row * 512 + kc + c8 * 8;
            float v[8];
            *(float4*)&v[0] = *(const float4*)wr;
            *(float4*)&v[4] = *(const float4*)(wr + 4);
            ushort8 hi, lo;
            #pragma unroll
            for (int j = 0; j < 8; ++j) {
                unsigned short h = f2bf(v[j]);
                hi[j] = h;
                lo[j] = f2bf(v[j] - bf2f(h));
            }
            int addr = row * 64 + ((c8 ^ (row & 7)) << 3);
            *(ushort8*)&Whs[addr] = hi;
            *(ushort8*)&Wls[addr] = lo;
        }
        __syncthreads();
        #pragma unroll
        for (int half = 0; half < 2; ++half) {
            int px = p0 + (wv * 2 + half) * 16 + l15;
            int pxc = min(px, THW - 1);
            const unsigned short* xh = Xh + ((size_t)b * THW + pxc) * 512 + kc;
            const unsigned short* xl = Xl + ((size_t)b * THW + pxc) * 512 + kc;
            #pragma unroll
            for (int ks = 0; ks < 2; ++ks) {
                ushort8 bh = *(const ushort8*)&xh[ks * 32 + quad * 8];
                ushort8 bl = *(const ushort8*)&xl[ks * 32 + quad * 8];
                #pragma unroll
                for (int oct = 0; oct < 8; ++oct) {
                    int row = oct * 16 + l15;
                    int ca = row * 64 + (((ks * 4 + quad) ^ (row & 7)) << 3);
                    ushort8 ah = *(const ushort8*)&Whs[ca];
                    ushort8 al = *(const ushort8*)&Wls[ca];
                    acc[oct][half] = __builtin_amdgcn_mfma_f32_16x16x32_bf16(
                        __builtin_bit_cast(bf16x8, ah),
                        __builtin_bit_cast(bf16x8, bh), acc[oct][half], 0, 0, 0);
                    acc[oct][half] = __builtin_amdgcn_mfma_f32_16x16x32_bf16(
                        __builtin_bit_cast(bf16x8, ah),
                        __builtin_bit_cast(bf16x8, bl), acc[oct][half], 0, 0, 0);
                    acc[oct][half] = __builtin_amdgcn_mfma_f32_16x16x32_bf16(
                        __builtin_bit_cast(bf16x8, al),
                        __builtin_bit_cast(bf16x8, bh), acc[oct][half], 0, 0, 0);
                }
            }
        }
    }
    // epilogue: C row = ocr+oct*16+quad*4+r, col px = p0+(wv*2+half)*16+l15
    if (sel < 2) {
        unsigned short* outbf = sel ? Mbf : Qbf;
        const float scale = sel ? 1.0f : 0.0625f;
        #pragma unroll
        for (int half = 0; half < 2; ++half) {
            int px = p0 + (wv * 2 + half) * 16 + l15;
            if (px < THW) {
                #pragma unroll
                for (int oct = 0; oct < 8; ++oct) {
                    int ch = ocr + oct * 16 + quad * 4;
                    ushort4v v;
                    #pragma unroll
                    for (int r = 0; r < 4; ++r) v[r] = f2bf(acc[oct][half][r] * scale);
                    *(ushort4v*)&outbf[((size_t)b * THW + px) * 256 + ch] = v;
                }
            }
        }
    } else {
        #pragma unroll
        for (int half = 0; half < 2; ++half) {
            int px = p0 + (wv * 2 + half) * 16 + l15;
            if (px < THW) {
                int m = px / HW;
                int key = px - m * HW;
                size_t vbbase = (size_t)(b * 4 + m) * 256;
                #pragma unroll
                for (int oct = 0; oct < 8; ++oct) {
                    int ch = ocr + oct * 16 + quad * 4;
                    float4 fv = make_float4(acc[oct][half][0], acc[oct][half][1],
                                            acc[oct][half][2], acc[oct][half][3]);
                    *(float4*)&Vcl[((size_t)b * THW + px) * 256 + ch] = fv;
                    #pragma unroll
                    for (int r = 0; r < 4; ++r)
                        Vbf[(vbbase + ch + r) * VP + key] = f2bf(acc[oct][half][r]);
                }
            }
        }
    }
}

// ---------------- K3: flash attention, wave-owns-queries + register-prefetch ---
// grid (16, 61). Each wave owns 16 queries (Q in regs). M/V time-share one
// 32KB LDS region; M(kt+1)/V(kt+1) prefetched into REGISTERS right after the
// QK barrier (latency hides under softmax+PV), committed via ds_write in the
// phase where the region is dead. 4 barriers/iter. LDS 41KB.
// __launch_bounds__(256,1): unified VGPR+AGPR cap 512. Working set ~230
// unified regs (o=64 AGPR + qreg/mpre/vpre=96 + addressing) -> zero spill,
// and floor(512/~230)=2 waves/SIMD — same occupancy as (256,2) which
// silently capped the UNIFIED file at 256 and spilled (R5: VGPR=128 + 64
// AGPR, ~60MB residual scratch traffic).
__global__ __launch_bounds__(256, 1) void k_attn_mfma(
    const unsigned short* __restrict__ Qbf, const unsigned short* __restrict__ Mbf,
    const unsigned short* __restrict__ Vbf, unsigned short* __restrict__ Rbf) {
    __shared__ unsigned short KV[16384] __attribute__((aligned(16)));  // 32KB M|V
    __shared__ unsigned short Ps[4096] __attribute__((aligned(16)));   // 8KB P
    __shared__ float alpha_s[64];
    __shared__ float l_s[64];

    const int bm = blockIdx.x;
    const int b = bm >> 2, m = bm & 3;
    const int q0 = blockIdx.y * 64;
    const int tid = threadIdx.x;
    const int wv = tid >> 6, lane = tid & 63;
    const int l15 = lane & 15, quad = lane >> 4;
    const int x7 = l15 & 7;

    const size_t mbase = ((size_t)b * THW + m * HW) * 256;
    const size_t vb = (size_t)bm * 256 * VP;

    // Q fragments in registers: this lane is column q = q0 + wv*16 + l15
    const int qg = min(q0 + wv * 16 + l15, THW - 1);
    const unsigned short* qp = Qbf + ((size_t)b * THW + qg) * 256 + quad * 8;
    ushort8 qreg[8];
    #pragma unroll
    for (int kci = 0; kci < 8; ++kci)
        qreg[kci] = *(const ushort8*)&qp[kci * 32];

    // prefetch M(0) into regs (tile 0 is always full: HW > 64)
    ushort8 mpre[8];
    #pragma unroll
    for (int it = 0; it < 8; ++it) {
        int v = it * 256 + tid;
        int key = v >> 5, ck = v & 31;
        mpre[it] = *(const ushort8*)&Mbf[mbase + (size_t)key * 256 + ck * 8];
    }
    // prefetch V(0) into regs
    ushort8 vpre[8];
    #pragma unroll
    for (int it = 0; it < 8; ++it) {
        int u = it * 256 + tid;
        int ch = u >> 3, k8 = (u & 7) << 3;
        vpre[it] = *(const ushort8*)&Vbf[vb + (size_t)ch * VP + k8];
    }

    floatx4 o[4][4];
    #pragma unroll
    for (int mt = 0; mt < 4; ++mt)
        #pragma unroll
        for (int nt = 0; nt < 4; ++nt) o[mt][nt] = (floatx4){0.f, 0.f, 0.f, 0.f};
    float m_run = -1e30f, l_run = 0.f;

    // commit M(0): KV[key][256ch], content chunk ck at slot ck^(key&7)
    #pragma unroll
    for (int it = 0; it < 8; ++it) {
        int v = it * 256 + tid;
        int key = v >> 5, ck = v & 31;
        *(ushort8*)&KV[key * 256 + ((ck ^ (key & 7)) << 3)] = mpre[it];
    }
    __syncthreads();   // M(0) visible

    for (int kt = 0; kt < 16; ++kt) {
        const int k0 = kt * 64;
        const int nv = min(64, HW - k0);
        // QK: C[key_local][q], A = M frags from LDS, B = Q regs
        floatx4 sc[4];
        #pragma unroll
        for (int kb = 0; kb < 4; ++kb) sc[kb] = (floatx4){0.f, 0.f, 0.f, 0.f};
        #pragma unroll
        for (int kb = 0; kb < 4; ++kb) {
            const int key = kb * 16 + l15;
            #pragma unroll
            for (int kci = 0; kci < 8; ++kci) {
                ushort8 mf = *(const ushort8*)&KV[key * 256 +
                    ((((kci << 2) + quad) ^ x7) << 3)];
                sc[kb] = __builtin_amdgcn_mfma_f32_16x16x32_bf16(
                    __builtin_bit_cast(bf16x8, mf),
                    __builtin_bit_cast(bf16x8, qreg[kci]), sc[kb], 0, 0, 0);
            }
        }
        __syncthreads();   // C: all M reads done
        // commit V(kt) from regs: KV[ch][64keys], chunk c at slot c^(ch&7)
        #pragma unroll
        for (int it = 0; it < 8; ++it) {
            int u = it * 256 + tid;
            int ch = u >> 3, k8 = (u & 7) << 3;
            *(ushort8*)&KV[ch * 64 + (((k8 >> 3) ^ (ch & 7)) << 3)] = vpre[it];
        }
        // prefetch M(kt+1) and V(kt+1) (fly during softmax + PV)
        if (kt < 15) {
            int k0n = k0 + 64;
            int nvn = min(64, HW - k0n);
            #pragma unroll
            for (int it = 0; it < 8; ++it) {
                int v = it * 256 + tid;
                int key = v >> 5, ck = v & 31;
                ushort8 val = {0, 0, 0, 0, 0, 0, 0, 0};
                if (key < nvn)
                    val = *(const ushort8*)&Mbf[mbase + (size_t)(k0n + key) * 256 + ck * 8];
                mpre[it] = val;
            }
            #pragma unroll
            for (int it = 0; it < 8; ++it) {
                int u = it * 256 + tid;
                int ch = u >> 3, k8 = (u & 7) << 3;
                vpre[it] = *(const ushort8*)&Vbf[vb + (size_t)ch * VP + k0n + k8];
            }
        }
        // wave-local softmax for q = l15 (keys spread over kb regs + quad lanes)
        #pragma unroll
        for (int kb = 0; kb < 4; ++kb) {
            #pragma unroll
            for (int r = 0; r < 4; ++r)
                if (kb * 16 + quad * 4 + r >= nv) sc[kb][r] = -1e30f;
        }
        float mx = -1e30f;
        #pragma unroll
        for (int kb = 0; kb < 4; ++kb)
            mx = fmaxf(mx, fmaxf(fmaxf(sc[kb][0], sc[kb][1]),
                                 fmaxf(sc[kb][2], sc[kb][3])));
        mx = fmaxf(mx, __shfl_xor(mx, 16));
        mx = fmaxf(mx, __shfl_xor(mx, 32));
        float m_new = fmaxf(m_run, mx);
        float al = __expf(m_run - m_new);
        float sm = 0.f;
        #pragma unroll
        for (int kb = 0; kb < 4; ++kb) {
            #pragma unroll
            for (int r = 0; r < 4; ++r) {
                float p = __expf(sc[kb][r] - m_new);
                sc[kb][r] = p;
                sm += p;
            }
        }
        sm += __shfl_xor(sm, 16);
        sm += __shfl_xor(sm, 32);
        l_run = l_run * al + sm;
        m_run = m_new;
        if (quad == 0) alpha_s[wv * 16 + l15] = al;
        // write P bf16 -> Ps[q][64keys] swizzled (4 keys packed per write)
        {
            const int prow = wv * 16 + l15;
            #pragma unroll
            for (int kb = 0; kb < 4; ++kb) {
                ushort4v pk;
                #pragma unroll
                for (int r = 0; r < 4; ++r) pk[r] = f2bf(sc[kb][r]);
                int cW = ((kb << 1) + (quad >> 1)) ^ x7;
                *(ushort4v*)&Ps[prow * 64 + (cW << 3) + ((quad & 1) << 2)] = pk;
            }
        }
        __syncthreads();   // D: V committed, Ps + alpha visible
        // rescale O, then PV (wave owns ch slice wv*64..+63, all 64 q)
        #pragma unroll
        for (int mt = 0; mt < 4; ++mt) {
            float alq[4];
            #pragma unroll
            for (int r = 0; r < 4; ++r) alq[r] = alpha_s[mt * 16 + quad * 4 + r];
            #pragma unroll
            for (int nt = 0; nt < 4; ++nt)
                #pragma unroll
                for (int r = 0; r < 4; ++r) o[mt][nt][r] *= alq[r];
        }
        #pragma unroll
        for (int ks = 0; ks < 2; ++ks) {
            ushort8 af[4];
            #pragma unroll
            for (int mt = 0; mt < 4; ++mt)
                af[mt] = *(const ushort8*)&Ps[(mt * 16 + l15) * 64 +
                    ((((ks << 2) + quad) ^ x7) << 3)];
            #pragma unroll
            for (int nt = 0; nt < 4; ++nt) {
                int ch = wv * 64 + nt * 16 + l15;
                ushort8 bv = *(const ushort8*)&KV[ch * 64 +
                    ((((ks << 2) + quad) ^ x7) << 3)];
                #pragma unroll
                for (int mt = 0; mt < 4; ++mt)
                    o[mt][nt] = __builtin_amdgcn_mfma_f32_16x16x32_bf16(
                        __builtin_bit_cast(bf16x8, af[mt]),
                        __builtin_bit_cast(bf16x8, bv), o[mt][nt], 0, 0, 0);
            }
        }
        __syncthreads();   // E: all V/Ps reads done
        if (kt < 15) {
            // commit M(kt+1)
            #pragma unroll
            for (int it = 0; it < 8; ++it) {
                int v = it * 256 + tid;
                int key = v >> 5, ck = v & 31;
                *(ushort8*)&KV[key * 256 + ((ck ^ (key & 7)) << 3)] = mpre[it];
            }
        }
        __syncthreads();   // F: M(kt+1) visible
    }
    if (quad == 0) l_s[wv * 16 + l15] = l_run;
    __syncthreads();
    // normalize + stage O (bf16) into KV as [q_local][256ch]
    #pragma unroll
    for (int mt = 0; mt < 4; ++mt) {
        float invl[4];
        #pragma unroll
        for (int r = 0; r < 4; ++r) invl[r] = 1.f / l_s[mt * 16 + quad * 4 + r];
        #pragma unroll
        for (int nt = 0; nt < 4; ++nt) {
            int ch = wv * 64 + nt * 16 + l15;
            #pragma unroll
            for (int r = 0; r < 4; ++r) {
                int qrow = mt * 16 + quad * 4 + r;
                KV[qrow * 256 + ch] = f2bf(o[mt][nt][r] * invl[r]);
            }
        }
    }
    __syncthreads();
    // coalesced nontemporal store: 8 chunks/thread, 16B/lane
    #pragma unroll
    for (int k = 0; k < 8; ++k) {
        int idx = k * 256 + tid;
        int qrow = idx >> 5, c = idx & 31;
        int q = q0 + qrow;
        if (q < THW) {
            ushort8 v = *(const ushort8*)&KV[qrow * 256 + c * 8];
            __builtin_nontemporal_store(v,
                (ushort8*)&Rbf[((size_t)bm * THW + q) * 256 + c * 8]);
        }
    }
}

// ---------------- K5: compare convs via MFMA (R now bf16) ----------------
__global__ __launch_bounds__(256) void k_cmp(
    const unsigned short* __restrict__ Rbf, const float* __restrict__ Vcl,
    const unsigned short* __restrict__ Wpk, float* __restrict__ Pc) {
    __shared__ unsigned short Ws[24576] __attribute__((aligned(16)));  // 48 KB
    const int strip = blockIdx.x;
    const int s = blockIdx.y;
    const int b = blockIdx.z >> 1, kind = blockIdx.z & 1;
    const int m = s >> 2, tq = s & 3;
    const int tid = threadIdx.x;
    const int wv = tid >> 6, lane = tid & 63;
    const int l15 = lane & 15, quad = lane >> 4;

    const unsigned short* wsrc = Wpk + (kind ? 24576 : 0);
    for (int i = tid; i < 3072; i += 256) {
        int row, ch, stride_us;
        if (kind == 0) { row = i >> 6; ch = i & 63; stride_us = 512; }
        else           { row = i >> 5; ch = i & 31; stride_us = 256; }
        ushort8 v = *(const ushort8*)&wsrc[i * 8];
        *(ushort8*)&Ws[row * stride_us + ((ch ^ (row & 7)) << 3)] = v;
    }
    __syncthreads();

    const size_t rbase = ((size_t)(b * 4 + m) * THW + tq * HW) * 256;
    const size_t vbase = ((size_t)b * THW + m * HW) * 256;

    #pragma unroll
    for (int half = 0; half < 2; ++half) {
        int pxt = wv * 2 + half;
        int hw = strip * 128 + pxt * 16 + l15;
        int hwc = min(hw, HW - 1);
        const unsigned short* rrow = Rbf + rbase + (size_t)hwc * 256;
        const float* vrow = Vcl + vbase + (size_t)hwc * 256;
        bf16x8 fr[8], fs[8];   // kind0: R,V ; kind1: D,P
        #pragma unroll
        for (int ks = 0; ks < 8; ++ks) {
            ushort8 r8 = *(const ushort8*)&rrow[ks * 32 + quad * 8];
            float vv[8];
            *(float4*)&vv[0] = *(const float4*)&vrow[ks * 32 + quad * 8];
            *(float4*)&vv[4] = *(const float4*)&vrow[ks * 32 + quad * 8 + 4];
            bf16x8 a, c;
            if (kind == 0) {
                a = __builtin_bit_cast(bf16x8, r8);
                #pragma unroll
                for (int j = 0; j < 8; ++j) c[j] = (__bf16)vv[j];
            } else {
                #pragma unroll
                for (int j = 0; j < 8; ++j) {
                    float rj = bf2f(r8[j]);
                    a[j] = (__bf16)(rj - vv[j]);
                    c[j] = (__bf16)(rj * vv[j]);
                }
            }
            fr[ks] = a; fs[ks] = c;
        }
        floatx4 acc[6];
        #pragma unroll
        for (int i = 0; i < 6; ++i) acc[i] = (floatx4){0.f, 0.f, 0.f, 0.f};
        if (kind == 0) {
            #pragma unroll
            for (int ks = 0; ks < 16; ++ks) {
                bf16x8 bfr = (ks < 8) ? fr[ks] : fs[ks - 8];
                #pragma unroll
                for (int cit = 0; cit < 3; ++cit) {
                    int row = cit * 16 + l15;
                    ushort8 aw = *(const ushort8*)&Ws[row * 512 + (((ks * 4 + quad) ^ (row & 7)) << 3)];
                    acc[cit] = __builtin_amdgcn_mfma_f32_16x16x32_bf16(
                        __builtin_bit_cast(bf16x8, aw), bfr, acc[cit], 0, 0, 0);
                }
            }
        } else {
            #pragma unroll
            for (int ks = 0; ks < 8; ++ks) {
                #pragma unroll
                for (int cit = 0; cit < 6; ++cit) {
                    int row = cit * 16 + l15;
                    ushort8 aw = *(const ushort8*)&Ws[row * 256 + (((ks * 4 + quad) ^ (row & 7)) << 3)];
                    bf16x8 bfr = (cit < 3) ? fr[ks] : fs[ks];
                    acc[cit] = __builtin_amdgcn_mfma_f32_16x16x32_bf16(
                        __builtin_bit_cast(bf16x8, aw), bfr, acc[cit], 0, 0, 0);
                }
            }
        }
        if (hw < HW) {
            if (kind == 0) {
                #pragma unroll
                for (int cit = 0; cit < 3; ++cit)
                    #pragma unroll
                    for (int r = 0; r < 4; ++r) {
                        int ci = cit * 16 + quad * 4 + r;
                        if (ci < 42)
                            Pc[((size_t)(b * NCMP + ci) * 16 + s) * HW + hw] = acc[cit][r];
                    }
            } else {
                #pragma unroll
                for (int cit = 0; cit < 6; ++cit)
                    #pragma unroll
                    for (int r = 0; r < 4; ++r) {
                        int cl = (cit % 3) * 16 + quad * 4 + r;
                        if (cl < 42) {
                            int ci = (cit < 3 ? 42 : 84) + cl;
                            Pc[((size_t)(b * NCMP + ci) * 16 + s) * HW + hw] = acc[cit][r];
                        }
                    }
            }
        }
    }
}

// ---------------- K6: BN stats for compare ----------------
__global__ __launch_bounds__(256) void k_stats_cmp(
    const float* __restrict__ Pc, const float* __restrict__ g_cat,
    const float* __restrict__ b_cat, const float* __restrict__ g_sub,
    const float* __restrict__ b_sub, const float* __restrict__ g_mul,
    const float* __restrict__ b_mul, float* __restrict__ bnc) {
    const int c = blockIdx.x, tid = threadIdx.x;
    float s = 0.f, q = 0.f;
    for (int i = tid; i < 4 * 16 * HW; i += 256) {
        int bb = i / (16 * HW), r = i - bb * (16 * HW);
        float v = Pc[(size_t)(bb * NCMP + c) * (16 * HW) + r];
        s += v; q += v * v;
    }
    __shared__ float rs[256], rq[256];
    rs[tid] = s; rq[tid] = q;
    __syncthreads();
    for (int off = 128; off > 0; off >>= 1) {
        if (tid < off) { rs[tid] += rs[tid + off]; rq[tid] += rq[tid + off]; }
        __syncthreads();
    }
    if (tid == 0) {
        const float n = 4.f * 16.f * HW;
        float mean = rs[0] / n;
        float var = rq[0] / n - mean * mean;
        float g, bt;
        if (c < 42)       { g = g_cat[c];      bt = b_cat[c]; }
        else if (c < 84)  { g = g_sub[c - 42]; bt = b_sub[c - 42]; }
        else              { g = g_mul[c - 84]; bt = b_mul[c - 84]; }
        float sc = g * rsqrtf(var + BN_EPS);
        bnc[c] = sc;
        bnc[NCMP + c] = bt - mean * sc;
    }
}

// ---------------- K7: build Y channel-last bf16 [b][p][1024] ----------------
__global__ __launch_bounds__(256) void k_build_y(
    const unsigned short* __restrict__ Rbf, const float* __restrict__ Vcl,
    const float* __restrict__ Pc, const float* __restrict__ bnc,
    unsigned short* __restrict__ Ybf) {
    const int strip = blockIdx.x, t = blockIdx.y, b = blockIdx.z;
    const int tid = threadIdx.x;
    const int chl = tid & 31;
    const int hwl = tid >> 5;
    for (int pass = 0; pass < 8; ++pass) {
        int hw = strip * 64 + pass * 8 + hwl;
        if (hw >= HW) continue;
        size_t ybase = ((size_t)b * THW + t * HW + hw) * 1024;
        for (int cb = 0; cb < 8; ++cb) {
            int ch = cb * 128 + chl * 4;
            float v[4];
            if (ch < 256) {
                v[0] = v[1] = v[2] = v[3] = 0.f;
                #pragma unroll
                for (int tq = 0; tq < 4; ++tq) {
                    ushort4v rv = *(const ushort4v*)&Rbf[
                        (((size_t)(b * 4 + t)) * THW + tq * HW + hw) * 256 + ch];
                    v[0] += bf2f(rv[0]); v[1] += bf2f(rv[1]);
                    v[2] += bf2f(rv[2]); v[3] += bf2f(rv[3]);
                }
                v[0] *= 0.25f; v[1] *= 0.25f; v[2] *= 0.25f; v[3] *= 0.25f;
            } else if (ch < 512) {
                float4 vv = *(const float4*)&Vcl[((size_t)b * THW + t * HW + hw) * 256 + (ch - 256)];
                v[0] = vv.x; v[1] = vv.y; v[2] = vv.z; v[3] = vv.w;
            } else if (ch < 1016) {
                int ci = (ch - 512) >> 2;
                float sc = bnc[ci], sh = bnc[NCMP + ci];
                #pragma unroll
                for (int mm = 0; mm < 4; ++mm) {
                    float pv = Pc[(((size_t)(b * NCMP + ci)) * 16 + mm * 4 + t) * HW + hw];
                    v[mm] = fmaxf(fmaf(pv, sc, sh), 0.f);
                }
            } else {
                v[0] = v[1] = v[2] = v[3] = 0.f;
            }
            ushort4v ov;
            #pragma unroll
            for (int i = 0; i < 4; ++i) ov[i] = f2bf(v[i]);
            *(ushort4v*)&Ybf[ybase + ch] = ov;
        }
    }
}

// ---------------- K8: aggregate GEMM via MFMA ----------------
__global__ __launch_bounds__(256) void k_aggm(
    const unsigned short* __restrict__ Wab, const unsigned short* __restrict__ Ybf,
    float* __restrict__ Z) {
    __shared__ unsigned short Wt[16384] __attribute__((aligned(16)));
    const int p0 = blockIdx.x * 128;
    const int oc0 = blockIdx.y * 128;
    const int b = blockIdx.z;
    const int tid = threadIdx.x;
    const int wv = tid >> 6, lane = tid & 63;
    const int l15 = lane & 15, quad = lane >> 4;
    floatx4 acc[8][2];
    #pragma unroll
    for (int i = 0; i < 8; ++i)
        #pragma unroll
        for (int h = 0; h < 2; ++h) acc[i][h] = (floatx4){0.f, 0.f, 0.f, 0.f};
    for (int kc = 0; kc < 8; ++kc) {
        __syncthreads();
        for (int i = tid; i < 2048; i += 256) {
            int row = i >> 4, ch = i & 15;
            ushort8 v = *(const ushort8*)&Wab[(size_t)(oc0 + row) * 1024 + kc * 128 + ch * 8];
            *(ushort8*)&Wt[row * 128 + ((ch ^ (row & 7)) << 3)] = v;
        }
        __syncthreads();
        #pragma unroll
        for (int half = 0; half < 2; ++half) {
            int px = p0 + (wv * 2 + half) * 16 + l15;
            int pxc = min(px, THW - 1);
            const unsigned short* yrow = Ybf + ((size_t)b * THW + pxc) * 1024 + kc * 128;
            #pragma unroll
            for (int ks = 0; ks < 4; ++ks) {
                ushort8 bf = *(const ushort8*)&yrow[ks * 32 + quad * 8];
                #pragma unroll
                for (int oct = 0; oct < 8; ++oct) {
                    int row = oct * 16 + l15;
                    ushort8 af = *(const ushort8*)&Wt[row * 128 + ((((ks * 4 + quad) ^ (row & 7))) << 3)];
                    acc[oct][half] = __builtin_amdgcn_mfma_f32_16x16x32_bf16(
                        __builtin_bit_cast(bf16x8, af),
                        __builtin_bit_cast(bf16x8, bf), acc[oct][half], 0, 0, 0);
                }
            }
        }
    }
    #pragma unroll
    for (int half = 0; half < 2; ++half) {
        int px = p0 + (wv * 2 + half) * 16 + l15;
        if (px < THW) {
            #pragma unroll
            for (int oct = 0; oct < 8; ++oct) {
                int oc = oc0 + oct * 16 + quad * 4;
                #pragma unroll
                for (int r = 0; r < 4; ++r)
                    Z[((size_t)(b * Cch + oc + r)) * THW + px] = acc[oct][half][r];
            }
        }
    }
}

// ---------------- K9: BN stats for aggregate ----------------
__global__ __launch_bounds__(256) void k_stats_agg(
    const float* __restrict__ Z, const float* __restrict__ g_agg,
    const float* __restrict__ b_agg, float* __restrict__ bna) {
    const int c = blockIdx.x, tid = threadIdx.x;
    float s = 0.f, q = 0.f;
    for (int i = tid; i < 4 * THW; i += 256) {
        int bb = i / THW, p = i - bb * THW;
        float v = Z[((size_t)bb * Cch + c) * THW + p];
        s += v; q += v * v;
    }
    __shared__ float rs[256], rq[256];
    rs[tid] = s; rq[tid] = q;
    __syncthreads();
    for (int off = 128; off > 0; off >>= 1) {
        if (tid < off) { rs[tid] += rs[tid + off]; rq[tid] += rq[tid + off]; }
        __syncthreads();
    }
    if (tid == 0) {
        const float n = 4.f * THW;
        float mean = rs[0] / n;
        float var = rq[0] / n - mean * mean;
        float sc = g_agg[c] * rsqrtf(var + BN_EPS);
        bna[c] = sc;
        bna[Cch + c] = b_agg[c] - mean * sc;
    }
}

// ---------------- K10: out = relu(xp + BN(Z)) ----------------
__global__ __launch_bounds__(256) void k_final(const float* __restrict__ xp,
                                               const float* __restrict__ Z,
                                               const float* __restrict__ bna,
                                               float* __restrict__ out) {
    int idx = blockIdx.x * 256 + threadIdx.x;
    if (idx >= NPIX) return;
    int c = (idx / THW) & 511;
    out[idx] = fmaxf(fmaf(Z[idx], bna[c], bna[Cch + c]) + xp[idx], 0.f);
}

extern "C" void kernel_launch(void* const* d_in, const int* in_sizes, int n_in,
                              void* d_out, int out_size, void* d_ws, size_t ws_size,
                              hipStream_t stream) {
    const float* x     = (const float*)d_in[0];
    const float* Wq    = (const float*)d_in[1];
    const float* Wm    = (const float*)d_in[2];
    const float* Wv    = (const float*)d_in[3];
    const float* Wcat  = (const float*)d_in[4];
    const float* Wsub  = (const float*)d_in[5];
    const float* Wmul  = (const float*)d_in[6];
    const float* g_cat = (const float*)d_in[7];
    const float* b_cat = (const float*)d_in[8];
    const float* g_sub = (const float*)d_in[9];
    const float* b_sub = (const float*)d_in[10];
    const float* g_mul = (const float*)d_in[11];
    const float* b_mul = (const float*)d_in[12];
    const float* Wagg  = (const float*)d_in[13];
    const float* g_agg = (const float*)d_in[14];
    const float* b_agg = (const float*)d_in[15];
    float* out = (float*)d_out;
    float* ws  = (float*)d_ws;

    // workspace layout (float offsets); total 35,714,560 fl = 142.9 MB
    float* xp  = ws;                          // 7,872,512
    float* Vcl = xp + 7872512;                // 3,936,256  -> 11,808,768
    float* bnc = Vcl + 3936256;               // 512        -> 11,809,280
    float* bna = bnc + 512;                   // 1024       -> 11,810,304
    unsigned short* Wpk = (unsigned short*)(bna + 1024);   // 49,152 us = 24,576 fl
    unsigned short* Wab = Wpk + 49152;                     // 524,288 us = 262,144 fl
    float* bfreg = (float*)(Wab + 524288);    // 7,872,512 fl -> Qbf/Mbf/Vbf; later Ybf
    unsigned short* Qbf = (unsigned short*)bfreg;          // 3,936,256 us
    unsigned short* Mbf = Qbf + 3936256;                   // 3,936,256 us
    unsigned short* Vbf = Mbf + 3936256;                   // 4,194,304 us
    unsigned short* Ybf = (unsigned short*)bfreg;          // alias (Q/M/V dead)
    unsigned short* Rbf = (unsigned short*)(bfreg + 7872512);  // 15,745,024 us = 7,872,512 fl
    float* Pc = (float*)(Rbf + 15745024);     // 7,750,656 fl (+121,856 pad for Z tail)
    float* Z  = (float*)Rbf;                  // alias: Rbf+Pc dead after build_y
    // Xh/Xl (split-bf16 channel-last xp) alias the Rbf region: live only
    // between k_xpose and k_qmv_mfma; k_attn overwrites Rbf afterwards.
    unsigned short* Xh = Rbf;                 // 7,872,512 us
    unsigned short* Xl = Xh + 7872512;        // 7,872,512 us (fills Rbf region exactly)

    k_prep_w<<<dim3(3248), dim3(256), 0, stream>>>(Wcat, Wsub, Wmul, Wagg, Wpk, Wab, Vbf);
    k_pool<<<dim3((NPIX + 255) / 256), dim3(256), 0, stream>>>(x, xp);
    k_xpose<<<dim3(61, 8, Bb), dim3(256), 0, stream>>>(xp, Xh, Xl);
    k_qmv_mfma<<<dim3(31, 6, Bb), dim3(256), 0, stream>>>(Xh, Xl, Wq, Wm, Wv,
                                                          Qbf, Mbf, Vcl, Vbf);
    k_attn_mfma<<<dim3(16, 61), dim3(256), 0, stream>>>(Qbf, Mbf, Vbf, Rbf);
    k_cmp<<<dim3(8, 16, 8), dim3(256), 0, stream>>>(Rbf, Vcl, Wpk, Pc);
    k_stats_cmp<<<dim3(NCMP), dim3(256), 0, stream>>>(Pc, g_cat, b_cat, g_sub, b_sub,
                                                      g_mul, b_mul, bnc);
    k_build_y<<<dim3(16, 4, Bb), dim3(256), 0, stream>>>(Rbf, Vcl, Pc, bnc, Ybf);
    k_aggm<<<dim3(31, 4, Bb), dim3(256), 0, stream>>>(Wab, Ybf, Z);
    k_stats_agg<<<dim3(Cch), dim3(256), 0, stream>>>(Z, g_agg, b_agg, bna);
    k_final<<<dim3((NPIX + 255) / 256), dim3(256), 0, stream>>>(xp, Z, bna, out);
}

// Round 8
// 638.963 us; speedup vs baseline: 1.7609x; 1.0992x over previous
//
#include <hip/hip_runtime.h>
#include <math.h>

// Problem dims
constexpr int Bb   = 4;
constexpr int Cch  = 512;
constexpr int HW   = 961;      // 31*31
constexpr int THW  = 3844;     // 4*961
constexpr int NCMP = 126;      // 3*42 compare channels
constexpr int NPIX = Bb * Cch * THW;  // 7,872,512
constexpr int Hp = 31, Wp = 31, H0c = 63, W0c = 63;
constexpr int VP = 1024;       // padded keys/frame for Vbf
#define BN_EPS 1e-5f

typedef __attribute__((ext_vector_type(4))) float floatx4;
typedef __attribute__((ext_vector_type(8))) __bf16 bf16x8;
typedef __attribute__((ext_vector_type(8))) unsigned short ushort8;
typedef __attribute__((ext_vector_type(4))) unsigned short ushort4v;

static __device__ __forceinline__ unsigned short f2bf(float x) {
    unsigned int u = __builtin_bit_cast(unsigned int, x);
    u += 0x7fff + ((u >> 16) & 1);   // RNE
    return (unsigned short)(u >> 16);
}
static __device__ __forceinline__ float bf2f(unsigned short u) {
    return __builtin_bit_cast(float, ((unsigned int)u) << 16);
}

// async global->LDS, 16B per lane; LDS dest = wave-uniform base + lane*16
static __device__ __forceinline__ void gl_lds16(const unsigned short* g,
                                                unsigned short* l) {
    __builtin_amdgcn_global_load_lds(
        (const __attribute__((address_space(1))) void*)g,
        (__attribute__((address_space(3))) void*)l, 16, 0, 0);
}

// ---------------- K0: pack weights to bf16 (+ zero Vbf key pad) ----------------
__global__ __launch_bounds__(256) void k_prep_w(
    const float* __restrict__ Wcat, const float* __restrict__ Wsub,
    const float* __restrict__ Wmul, const float* __restrict__ Wagg,
    unsigned short* __restrict__ Wpk, unsigned short* __restrict__ Wab,
    unsigned short* __restrict__ Vbf) {
    int idx = blockIdx.x * 256 + threadIdx.x;
    if (idx < 24576) {                       // cat
        int row = idx >> 9, k = idx & 511;
        Wpk[idx] = (row < 42) ? f2bf(Wcat[row * 512 + k]) : 0;
    } else if (idx < 36864) {                // sub
        int i = idx - 24576;
        int row = i >> 8, k = i & 255;
        Wpk[idx] = (row < 42) ? f2bf(Wsub[row * 256 + k]) : 0;
    } else if (idx < 49152) {                // mul
        int i = idx - 36864;
        int row = i >> 8, k = i & 255;
        Wpk[idx] = (row < 42) ? f2bf(Wmul[row * 256 + k]) : 0;
    } else if (idx < 49152 + 524288) {       // agg
        int i = idx - 49152;
        int row = i >> 10, k = i & 1023;
        Wab[i] = (k < 1016) ? f2bf(Wagg[(size_t)row * 1016 + k]) : 0;
    } else if (idx < 573440 + 258048) {      // Vbf pad keys [961,1024) := 0
        int i = idx - 573440;
        int row = i / 63, k = i - row * 63;  // row < 4096 = 16bm*256ch
        Vbf[(size_t)row * VP + 961 + k] = 0;
    }
}

// ---------------- K1: maxpool (1,3,3)/(1,2,2) ----------------
__global__ __launch_bounds__(256) void k_pool(const float* __restrict__ x,
                                              float* __restrict__ xp) {
    int idx = blockIdx.x * 256 + threadIdx.x;
    if (idx >= NPIX) return;
    int w = idx % Wp;
    int h = (idx / Wp) % Hp;
    int bct = idx / HW;
    const float* src = x + (size_t)bct * (H0c * W0c) + (2 * h) * W0c + 2 * w;
    float m = -INFINITY;
    #pragma unroll
    for (int i = 0; i < 3; ++i) {
        m = fmaxf(m, src[i * W0c + 0]);
        m = fmaxf(m, src[i * W0c + 1]);
        m = fmaxf(m, src[i * W0c + 2]);
    }
    xp[idx] = m;
}

// ---------------- K1b: transpose xp -> channel-last bf16 hi/lo split ----------------
// xp [b][512][THW] fp32  ->  Xh/Xl [b][THW][512] bf16 (hi + residual-lo)
__global__ __launch_bounds__(256) void k_xpose(const float* __restrict__ xp,
                                               unsigned short* __restrict__ Xh,
                                               unsigned short* __restrict__ Xl) {
    __shared__ float T[64][65];   // +1 pad: conflict-free column reads
    const int p0 = blockIdx.x * 64;
    const int c0 = blockIdx.y * 64;
    const int b  = blockIdx.z;
    const int tid = threadIdx.x;
    // load 64c x 64px, float4 along px (coalesced)
    {
        int px4 = (tid & 15) * 4;
        int cb = tid >> 4;          // 0..15
        #pragma unroll
        for (int i = 0; i < 4; ++i) {
            int c = cb + i * 16;
            int p = p0 + px4;
            const float* src = xp + ((size_t)(b * Cch + c0 + c)) * THW + p;
            float4 v;
            if (p + 3 < THW) {
                v = *(const float4*)src;
            } else {
                v.x = (p     < THW) ? src[0] : 0.f;
                v.y = (p + 1 < THW) ? src[1] : 0.f;
                v.z = (p + 2 < THW) ? src[2] : 0.f;
                v.w = (p + 3 < THW) ? src[3] : 0.f;
            }
            T[c][px4] = v.x; T[c][px4 + 1] = v.y;
            T[c][px4 + 2] = v.z; T[c][px4 + 3] = v.w;
        }
    }
    __syncthreads();
    {
        int px = tid >> 2;
        int cs = (tid & 3) * 16;
        int p = p0 + px;
        if (p < THW) {
            ushort8 hi[2], lo[2];
            #pragma unroll
            for (int j = 0; j < 16; ++j) {
                float v = T[cs + j][px];
                unsigned short h = f2bf(v);
                hi[j >> 3][j & 7] = h;
                lo[j >> 3][j & 7] = f2bf(v - bf2f(h));
            }
            size_t base = ((size_t)b * THW + p) * 512 + c0 + cs;
            *(ushort8*)&Xh[base]     = hi[0];
            *(ushort8*)&Xh[base + 8] = hi[1];
            *(ushort8*)&Xl[base]     = lo[0];
            *(ushort8*)&Xl[base + 8] = lo[1];
        }
    }
}

// ---------------- K2: Q/M/V projections via split-bf16 MFMA ----------------
// grid (31 px-tiles, 6 oc-tiles, B). BM=128 oc, BN=128 px, K-step 64.
// acc = Whi*Xhi + Whi*Xlo + Wlo*Xhi  (~fp32 accuracy, 3x bf16 MFMA rate)
__global__ __launch_bounds__(256) void k_qmv_mfma(
    const unsigned short* __restrict__ Xh, const unsigned short* __restrict__ Xl,
    const float* __restrict__ Wq, const float* __restrict__ Wm,
    const float* __restrict__ Wv,
    unsigned short* __restrict__ Qbf, unsigned short* __restrict__ Mbf,
    float* __restrict__ Vcl, unsigned short* __restrict__ Vbf) {
    __shared__ unsigned short Whs[128 * 64] __attribute__((aligned(16)));
    __shared__ unsigned short Wls[128 * 64] __attribute__((aligned(16)));
    const int p0  = blockIdx.x * 128;
    const int sel = blockIdx.y >> 1;            // 0:Q 1:M 2:V
    const int ocr = (blockIdx.y & 1) * 128;     // row offset within the 256-row matrix
    const int b   = blockIdx.z;
    const float* Wbase = ((sel == 0) ? Wq : (sel == 1) ? Wm : Wv) + (size_t)ocr * 512;
    const int tid = threadIdx.x;
    const int wv = tid >> 6, lane = tid & 63;
    const int l15 = lane & 15, quad = lane >> 4;

    floatx4 acc[8][2];
    #pragma unroll
    for (int i = 0; i < 8; ++i)
        #pragma unroll
        for (int h = 0; h < 2; ++h) acc[i][h] = (floatx4){0.f, 0.f, 0.f, 0.f};

    for (int kc = 0; kc < 512; kc += 64) {
        __syncthreads();
        // stage W tile [128oc][64k] hi+lo, XOR chunk swizzle (conflict-free b128)
        #pragma unroll
        for (int i = 0; i < 4; ++i) {
            int t = i * 256 + tid;              // 0..1023
            int row = t >> 3, c8 = t & 7;       // row 0..127, chunk 0..7
            const float* wr = Wbase + (size_t)row * 512 + kc + c8 * 8;
            float v[8];
            *(float4*)&v[0] = *(const float4*)wr;
            *(float4*)&v[4] = *(const float4*)(wr + 4);
            ushort8 hi, lo;
            #pragma unroll
            for (int j = 0; j < 8; ++j) {
                unsigned short h = f2bf(v[j]);
                hi[j] = h;
                lo[j] = f2bf(v[j] - bf2f(h));
            }
            int addr = row * 64 + ((c8 ^ (row & 7)) << 3);
            *(ushort8*)&Whs[addr] = hi;
            *(ushort8*)&Wls[addr] = lo;
        }
        __syncthreads();
        #pragma unroll
        for (int half = 0; half < 2; ++half) {
            int px = p0 + (wv * 2 + half) * 16 + l15;
            int pxc = min(px, THW - 1);
            const unsigned short* xh = Xh + ((size_t)b * THW + pxc) * 512 + kc;
            const unsigned short* xl = Xl + ((size_t)b * THW + pxc) * 512 + kc;
            #pragma unroll
            for (int ks = 0; ks < 2; ++ks) {
                ushort8 bh = *(const ushort8*)&xh[ks * 32 + quad * 8];
                ushort8 bl = *(const ushort8*)&xl[ks * 32 + quad * 8];
                #pragma unroll
                for (int oct = 0; oct < 8; ++oct) {
                    int row = oct * 16 + l15;
                    int ca = row * 64 + (((ks * 4 + quad) ^ (row & 7)) << 3);
                    ushort8 ah = *(const ushort8*)&Whs[ca];
                    ushort8 al = *(const ushort8*)&Wls[ca];
                    acc[oct][half] = __builtin_amdgcn_mfma_f32_16x16x32_bf16(
                        __builtin_bit_cast(bf16x8, ah),
                        __builtin_bit_cast(bf16x8, bh), acc[oct][half], 0, 0, 0);
                    acc[oct][half] = __builtin_amdgcn_mfma_f32_16x16x32_bf16(
                        __builtin_bit_cast(bf16x8, ah),
                        __builtin_bit_cast(bf16x8, bl), acc[oct][half], 0, 0, 0);
                    acc[oct][half] = __builtin_amdgcn_mfma_f32_16x16x32_bf16(
                        __builtin_bit_cast(bf16x8, al),
                        __builtin_bit_cast(bf16x8, bh), acc[oct][half], 0, 0, 0);
                }
            }
        }
    }
    // epilogue: C row = ocr+oct*16+quad*4+r, col px = p0+(wv*2+half)*16+l15
    if (sel < 2) {
        unsigned short* outbf = sel ? Mbf : Qbf;
        const float scale = sel ? 1.0f : 0.0625f;
        #pragma unroll
        for (int half = 0; half < 2; ++half) {
            int px = p0 + (wv * 2 + half) * 16 + l15;
            if (px < THW) {
                #pragma unroll
                for (int oct = 0; oct < 8; ++oct) {
                    int ch = ocr + oct * 16 + quad * 4;
                    ushort4v v;
                    #pragma unroll
                    for (int r = 0; r < 4; ++r) v[r] = f2bf(acc[oct][half][r] * scale);
                    *(ushort4v*)&outbf[((size_t)b * THW + px) * 256 + ch] = v;
                }
            }
        }
    } else {
        #pragma unroll
        for (int half = 0; half < 2; ++half) {
            int px = p0 + (wv * 2 + half) * 16 + l15;
            if (px < THW) {
                int m = px / HW;
                int key = px - m * HW;
                size_t vbbase = (size_t)(b * 4 + m) * 256;
                #pragma unroll
                for (int oct = 0; oct < 8; ++oct) {
                    int ch = ocr + oct * 16 + quad * 4;
                    float4 fv = make_float4(acc[oct][half][0], acc[oct][half][1],
                                            acc[oct][half][2], acc[oct][half][3]);
                    *(float4*)&Vcl[((size_t)b * THW + px) * 256 + ch] = fv;
                    #pragma unroll
                    for (int r = 0; r < 4; ++r)
                        Vbf[(vbbase + ch + r) * VP + key] = f2bf(acc[oct][half][r]);
                }
            }
        }
    }
}

// ---------------- K3: flash attention, V-from-global + M-dbuf-async ----------
// grid (16, 61). Each wave owns 16 queries (Q in regs). V is NEVER staged in
// LDS: PV reads its 16B fragments straight from Vbf (L2-hot, 61-block reuse).
// M double-buffered in LDS via global_load_lds issued at the TOP of iter kt
// for tile kt+1 (full QK+softmax phase of flight). 2 barriers/iter.
// LDS 72.5KB -> 2 blocks/CU; regs ~120 VGPR + 64 AGPR -> fits (256,2) no spill.
__global__ __launch_bounds__(256, 2) void k_attn_mfma(
    const unsigned short* __restrict__ Qbf, const unsigned short* __restrict__ Mbf,
    const unsigned short* __restrict__ Vbf, unsigned short* __restrict__ Rbf) {
    __shared__ unsigned short Mb[2][16384] __attribute__((aligned(16)));  // 64KB
    __shared__ unsigned short Ps[4096] __attribute__((aligned(16)));      // 8KB
    __shared__ float alpha_s[64];
    __shared__ float l_s[64];

    const int bm = blockIdx.x;
    const int b = bm >> 2, m = bm & 3;
    const int q0 = blockIdx.y * 64;
    const int tid = threadIdx.x;
    const int wv = tid >> 6, lane = tid & 63;
    const int l15 = lane & 15, quad = lane >> 4;
    const int x7 = l15 & 7;

    const size_t mbase = ((size_t)b * THW + m * HW) * 256;
    const size_t vb = (size_t)bm * 256 * VP;

    // Q fragments in registers: this lane is column q = q0 + wv*16 + l15
    const int qg = min(q0 + wv * 16 + l15, THW - 1);
    const unsigned short* qp = Qbf + ((size_t)b * THW + qg) * 256 + quad * 8;
    ushort8 qreg[8];
    #pragma unroll
    for (int kci = 0; kci < 8; ++kci)
        qreg[kci] = *(const ushort8*)&qp[kci * 32];

    // stage M(0) into Mb[0]: content chunk c of row key at slot c^(key&7),
    // achieved via linear LDS dest + inverse-swizzled GLOBAL source (rule 21).
    #pragma unroll
    for (int i = 0; i < 8; ++i) {
        int blk = wv * 8 + i;                  // wave-uniform 1KB block
        int key = blk * 2 + (lane >> 5);
        int cS = (lane & 31) ^ (key & 7);
        gl_lds16(Mbf + mbase + (size_t)key * 256 + (cS << 3), &Mb[0][blk * 512]);
    }

    floatx4 o[4][4];
    #pragma unroll
    for (int mt = 0; mt < 4; ++mt)
        #pragma unroll
        for (int nt = 0; nt < 4; ++nt) o[mt][nt] = (floatx4){0.f, 0.f, 0.f, 0.f};
    float m_run = -1e30f, l_run = 0.f;

    __syncthreads();   // M(0) staged (barrier drains vmcnt)

    int cur = 0;
    for (int kt = 0; kt < 16; ++kt) {
        const int k0 = kt * 64;
        const int nv = min(64, HW - k0);
        // issue M(kt+1) -> Mb[cur^1] (free all iter); flies under QK+softmax
        if (kt < 15) {
            int k0n = k0 + 64;
            #pragma unroll
            for (int i = 0; i < 8; ++i) {
                int blk = wv * 8 + i;
                int key = blk * 2 + (lane >> 5);
                int cS = (lane & 31) ^ (key & 7);
                int kg = min(k0n + key, HW - 1);
                gl_lds16(Mbf + mbase + (size_t)kg * 256 + (cS << 3),
                         &Mb[cur ^ 1][blk * 512]);
            }
        }
        // QK: C[key_local][q], A = M frags from LDS, B = Q regs
        floatx4 sc[4];
        #pragma unroll
        for (int kb = 0; kb < 4; ++kb) sc[kb] = (floatx4){0.f, 0.f, 0.f, 0.f};
        #pragma unroll
        for (int kb = 0; kb < 4; ++kb) {
            const int key = kb * 16 + l15;
            #pragma unroll
            for (int kci = 0; kci < 8; ++kci) {
                ushort8 mf = *(const ushort8*)&Mb[cur][key * 256 +
                    ((((kci << 2) + quad) ^ x7) << 3)];
                sc[kb] = __builtin_amdgcn_mfma_f32_16x16x32_bf16(
                    __builtin_bit_cast(bf16x8, mf),
                    __builtin_bit_cast(bf16x8, qreg[kci]), sc[kb], 0, 0, 0);
            }
        }
        // wave-local softmax for q = l15 (keys spread over kb regs + quad lanes)
        #pragma unroll
        for (int kb = 0; kb < 4; ++kb) {
            #pragma unroll
            for (int r = 0; r < 4; ++r)
                if (kb * 16 + quad * 4 + r >= nv) sc[kb][r] = -1e30f;
        }
        float mx = -1e30f;
        #pragma unroll
        for (int kb = 0; kb < 4; ++kb)
            mx = fmaxf(mx, fmaxf(fmaxf(sc[kb][0], sc[kb][1]),
                                 fmaxf(sc[kb][2], sc[kb][3])));
        mx = fmaxf(mx, __shfl_xor(mx, 16));
        mx = fmaxf(mx, __shfl_xor(mx, 32));
        float m_new = fmaxf(m_run, mx);
        float al = __expf(m_run - m_new);
        float sm = 0.f;
        #pragma unroll
        for (int kb = 0; kb < 4; ++kb) {
            #pragma unroll
            for (int r = 0; r < 4; ++r) {
                float p = __expf(sc[kb][r] - m_new);
                sc[kb][r] = p;
                sm += p;
            }
        }
        sm += __shfl_xor(sm, 16);
        sm += __shfl_xor(sm, 32);
        l_run = l_run * al + sm;
        m_run = m_new;
        if (quad == 0) alpha_s[wv * 16 + l15] = al;
        // write P bf16 -> Ps[q][64keys] swizzled (4 keys packed per write)
        {
            const int prow = wv * 16 + l15;
            #pragma unroll
            for (int kb = 0; kb < 4; ++kb) {
                ushort4v pk;
                #pragma unroll
                for (int r = 0; r < 4; ++r) pk[r] = f2bf(sc[kb][r]);
                int cW = ((kb << 1) + (quad >> 1)) ^ x7;
                *(ushort4v*)&Ps[prow * 64 + (cW << 3) + ((quad & 1) << 2)] = pk;
            }
        }
        __syncthreads();   // B1: Ps+alpha visible; M(kt) reads done; M(kt+1) landed
        // PV: V fragments straight from global (contiguous 16B, L2-hot)
        ushort8 bvr[8];
        #pragma unroll
        for (int ks = 0; ks < 2; ++ks)
            #pragma unroll
            for (int nt = 0; nt < 4; ++nt) {
                int ch = wv * 64 + nt * 16 + l15;
                bvr[ks * 4 + nt] = *(const ushort8*)&Vbf[
                    vb + (size_t)ch * VP + k0 + ((((ks << 2) + quad)) << 3)];
            }
        // rescale O
        #pragma unroll
        for (int mt = 0; mt < 4; ++mt) {
            float alq[4];
            #pragma unroll
            for (int r = 0; r < 4; ++r) alq[r] = alpha_s[mt * 16 + quad * 4 + r];
            #pragma unroll
            for (int nt = 0; nt < 4; ++nt)
                #pragma unroll
                for (int r = 0; r < 4; ++r) o[mt][nt][r] *= alq[r];
        }
        #pragma unroll
        for (int ks = 0; ks < 2; ++ks) {
            ushort8 af[4];
            #pragma unroll
            for (int mt = 0; mt < 4; ++mt)
                af[mt] = *(const ushort8*)&Ps[(mt * 16 + l15) * 64 +
                    ((((ks << 2) + quad) ^ x7) << 3)];
            #pragma unroll
            for (int nt = 0; nt < 4; ++nt) {
                #pragma unroll
                for (int mt = 0; mt < 4; ++mt)
                    o[mt][nt] = __builtin_amdgcn_mfma_f32_16x16x32_bf16(
                        __builtin_bit_cast(bf16x8, af[mt]),
                        __builtin_bit_cast(bf16x8, bvr[ks * 4 + nt]), o[mt][nt],
                        0, 0, 0);
            }
        }
        __syncthreads();   // B2: Ps reads done (next iter overwrites)
        cur ^= 1;
    }
    if (quad == 0) l_s[wv * 16 + l15] = l_run;
    __syncthreads();
    // normalize + stage O (bf16) into Mb[0] as [q_local][256ch]
    #pragma unroll
    for (int mt = 0; mt < 4; ++mt) {
        float invl[4];
        #pragma unroll
        for (int r = 0; r < 4; ++r) invl[r] = 1.f / l_s[mt * 16 + quad * 4 + r];
        #pragma unroll
        for (int nt = 0; nt < 4; ++nt) {
            int ch = wv * 64 + nt * 16 + l15;
            #pragma unroll
            for (int r = 0; r < 4; ++r) {
                int qrow = mt * 16 + quad * 4 + r;
                Mb[0][qrow * 256 + ch] = f2bf(o[mt][nt][r] * invl[r]);
            }
        }
    }
    __syncthreads();
    // coalesced nontemporal store: 8 chunks/thread, 16B/lane
    #pragma unroll
    for (int k = 0; k < 8; ++k) {
        int idx = k * 256 + tid;
        int qrow = idx >> 5, c = idx & 31;
        int q = q0 + qrow;
        if (q < THW) {
            ushort8 v = *(const ushort8*)&Mb[0][qrow * 256 + c * 8];
            __builtin_nontemporal_store(v,
                (ushort8*)&Rbf[((size_t)bm * THW + q) * 256 + c * 8]);
        }
    }
}

// ---------------- K5: compare convs via MFMA (R now bf16) ----------------
__global__ __launch_bounds__(256) void k_cmp(
    const unsigned short* __restrict__ Rbf, const float* __restrict__ Vcl,
    const unsigned short* __restrict__ Wpk, float* __restrict__ Pc) {
    __shared__ unsigned short Ws[24576] __attribute__((aligned(16)));  // 48 KB
    const int strip = blockIdx.x;
    const int s = blockIdx.y;
    const int b = blockIdx.z >> 1, kind = blockIdx.z & 1;
    const int m = s >> 2, tq = s & 3;
    const int tid = threadIdx.x;
    const int wv = tid >> 6, lane = tid & 63;
    const int l15 = lane & 15, quad = lane >> 4;

    const unsigned short* wsrc = Wpk + (kind ? 24576 : 0);
    for (int i = tid; i < 3072; i += 256) {
        int row, ch, stride_us;
        if (kind == 0) { row = i >> 6; ch = i & 63; stride_us = 512; }
        else           { row = i >> 5; ch = i & 31; stride_us = 256; }
        ushort8 v = *(const ushort8*)&wsrc[i * 8];
        *(ushort8*)&Ws[row * stride_us + ((ch ^ (row & 7)) << 3)] = v;
    }
    __syncthreads();

    const size_t rbase = ((size_t)(b * 4 + m) * THW + tq * HW) * 256;
    const size_t vbase = ((size_t)b * THW + m * HW) * 256;

    #pragma unroll
    for (int half = 0; half < 2; ++half) {
        int pxt = wv * 2 + half;
        int hw = strip * 128 + pxt * 16 + l15;
        int hwc = min(hw, HW - 1);
        const unsigned short* rrow = Rbf + rbase + (size_t)hwc * 256;
        const float* vrow = Vcl + vbase + (size_t)hwc * 256;
        bf16x8 fr[8], fs[8];   // kind0: R,V ; kind1: D,P
        #pragma unroll
        for (int ks = 0; ks < 8; ++ks) {
            ushort8 r8 = *(const ushort8*)&rrow[ks * 32 + quad * 8];
            float vv[8];
            *(float4*)&vv[0] = *(const float4*)&vrow[ks * 32 + quad * 8];
            *(float4*)&vv[4] = *(const float4*)&vrow[ks * 32 + quad * 8 + 4];
            bf16x8 a, c;
            if (kind == 0) {
                a = __builtin_bit_cast(bf16x8, r8);
                #pragma unroll
                for (int j = 0; j < 8; ++j) c[j] = (__bf16)vv[j];
            } else {
                #pragma unroll
                for (int j = 0; j < 8; ++j) {
                    float rj = bf2f(r8[j]);
                    a[j] = (__bf16)(rj - vv[j]);
                    c[j] = (__bf16)(rj * vv[j]);
                }
            }
            fr[ks] = a; fs[ks] = c;
        }
        floatx4 acc[6];
        #pragma unroll
        for (int i = 0; i < 6; ++i) acc[i] = (floatx4){0.f, 0.f, 0.f, 0.f};
        if (kind == 0) {
            #pragma unroll
            for (int ks = 0; ks < 16; ++ks) {
                bf16x8 bfr = (ks < 8) ? fr[ks] : fs[ks - 8];
                #pragma unroll
                for (int cit = 0; cit < 3; ++cit) {
                    int row = cit * 16 + l15;
                    ushort8 aw = *(const ushort8*)&Ws[row * 512 + (((ks * 4 + quad) ^ (row & 7)) << 3)];
                    acc[cit] = __builtin_amdgcn_mfma_f32_16x16x32_bf16(
                        __builtin_bit_cast(bf16x8, aw), bfr, acc[cit], 0, 0, 0);
                }
            }
        } else {
            #pragma unroll
            for (int ks = 0; ks < 8; ++ks) {
                #pragma unroll
                for (int cit = 0; cit < 6; ++cit) {
                    int row = cit * 16 + l15;
                    ushort8 aw = *(const ushort8*)&Ws[row * 256 + (((ks * 4 + quad) ^ (row & 7)) << 3)];
                    bf16x8 bfr = (cit < 3) ? fr[ks] : fs[ks];
                    acc[cit] = __builtin_amdgcn_mfma_f32_16x16x32_bf16(
                        __builtin_bit_cast(bf16x8, aw), bfr, acc[cit], 0, 0, 0);
                }
            }
        }
        if (hw < HW) {
            if (kind == 0) {
                #pragma unroll
                for (int cit = 0; cit < 3; ++cit)
                    #pragma unroll
                    for (int r = 0; r < 4; ++r) {
                        int ci = cit * 16 + quad * 4 + r;
                        if (ci < 42)
                            Pc[((size_t)(b * NCMP + ci) * 16 + s) * HW + hw] = acc[cit][r];
                    }
            } else {
                #pragma unroll
                for (int cit = 0; cit < 6; ++cit)
                    #pragma unroll
                    for (int r = 0; r < 4; ++r) {
                        int cl = (cit % 3) * 16 + quad * 4 + r;
                        if (cl < 42) {
                            int ci = (cit < 3 ? 42 : 84) + cl;
                            Pc[((size_t)(b * NCMP + ci) * 16 + s) * HW + hw] = acc[cit][r];
                        }
                    }
            }
        }
    }
}

// ---------------- K6: BN stats for compare ----------------
__global__ __launch_bounds__(256) void k_stats_cmp(
    const float* __restrict__ Pc, const float* __restrict__ g_cat,
    const float* __restrict__ b_cat, const float* __restrict__ g_sub,
    const float* __restrict__ b_sub, const float* __restrict__ g_mul,
    const float* __restrict__ b_mul, float* __restrict__ bnc) {
    const int c = blockIdx.x, tid = threadIdx.x;
    float s = 0.f, q = 0.f;
    for (int i = tid; i < 4 * 16 * HW; i += 256) {
        int bb = i / (16 * HW), r = i - bb * (16 * HW);
        float v = Pc[(size_t)(bb * NCMP + c) * (16 * HW) + r];
        s += v; q += v * v;
    }
    __shared__ float rs[256], rq[256];
    rs[tid] = s; rq[tid] = q;
    __syncthreads();
    for (int off = 128; off > 0; off >>= 1) {
        if (tid < off) { rs[tid] += rs[tid + off]; rq[tid] += rq[tid + off]; }
        __syncthreads();
    }
    if (tid == 0) {
        const float n = 4.f * 16.f * HW;
        float mean = rs[0] / n;
        float var = rq[0] / n - mean * mean;
        float g, bt;
        if (c < 42)       { g = g_cat[c];      bt = b_cat[c]; }
        else if (c < 84)  { g = g_sub[c - 42]; bt = b_sub[c - 42]; }
        else              { g = g_mul[c - 84]; bt = b_mul[c - 84]; }
        float sc = g * rsqrtf(var + BN_EPS);
        bnc[c] = sc;
        bnc[NCMP + c] = bt - mean * sc;
    }
}

// ---------------- K7: build Y channel-last bf16 [b][p][1024] ----------------
__global__ __launch_bounds__(256) void k_build_y(
    const unsigned short* __restrict__ Rbf, const float* __restrict__ Vcl,
    const float* __restrict__ Pc, const float* __restrict__ bnc,
    unsigned short* __restrict__ Ybf) {
    const int strip = blockIdx.x, t = blockIdx.y, b = blockIdx.z;
    const int tid = threadIdx.x;
    const int chl = tid & 31;
    const int hwl = tid >> 5;
    for (int pass = 0; pass < 8; ++pass) {
        int hw = strip * 64 + pass * 8 + hwl;
        if (hw >= HW) continue;
        size_t ybase = ((size_t)b * THW + t * HW + hw) * 1024;
        for (int cb = 0; cb < 8; ++cb) {
            int ch = cb * 128 + chl * 4;
            float v[4];
            if (ch < 256) {
                v[0] = v[1] = v[2] = v[3] = 0.f;
                #pragma unroll
                for (int tq = 0; tq < 4; ++tq) {
                    ushort4v rv = *(const ushort4v*)&Rbf[
                        (((size_t)(b * 4 + t)) * THW + tq * HW + hw) * 256 + ch];
                    v[0] += bf2f(rv[0]); v[1] += bf2f(rv[1]);
                    v[2] += bf2f(rv[2]); v[3] += bf2f(rv[3]);
                }
                v[0] *= 0.25f; v[1] *= 0.25f; v[2] *= 0.25f; v[3] *= 0.25f;
            } else if (ch < 512) {
                float4 vv = *(const float4*)&Vcl[((size_t)b * THW + t * HW + hw) * 256 + (ch - 256)];
                v[0] = vv.x; v[1] = vv.y; v[2] = vv.z; v[3] = vv.w;
            } else if (ch < 1016) {
                int ci = (ch - 512) >> 2;
                float sc = bnc[ci], sh = bnc[NCMP + ci];
                #pragma unroll
                for (int mm = 0; mm < 4; ++mm) {
                    float pv = Pc[(((size_t)(b * NCMP + ci)) * 16 + mm * 4 + t) * HW + hw];
                    v[mm] = fmaxf(fmaf(pv, sc, sh), 0.f);
                }
            } else {
                v[0] = v[1] = v[2] = v[3] = 0.f;
            }
            ushort4v ov;
            #pragma unroll
            for (int i = 0; i < 4; ++i) ov[i] = f2bf(v[i]);
            *(ushort4v*)&Ybf[ybase + ch] = ov;
        }
    }
}

// ---------------- K8: aggregate GEMM via MFMA ----------------
__global__ __launch_bounds__(256) void k_aggm(
    const unsigned short* __restrict__ Wab, const unsigned short* __restrict__ Ybf,
    float* __restrict__ Z) {
    __shared__ unsigned short Wt[16384] __attribute__((aligned(16)));
    const int p0 = blockIdx.x * 128;
    const int oc0 = blockIdx.y * 128;
    const int b = blockIdx.z;
    const int tid = threadIdx.x;
    const int wv = tid >> 6, lane = tid & 63;
    const int l15 = lane & 15, quad = lane >> 4;
    floatx4 acc[8][2];
    #pragma unroll
    for (int i = 0; i < 8; ++i)
        #pragma unroll
        for (int h = 0; h < 2; ++h) acc[i][h] = (floatx4){0.f, 0.f, 0.f, 0.f};
    for (int kc = 0; kc < 8; ++kc) {
        __syncthreads();
        for (int i = tid; i < 2048; i += 256) {
            int row = i >> 4, ch = i & 15;
            ushort8 v = *(const ushort8*)&Wab[(size_t)(oc0 + row) * 1024 + kc * 128 + ch * 8];
            *(ushort8*)&Wt[row * 128 + ((ch ^ (row & 7)) << 3)] = v;
        }
        __syncthreads();
        #pragma unroll
        for (int half = 0; half < 2; ++half) {
            int px = p0 + (wv * 2 + half) * 16 + l15;
            int pxc = min(px, THW - 1);
            const unsigned short* yrow = Ybf + ((size_t)b * THW + pxc) * 1024 + kc * 128;
            #pragma unroll
            for (int ks = 0; ks < 4; ++ks) {
                ushort8 bf = *(const ushort8*)&yrow[ks * 32 + quad * 8];
                #pragma unroll
                for (int oct = 0; oct < 8; ++oct) {
                    int row = oct * 16 + l15;
                    ushort8 af = *(const ushort8*)&Wt[row * 128 + ((((ks * 4 + quad) ^ (row & 7))) << 3)];
                    acc[oct][half] = __builtin_amdgcn_mfma_f32_16x16x32_bf16(
                        __builtin_bit_cast(bf16x8, af),
                        __builtin_bit_cast(bf16x8, bf), acc[oct][half], 0, 0, 0);
                }
            }
        }
    }
    #pragma unroll
    for (int half = 0; half < 2; ++half) {
        int px = p0 + (wv * 2 + half) * 16 + l15;
        if (px < THW) {
            #pragma unroll
            for (int oct = 0; oct < 8; ++oct) {
                int oc = oc0 + oct * 16 + quad * 4;
                #pragma unroll
                for (int r = 0; r < 4; ++r)
                    Z[((size_t)(b * Cch + oc + r)) * THW + px] = acc[oct][half][r];
            }
        }
    }
}

// ---------------- K9: BN stats for aggregate ----------------
__global__ __launch_bounds__(256) void k_stats_agg(
    const float* __restrict__ Z, const float* __restrict__ g_agg,
    const float* __restrict__ b_agg, float* __restrict__ bna) {
    const int c = blockIdx.x, tid = threadIdx.x;
    float s = 0.f, q = 0.f;
    for (int i = tid; i < 4 * THW; i += 256) {
        int bb = i / THW, p = i - bb * THW;
        float v = Z[((size_t)bb * Cch + c) * THW + p];
        s += v; q += v * v;
    }
    __shared__ float rs[256], rq[256];
    rs[tid] = s; rq[tid] = q;
    __syncthreads();
    for (int off = 128; off > 0; off >>= 1) {
        if (tid < off) { rs[tid] += rs[tid + off]; rq[tid] += rq[tid + off]; }
        __syncthreads();
    }
    if (tid == 0) {
        const float n = 4.f * THW;
        float mean = rs[0] / n;
        float var = rq[0] / n - mean * mean;
        float sc = g_agg[c] * rsqrtf(var + BN_EPS);
        bna[c] = sc;
        bna[Cch + c] = b_agg[c] - mean * sc;
    }
}

// ---------------- K10: out = relu(xp + BN(Z)) ----------------
__global__ __launch_bounds__(256) void k_final(const float* __restrict__ xp,
                                               const float* __restrict__ Z,
                                               const float* __restrict__ bna,
                                               float* __restrict__ out) {
    int idx = blockIdx.x * 256 + threadIdx.x;
    if (idx >= NPIX) return;
    int c = (idx / THW) & 511;
    out[idx] = fmaxf(fmaf(Z[idx], bna[c], bna[Cch + c]) + xp[idx], 0.f);
}

extern "C" void kernel_launch(void* const* d_in, const int* in_sizes, int n_in,
                              void* d_out, int out_size, void* d_ws, size_t ws_size,
                              hipStream_t stream) {
    const float* x     = (const float*)d_in[0];
    const float* Wq    = (const float*)d_in[1];
    const float* Wm    = (const float*)d_in[2];
    const float* Wv    = (const float*)d_in[3];
    const float* Wcat  = (const float*)d_in[4];
    const float* Wsub  = (const float*)d_in[5];
    const float* Wmul  = (const float*)d_in[6];
    const float* g_cat = (const float*)d_in[7];
    const float* b_cat = (const float*)d_in[8];
    const float* g_sub = (const float*)d_in[9];
    const float* b_sub = (const float*)d_in[10];
    const float* g_mul = (const float*)d_in[11];
    const float* b_mul = (const float*)d_in[12];
    const float* Wagg  = (const float*)d_in[13];
    const float* g_agg = (const float*)d_in[14];
    const float* b_agg = (const float*)d_in[15];
    float* out = (float*)d_out;
    float* ws  = (float*)d_ws;

    // workspace layout (float offsets); total 35,714,560 fl = 142.9 MB
    float* xp  = ws;                          // 7,872,512
    float* Vcl = xp + 7872512;                // 3,936,256  -> 11,808,768
    float* bnc = Vcl + 3936256;               // 512        -> 11,809,280
    float* bna = bnc + 512;                   // 1024       -> 11,810,304
    unsigned short* Wpk = (unsigned short*)(bna + 1024);   // 49,152 us = 24,576 fl
    unsigned short* Wab = Wpk + 49152;                     // 524,288 us = 262,144 fl
    float* bfreg = (float*)(Wab + 524288);    // 7,872,512 fl -> Qbf/Mbf/Vbf; later Ybf
    unsigned short* Qbf = (unsigned short*)bfreg;          // 3,936,256 us
    unsigned short* Mbf = Qbf + 3936256;                   // 3,936,256 us
    unsigned short* Vbf = Mbf + 3936256;                   // 4,194,304 us
    unsigned short* Ybf = (unsigned short*)bfreg;          // alias (Q/M/V dead)
    unsigned short* Rbf = (unsigned short*)(bfreg + 7872512);  // 15,745,024 us = 7,872,512 fl
    float* Pc = (float*)(Rbf + 15745024);     // 7,750,656 fl (+121,856 pad for Z tail)
    float* Z  = (float*)Rbf;                  // alias: Rbf+Pc dead after build_y
    // Xh/Xl (split-bf16 channel-last xp) alias the Rbf region: live only
    // between k_xpose and k_qmv_mfma; k_attn overwrites Rbf afterwards.
    unsigned short* Xh = Rbf;                 // 7,872,512 us
    unsigned short* Xl = Xh + 7872512;        // 7,872,512 us (fills Rbf region exactly)

    k_prep_w<<<dim3(3248), dim3(256), 0, stream>>>(Wcat, Wsub, Wmul, Wagg, Wpk, Wab, Vbf);
    k_pool<<<dim3((NPIX + 255) / 256), dim3(256), 0, stream>>>(x, xp);
    k_xpose<<<dim3(61, 8, Bb), dim3(256), 0, stream>>>(xp, Xh, Xl);
    k_qmv_mfma<<<dim3(31, 6, Bb), dim3(256), 0, stream>>>(Xh, Xl, Wq, Wm, Wv,
                                                          Qbf, Mbf, Vcl, Vbf);
    k_attn_mfma<<<dim3(16, 61), dim3(256), 0, stream>>>(Qbf, Mbf, Vbf, Rbf);
    k_cmp<<<dim3(8, 16, 8), dim3(256), 0, stream>>>(Rbf, Vcl, Wpk, Pc);
    k_stats_cmp<<<dim3(NCMP), dim3(256), 0, stream>>>(Pc, g_cat, b_cat, g_sub, b_sub,
                                                      g_mul, b_mul, bnc);
    k_build_y<<<dim3(16, 4, Bb), dim3(256), 0, stream>>>(Rbf, Vcl, Pc, bnc, Ybf);
    k_aggm<<<dim3(31, 4, Bb), dim3(256), 0, stream>>>(Wab, Ybf, Z);
    k_stats_agg<<<dim3(Cch), dim3(256), 0, stream>>>(Z, g_agg, b_agg, bna);
    k_final<<<dim3((NPIX + 255) / 256), dim3(256), 0, stream>>>(xp, Z, bna, out);
}

// Round 9
// 623.411 us; speedup vs baseline: 1.8048x; 1.0249x over previous
//
#include <hip/hip_runtime.h>
#include <math.h>

// Problem dims
constexpr int Bb   = 4;
constexpr int Cch  = 512;
constexpr int HW   = 961;      // 31*31
constexpr int THW  = 3844;     // 4*961
constexpr int NCMP = 126;      // 3*42 compare channels
constexpr int NPIX = Bb * Cch * THW;  // 7,872,512
constexpr int Hp = 31, Wp = 31, H0c = 63, W0c = 63;
constexpr int VP = 1024;       // padded keys/frame for Vbf
#define BN_EPS 1e-5f

typedef __attribute__((ext_vector_type(4))) float floatx4;
typedef __attribute__((ext_vector_type(8))) __bf16 bf16x8;
typedef __attribute__((ext_vector_type(8))) unsigned short ushort8;
typedef __attribute__((ext_vector_type(4))) unsigned short ushort4v;

static __device__ __forceinline__ unsigned short f2bf(float x) {
    unsigned int u = __builtin_bit_cast(unsigned int, x);
    u += 0x7fff + ((u >> 16) & 1);   // RNE
    return (unsigned short)(u >> 16);
}
static __device__ __forceinline__ float bf2f(unsigned short u) {
    return __builtin_bit_cast(float, ((unsigned int)u) << 16);
}

// async global->LDS, 16B per lane; LDS dest = wave-uniform base + lane*16
static __device__ __forceinline__ void gl_lds16(const unsigned short* g,
                                                unsigned short* l) {
    __builtin_amdgcn_global_load_lds(
        (const __attribute__((address_space(1))) void*)g,
        (__attribute__((address_space(3))) void*)l, 16, 0, 0);
}

// ---------------- K0: pack weights to bf16 (+ Vbf pad + W hi/lo split) -------
// New: Wh/Wl hold the Q/M/V weights split into bf16 hi + residual-lo, stored
// as the exact per-tile LDS image k_qmv stages (chunk-swizzled), so k_qmv's
// staging becomes a pure global_load_lds copy (no per-block re-conversion).
__global__ __launch_bounds__(256) void k_prep_w(
    const float* __restrict__ Wq, const float* __restrict__ Wm,
    const float* __restrict__ Wv,
    const float* __restrict__ Wcat, const float* __restrict__ Wsub,
    const float* __restrict__ Wmul, const float* __restrict__ Wagg,
    unsigned short* __restrict__ Wpk, unsigned short* __restrict__ Wab,
    unsigned short* __restrict__ Vbf,
    unsigned short* __restrict__ Wh, unsigned short* __restrict__ Wl) {
    int idx = blockIdx.x * 256 + threadIdx.x;
    if (idx < 24576) {                       // cat
        int row = idx >> 9, k = idx & 511;
        Wpk[idx] = (row < 42) ? f2bf(Wcat[row * 512 + k]) : 0;
    } else if (idx < 36864) {                // sub
        int i = idx - 24576;
        int row = i >> 8, k = i & 255;
        Wpk[idx] = (row < 42) ? f2bf(Wsub[row * 256 + k]) : 0;
    } else if (idx < 49152) {                // mul
        int i = idx - 36864;
        int row = i >> 8, k = i & 255;
        Wpk[idx] = (row < 42) ? f2bf(Wmul[row * 256 + k]) : 0;
    } else if (idx < 49152 + 524288) {       // agg
        int i = idx - 49152;
        int row = i >> 10, k = i & 1023;
        Wab[i] = (k < 1016) ? f2bf(Wagg[(size_t)row * 1016 + k]) : 0;
    } else if (idx < 573440 + 258048) {      // Vbf pad keys [961,1024) := 0
        int i = idx - 573440;
        int row = i / 63, k = i - row * 63;  // row < 4096 = 16bm*256ch
        Vbf[(size_t)row * VP + 961 + k] = 0;
    } else if (idx < 831488 + 393216) {      // W hi/lo split, LDS-image layout
        int i = idx - 831488;                // [sel][ocr][kc][row][c8^][j]
        int sel  = i >> 17;                  // 0..2 (131072 per matrix)
        int r1   = i & 131071;
        int ocrb = r1 >> 16;                 // 0..1
        int r2   = r1 & 65535;
        int kcI  = r2 >> 13;                 // 0..7
        int r3   = r2 & 8191;
        int row  = r3 >> 6;                  // 0..127
        int c8   = (r3 >> 3) & 7;
        int j    = r3 & 7;
        const float* Wsrc = (sel == 0) ? Wq : (sel == 1) ? Wm : Wv;
        float w = Wsrc[(size_t)(ocrb * 128 + row) * 512 + kcI * 64 + c8 * 8 + j];
        unsigned short h = f2bf(w);
        int dst = ((sel * 2 + ocrb) * 8 + kcI) * 8192 + row * 64 +
                  ((c8 ^ (row & 7)) << 3) + j;
        Wh[dst] = h;
        Wl[dst] = f2bf(w - bf2f(h));
    }
}

// ---------------- K1: maxpool (1,3,3)/(1,2,2) ----------------
__global__ __launch_bounds__(256) void k_pool(const float* __restrict__ x,
                                              float* __restrict__ xp) {
    int idx = blockIdx.x * 256 + threadIdx.x;
    if (idx >= NPIX) return;
    int w = idx % Wp;
    int h = (idx / Wp) % Hp;
    int bct = idx / HW;
    const float* src = x + (size_t)bct * (H0c * W0c) + (2 * h) * W0c + 2 * w;
    float m = -INFINITY;
    #pragma unroll
    for (int i = 0; i < 3; ++i) {
        m = fmaxf(m, src[i * W0c + 0]);
        m = fmaxf(m, src[i * W0c + 1]);
        m = fmaxf(m, src[i * W0c + 2]);
    }
    xp[idx] = m;
}

// ---------------- K1b: transpose xp -> channel-last bf16 hi/lo split ----------------
// xp [b][512][THW] fp32  ->  Xh/Xl [b][THW][512] bf16 (hi + residual-lo)
__global__ __launch_bounds__(256) void k_xpose(const float* __restrict__ xp,
                                               unsigned short* __restrict__ Xh,
                                               unsigned short* __restrict__ Xl) {
    __shared__ float T[64][65];   // +1 pad: conflict-free column reads
    const int p0 = blockIdx.x * 64;
    const int c0 = blockIdx.y * 64;
    const int b  = blockIdx.z;
    const int tid = threadIdx.x;
    // load 64c x 64px, float4 along px (coalesced)
    {
        int px4 = (tid & 15) * 4;
        int cb = tid >> 4;          // 0..15
        #pragma unroll
        for (int i = 0; i < 4; ++i) {
            int c = cb + i * 16;
            int p = p0 + px4;
            const float* src = xp + ((size_t)(b * Cch + c0 + c)) * THW + p;
            float4 v;
            if (p + 3 < THW) {
                v = *(const float4*)src;
            } else {
                v.x = (p     < THW) ? src[0] : 0.f;
                v.y = (p + 1 < THW) ? src[1] : 0.f;
                v.z = (p + 2 < THW) ? src[2] : 0.f;
                v.w = (p + 3 < THW) ? src[3] : 0.f;
            }
            T[c][px4] = v.x; T[c][px4 + 1] = v.y;
            T[c][px4 + 2] = v.z; T[c][px4 + 3] = v.w;
        }
    }
    __syncthreads();
    {
        int px = tid >> 2;
        int cs = (tid & 3) * 16;
        int p = p0 + px;
        if (p < THW) {
            ushort8 hi[2], lo[2];
            #pragma unroll
            for (int j = 0; j < 16; ++j) {
                float v = T[cs + j][px];
                unsigned short h = f2bf(v);
                hi[j >> 3][j & 7] = h;
                lo[j >> 3][j & 7] = f2bf(v - bf2f(h));
            }
            size_t base = ((size_t)b * THW + p) * 512 + c0 + cs;
            *(ushort8*)&Xh[base]     = hi[0];
            *(ushort8*)&Xh[base + 8] = hi[1];
            *(ushort8*)&Xl[base]     = lo[0];
            *(ushort8*)&Xl[base + 8] = lo[1];
        }
    }
}

// ---------------- K2: Q/M/V projections via split-bf16 MFMA ----------------
// grid (31 px-tiles, 6 oc-tiles, B). BM=128 oc, BN=128 px, K-step 64.
// acc = Whi*Xhi + Whi*Xlo + Wlo*Xhi  (~fp32 accuracy, 3x bf16 MFMA rate)
// W tiles pre-split+pre-swizzled in k_prep_w -> staging = pure async copy.
__global__ __launch_bounds__(256) void k_qmv_mfma(
    const unsigned short* __restrict__ Xh, const unsigned short* __restrict__ Xl,
    const unsigned short* __restrict__ Wh, const unsigned short* __restrict__ Wl,
    unsigned short* __restrict__ Qbf, unsigned short* __restrict__ Mbf,
    float* __restrict__ Vcl, unsigned short* __restrict__ Vbf) {
    __shared__ unsigned short Whs[128 * 64] __attribute__((aligned(16)));
    __shared__ unsigned short Wls[128 * 64] __attribute__((aligned(16)));
    const int p0  = blockIdx.x * 128;
    const int sel = blockIdx.y >> 1;            // 0:Q 1:M 2:V
    const int ocrb = blockIdx.y & 1;
    const int ocr = ocrb * 128;                 // row offset within 256-row matrix
    const int b   = blockIdx.z;
    const int tid = threadIdx.x;
    const int wv = tid >> 6, lane = tid & 63;
    const int l15 = lane & 15, quad = lane >> 4;
    const int tbase = ((sel * 2 + ocrb) * 8) * 8192;

    floatx4 acc[8][2];
    #pragma unroll
    for (int i = 0; i < 8; ++i)
        #pragma unroll
        for (int h = 0; h < 2; ++h) acc[i][h] = (floatx4){0.f, 0.f, 0.f, 0.f};

    for (int kcI = 0; kcI < 8; ++kcI) {
        const int kc = kcI * 64;
        __syncthreads();
        // stage W tile image (16KB hi + 16KB lo) via async copy
        const int toff = tbase + kcI * 8192;
        #pragma unroll
        for (int i = 0; i < 4; ++i) {
            int blk = wv * 4 + i;               // 0..15 x 1KB
            gl_lds16(Wh + toff + blk * 512 + lane * 8, &Whs[blk * 512]);
            gl_lds16(Wl + toff + blk * 512 + lane * 8, &Wls[blk * 512]);
        }
        __syncthreads();
        #pragma unroll
        for (int half = 0; half < 2; ++half) {
            int px = p0 + (wv * 2 + half) * 16 + l15;
            int pxc = min(px, THW - 1);
            const unsigned short* xh = Xh + ((size_t)b * THW + pxc) * 512 + kc;
            const unsigned short* xl = Xl + ((size_t)b * THW + pxc) * 512 + kc;
            #pragma unroll
            for (int ks = 0; ks < 2; ++ks) {
                ushort8 bh = *(const ushort8*)&xh[ks * 32 + quad * 8];
                ushort8 bl = *(const ushort8*)&xl[ks * 32 + quad * 8];
                #pragma unroll
                for (int oct = 0; oct < 8; ++oct) {
                    int row = oct * 16 + l15;
                    int ca = row * 64 + (((ks * 4 + quad) ^ (row & 7)) << 3);
                    ushort8 ah = *(const ushort8*)&Whs[ca];
                    ushort8 al = *(const ushort8*)&Wls[ca];
                    acc[oct][half] = __builtin_amdgcn_mfma_f32_16x16x32_bf16(
                        __builtin_bit_cast(bf16x8, ah),
                        __builtin_bit_cast(bf16x8, bh), acc[oct][half], 0, 0, 0);
                    acc[oct][half] = __builtin_amdgcn_mfma_f32_16x16x32_bf16(
                        __builtin_bit_cast(bf16x8, ah),
                        __builtin_bit_cast(bf16x8, bl), acc[oct][half], 0, 0, 0);
                    acc[oct][half] = __builtin_amdgcn_mfma_f32_16x16x32_bf16(
                        __builtin_bit_cast(bf16x8, al),
                        __builtin_bit_cast(bf16x8, bh), acc[oct][half], 0, 0, 0);
                }
            }
        }
    }
    // epilogue: C row = ocr+oct*16+quad*4+r, col px = p0+(wv*2+half)*16+l15
    if (sel < 2) {
        unsigned short* outbf = sel ? Mbf : Qbf;
        const float scale = sel ? 1.0f : 0.0625f;
        #pragma unroll
        for (int half = 0; half < 2; ++half) {
            int px = p0 + (wv * 2 + half) * 16 + l15;
            if (px < THW) {
                #pragma unroll
                for (int oct = 0; oct < 8; ++oct) {
                    int ch = ocr + oct * 16 + quad * 4;
                    ushort4v v;
                    #pragma unroll
                    for (int r = 0; r < 4; ++r) v[r] = f2bf(acc[oct][half][r] * scale);
                    *(ushort4v*)&outbf[((size_t)b * THW + px) * 256 + ch] = v;
                }
            }
        }
    } else {
        #pragma unroll
        for (int half = 0; half < 2; ++half) {
            int px = p0 + (wv * 2 + half) * 16 + l15;
            if (px < THW) {
                int m = px / HW;
                int key = px - m * HW;
                size_t vbbase = (size_t)(b * 4 + m) * 256;
                #pragma unroll
                for (int oct = 0; oct < 8; ++oct) {
                    int ch = ocr + oct * 16 + quad * 4;
                    float4 fv = make_float4(acc[oct][half][0], acc[oct][half][1],
                                            acc[oct][half][2], acc[oct][half][3]);
                    *(float4*)&Vcl[((size_t)b * THW + px) * 256 + ch] = fv;
                    #pragma unroll
                    for (int r = 0; r < 4; ++r)
                        Vbf[(vbbase + ch + r) * VP + key] = f2bf(acc[oct][half][r]);
                }
            }
        }
    }
}

// ---------------- K3: flash attention, V-from-global + M-dbuf-async ----------
// grid (16, 61). Each wave owns 16 queries (Q in regs). V read straight from
// Vbf (L2-hot); V loads ISSUED AT ITERATION TOP so latency hides under
// QK+softmax. M double-buffered via global_load_lds. Defer-rescale skips the
// O-multiply when running max is stable (al==1 exactly). 2 barriers/iter.
__global__ __launch_bounds__(256, 2) void k_attn_mfma(
    const unsigned short* __restrict__ Qbf, const unsigned short* __restrict__ Mbf,
    const unsigned short* __restrict__ Vbf, unsigned short* __restrict__ Rbf) {
    __shared__ unsigned short Mb[2][16384] __attribute__((aligned(16)));  // 64KB
    __shared__ unsigned short Ps[4096] __attribute__((aligned(16)));      // 8KB
    __shared__ float alpha_s[64];
    __shared__ float l_s[64];

    const int bm = blockIdx.x;
    const int b = bm >> 2, m = bm & 3;
    const int q0 = blockIdx.y * 64;
    const int tid = threadIdx.x;
    const int wv = tid >> 6, lane = tid & 63;
    const int l15 = lane & 15, quad = lane >> 4;
    const int x7 = l15 & 7;

    const size_t mbase = ((size_t)b * THW + m * HW) * 256;
    const size_t vb = (size_t)bm * 256 * VP;

    // Q fragments in registers: this lane is column q = q0 + wv*16 + l15
    const int qg = min(q0 + wv * 16 + l15, THW - 1);
    const unsigned short* qp = Qbf + ((size_t)b * THW + qg) * 256 + quad * 8;
    ushort8 qreg[8];
    #pragma unroll
    for (int kci = 0; kci < 8; ++kci)
        qreg[kci] = *(const ushort8*)&qp[kci * 32];

    // stage M(0) into Mb[0]: content chunk c of row key at slot c^(key&7),
    // via linear LDS dest + inverse-swizzled GLOBAL source (rule 21).
    #pragma unroll
    for (int i = 0; i < 8; ++i) {
        int blk = wv * 8 + i;                  // wave-uniform 1KB block
        int key = blk * 2 + (lane >> 5);
        int cS = (lane & 31) ^ (key & 7);
        gl_lds16(Mbf + mbase + (size_t)key * 256 + (cS << 3), &Mb[0][blk * 512]);
    }

    floatx4 o[4][4];
    #pragma unroll
    for (int mt = 0; mt < 4; ++mt)
        #pragma unroll
        for (int nt = 0; nt < 4; ++nt) o[mt][nt] = (floatx4){0.f, 0.f, 0.f, 0.f};
    float m_run = -1e30f, l_run = 0.f;

    __syncthreads();   // M(0) staged (barrier drains vmcnt)

    int cur = 0;
    for (int kt = 0; kt < 16; ++kt) {
        const int k0 = kt * 64;
        const int nv = min(64, HW - k0);
        // issue M(kt+1) -> Mb[cur^1] (free all iter); flies under QK+softmax
        if (kt < 15) {
            int k0n = k0 + 64;
            #pragma unroll
            for (int i = 0; i < 8; ++i) {
                int blk = wv * 8 + i;
                int key = blk * 2 + (lane >> 5);
                int cS = (lane & 31) ^ (key & 7);
                int kg = min(k0n + key, HW - 1);
                gl_lds16(Mbf + mbase + (size_t)kg * 256 + (cS << 3),
                         &Mb[cur ^ 1][blk * 512]);
            }
        }
        // issue V(kt) loads NOW — consumed in PV after B1, latency fully hidden
        ushort8 bvr[8];
        #pragma unroll
        for (int ks = 0; ks < 2; ++ks)
            #pragma unroll
            for (int nt = 0; nt < 4; ++nt) {
                int ch = wv * 64 + nt * 16 + l15;
                bvr[ks * 4 + nt] = *(const ushort8*)&Vbf[
                    vb + (size_t)ch * VP + k0 + ((((ks << 2) + quad)) << 3)];
            }
        // QK: C[key_local][q], A = M frags from LDS, B = Q regs
        floatx4 sc[4];
        #pragma unroll
        for (int kb = 0; kb < 4; ++kb) sc[kb] = (floatx4){0.f, 0.f, 0.f, 0.f};
        #pragma unroll
        for (int kb = 0; kb < 4; ++kb) {
            const int key = kb * 16 + l15;
            #pragma unroll
            for (int kci = 0; kci < 8; ++kci) {
                ushort8 mf = *(const ushort8*)&Mb[cur][key * 256 +
                    ((((kci << 2) + quad) ^ x7) << 3)];
                sc[kb] = __builtin_amdgcn_mfma_f32_16x16x32_bf16(
                    __builtin_bit_cast(bf16x8, mf),
                    __builtin_bit_cast(bf16x8, qreg[kci]), sc[kb], 0, 0, 0);
            }
        }
        // wave-local softmax for q = l15 (keys spread over kb regs + quad lanes)
        #pragma unroll
        for (int kb = 0; kb < 4; ++kb) {
            #pragma unroll
            for (int r = 0; r < 4; ++r)
                if (kb * 16 + quad * 4 + r >= nv) sc[kb][r] = -1e30f;
        }
        float mx = -1e30f;
        #pragma unroll
        for (int kb = 0; kb < 4; ++kb)
            mx = fmaxf(mx, fmaxf(fmaxf(sc[kb][0], sc[kb][1]),
                                 fmaxf(sc[kb][2], sc[kb][3])));
        mx = fmaxf(mx, __shfl_xor(mx, 16));
        mx = fmaxf(mx, __shfl_xor(mx, 32));
        float m_new = fmaxf(m_run, mx);
        float al = __expf(m_run - m_new);
        float sm = 0.f;
        #pragma unroll
        for (int kb = 0; kb < 4; ++kb) {
            #pragma unroll
            for (int r = 0; r < 4; ++r) {
                float p = __expf(sc[kb][r] - m_new);
                sc[kb][r] = p;
                sm += p;
            }
        }
        sm += __shfl_xor(sm, 16);
        sm += __shfl_xor(sm, 32);
        l_run = l_run * al + sm;
        m_run = m_new;
        if (quad == 0) alpha_s[wv * 16 + l15] = al;
        // write P bf16 -> Ps[q][64keys] swizzled (4 keys packed per write)
        {
            const int prow = wv * 16 + l15;
            #pragma unroll
            for (int kb = 0; kb < 4; ++kb) {
                ushort4v pk;
                #pragma unroll
                for (int r = 0; r < 4; ++r) pk[r] = f2bf(sc[kb][r]);
                int cW = ((kb << 1) + (quad >> 1)) ^ x7;
                *(ushort4v*)&Ps[prow * 64 + (cW << 3) + ((quad & 1) << 2)] = pk;
            }
        }
        __syncthreads();   // B1: Ps+alpha visible; M(kt) reads done; M(kt+1) landed
        // rescale O (skip when running max stable: al == 1.0 exactly)
        #pragma unroll
        for (int mt = 0; mt < 4; ++mt) {
            float alq[4];
            #pragma unroll
            for (int r = 0; r < 4; ++r) alq[r] = alpha_s[mt * 16 + quad * 4 + r];
            if (!__all((alq[0] == 1.f) && (alq[1] == 1.f) &&
                       (alq[2] == 1.f) && (alq[3] == 1.f))) {
                #pragma unroll
                for (int nt = 0; nt < 4; ++nt)
                    #pragma unroll
                    for (int r = 0; r < 4; ++r) o[mt][nt][r] *= alq[r];
            }
        }
        #pragma unroll
        for (int ks = 0; ks < 2; ++ks) {
            ushort8 af[4];
            #pragma unroll
            for (int mt = 0; mt < 4; ++mt)
                af[mt] = *(const ushort8*)&Ps[(mt * 16 + l15) * 64 +
                    ((((ks << 2) + quad) ^ x7) << 3)];
            #pragma unroll
            for (int nt = 0; nt < 4; ++nt) {
                #pragma unroll
                for (int mt = 0; mt < 4; ++mt)
                    o[mt][nt] = __builtin_amdgcn_mfma_f32_16x16x32_bf16(
                        __builtin_bit_cast(bf16x8, af[mt]),
                        __builtin_bit_cast(bf16x8, bvr[ks * 4 + nt]), o[mt][nt],
                        0, 0, 0);
            }
        }
        __syncthreads();   // B2: Ps reads done (next iter overwrites)
        cur ^= 1;
    }
    if (quad == 0) l_s[wv * 16 + l15] = l_run;
    __syncthreads();
    // normalize + stage O (bf16) into Mb[0] as [q_local][256ch]
    #pragma unroll
    for (int mt = 0; mt < 4; ++mt) {
        float invl[4];
        #pragma unroll
        for (int r = 0; r < 4; ++r) invl[r] = 1.f / l_s[mt * 16 + quad * 4 + r];
        #pragma unroll
        for (int nt = 0; nt < 4; ++nt) {
            int ch = wv * 64 + nt * 16 + l15;
            #pragma unroll
            for (int r = 0; r < 4; ++r) {
                int qrow = mt * 16 + quad * 4 + r;
                Mb[0][qrow * 256 + ch] = f2bf(o[mt][nt][r] * invl[r]);
            }
        }
    }
    __syncthreads();
    // coalesced nontemporal store: 8 chunks/thread, 16B/lane
    #pragma unroll
    for (int k = 0; k < 8; ++k) {
        int idx = k * 256 + tid;
        int qrow = idx >> 5, c = idx & 31;
        int q = q0 + qrow;
        if (q < THW) {
            ushort8 v = *(const ushort8*)&Mb[0][qrow * 256 + c * 8];
            __builtin_nontemporal_store(v,
                (ushort8*)&Rbf[((size_t)bm * THW + q) * 256 + c * 8]);
        }
    }
}

// ---------------- K5: compare convs via MFMA (R now bf16) ----------------
__global__ __launch_bounds__(256) void k_cmp(
    const unsigned short* __restrict__ Rbf, const float* __restrict__ Vcl,
    const unsigned short* __restrict__ Wpk, float* __restrict__ Pc) {
    __shared__ unsigned short Ws[24576] __attribute__((aligned(16)));  // 48 KB
    const int strip = blockIdx.x;
    const int s = blockIdx.y;
    const int b = blockIdx.z >> 1, kind = blockIdx.z & 1;
    const int m = s >> 2, tq = s & 3;
    const int tid = threadIdx.x;
    const int wv = tid >> 6, lane = tid & 63;
    const int l15 = lane & 15, quad = lane >> 4;

    const unsigned short* wsrc = Wpk + (kind ? 24576 : 0);
    for (int i = tid; i < 3072; i += 256) {
        int row, ch, stride_us;
        if (kind == 0) { row = i >> 6; ch = i & 63; stride_us = 512; }
        else           { row = i >> 5; ch = i & 31; stride_us = 256; }
        ushort8 v = *(const ushort8*)&wsrc[i * 8];
        *(ushort8*)&Ws[row * stride_us + ((ch ^ (row & 7)) << 3)] = v;
    }
    __syncthreads();

    const size_t rbase = ((size_t)(b * 4 + m) * THW + tq * HW) * 256;
    const size_t vbase = ((size_t)b * THW + m * HW) * 256;

    #pragma unroll
    for (int half = 0; half < 2; ++half) {
        int pxt = wv * 2 + half;
        int hw = strip * 128 + pxt * 16 + l15;
        int hwc = min(hw, HW - 1);
        const unsigned short* rrow = Rbf + rbase + (size_t)hwc * 256;
        const float* vrow = Vcl + vbase + (size_t)hwc * 256;
        bf16x8 fr[8], fs[8];   // kind0: R,V ; kind1: D,P
        #pragma unroll
        for (int ks = 0; ks < 8; ++ks) {
            ushort8 r8 = *(const ushort8*)&rrow[ks * 32 + quad * 8];
            float vv[8];
            *(float4*)&vv[0] = *(const float4*)&vrow[ks * 32 + quad * 8];
            *(float4*)&vv[4] = *(const float4*)&vrow[ks * 32 + quad * 8 + 4];
            bf16x8 a, c;
            if (kind == 0) {
                a = __builtin_bit_cast(bf16x8, r8);
                #pragma unroll
                for (int j = 0; j < 8; ++j) c[j] = (__bf16)vv[j];
            } else {
                #pragma unroll
                for (int j = 0; j < 8; ++j) {
                    float rj = bf2f(r8[j]);
                    a[j] = (__bf16)(rj - vv[j]);
                    c[j] = (__bf16)(rj * vv[j]);
                }
            }
            fr[ks] = a; fs[ks] = c;
        }
        floatx4 acc[6];
        #pragma unroll
        for (int i = 0; i < 6; ++i) acc[i] = (floatx4){0.f, 0.f, 0.f, 0.f};
        if (kind == 0) {
            #pragma unroll
            for (int ks = 0; ks < 16; ++ks) {
                bf16x8 bfr = (ks < 8) ? fr[ks] : fs[ks - 8];
                #pragma unroll
                for (int cit = 0; cit < 3; ++cit) {
                    int row = cit * 16 + l15;
                    ushort8 aw = *(const ushort8*)&Ws[row * 512 + (((ks * 4 + quad) ^ (row & 7)) << 3)];
                    acc[cit] = __builtin_amdgcn_mfma_f32_16x16x32_bf16(
                        __builtin_bit_cast(bf16x8, aw), bfr, acc[cit], 0, 0, 0);
                }
            }
        } else {
            #pragma unroll
            for (int ks = 0; ks < 8; ++ks) {
                #pragma unroll
                for (int cit = 0; cit < 6; ++cit) {
                    int row = cit * 16 + l15;
                    ushort8 aw = *(const ushort8*)&Ws[row * 256 + (((ks * 4 + quad) ^ (row & 7)) << 3)];
                    bf16x8 bfr = (cit < 3) ? fr[ks] : fs[ks];
                    acc[cit] = __builtin_amdgcn_mfma_f32_16x16x32_bf16(
                        __builtin_bit_cast(bf16x8, aw), bfr, acc[cit], 0, 0, 0);
                }
            }
        }
        if (hw < HW) {
            if (kind == 0) {
                #pragma unroll
                for (int cit = 0; cit < 3; ++cit)
                    #pragma unroll
                    for (int r = 0; r < 4; ++r) {
                        int ci = cit * 16 + quad * 4 + r;
                        if (ci < 42)
                            Pc[((size_t)(b * NCMP + ci) * 16 + s) * HW + hw] = acc[cit][r];
                    }
            } else {
                #pragma unroll
                for (int cit = 0; cit < 6; ++cit)
                    #pragma unroll
                    for (int r = 0; r < 4; ++r) {
                        int cl = (cit % 3) * 16 + quad * 4 + r;
                        if (cl < 42) {
                            int ci = (cit < 3 ? 42 : 84) + cl;
                            Pc[((size_t)(b * NCMP + ci) * 16 + s) * HW + hw] = acc[cit][r];
                        }
                    }
            }
        }
    }
}

// ---------------- K6: BN stats for compare ----------------
__global__ __launch_bounds__(256) void k_stats_cmp(
    const float* __restrict__ Pc, const float* __restrict__ g_cat,
    const float* __restrict__ b_cat, const float* __restrict__ g_sub,
    const float* __restrict__ b_sub, const float* __restrict__ g_mul,
    const float* __restrict__ b_mul, float* __restrict__ bnc) {
    const int c = blockIdx.x, tid = threadIdx.x;
    float s = 0.f, q = 0.f;
    for (int i = tid; i < 4 * 16 * HW; i += 256) {
        int bb = i / (16 * HW), r = i - bb * (16 * HW);
        float v = Pc[(size_t)(bb * NCMP + c) * (16 * HW) + r];
        s += v; q += v * v;
    }
    __shared__ float rs[256], rq[256];
    rs[tid] = s; rq[tid] = q;
    __syncthreads();
    for (int off = 128; off > 0; off >>= 1) {
        if (tid < off) { rs[tid] += rs[tid + off]; rq[tid] += rq[tid + off]; }
        __syncthreads();
    }
    if (tid == 0) {
        const float n = 4.f * 16.f * HW;
        float mean = rs[0] / n;
        float var = rq[0] / n - mean * mean;
        float g, bt;
        if (c < 42)       { g = g_cat[c];      bt = b_cat[c]; }
        else if (c < 84)  { g = g_sub[c - 42]; bt = b_sub[c - 42]; }
        else              { g = g_mul[c - 84]; bt = b_mul[c - 84]; }
        float sc = g * rsqrtf(var + BN_EPS);
        bnc[c] = sc;
        bnc[NCMP + c] = bt - mean * sc;
    }
}

// ---------------- K7: build Y channel-last bf16 [b][p][1024] ----------------
__global__ __launch_bounds__(256) void k_build_y(
    const unsigned short* __restrict__ Rbf, const float* __restrict__ Vcl,
    const float* __restrict__ Pc, const float* __restrict__ bnc,
    unsigned short* __restrict__ Ybf) {
    const int strip = blockIdx.x, t = blockIdx.y, b = blockIdx.z;
    const int tid = threadIdx.x;
    const int chl = tid & 31;
    const int hwl = tid >> 5;
    for (int pass = 0; pass < 8; ++pass) {
        int hw = strip * 64 + pass * 8 + hwl;
        if (hw >= HW) continue;
        size_t ybase = ((size_t)b * THW + t * HW + hw) * 1024;
        for (int cb = 0; cb < 8; ++cb) {
            int ch = cb * 128 + chl * 4;
            float v[4];
            if (ch < 256) {
                v[0] = v[1] = v[2] = v[3] = 0.f;
                #pragma unroll
                for (int tq = 0; tq < 4; ++tq) {
                    ushort4v rv = *(const ushort4v*)&Rbf[
                        (((size_t)(b * 4 + t)) * THW + tq * HW + hw) * 256 + ch];
                    v[0] += bf2f(rv[0]); v[1] += bf2f(rv[1]);
                    v[2] += bf2f(rv[2]); v[3] += bf2f(rv[3]);
                }
                v[0] *= 0.25f; v[1] *= 0.25f; v[2] *= 0.25f; v[3] *= 0.25f;
            } else if (ch < 512) {
                float4 vv = *(const float4*)&Vcl[((size_t)b * THW + t * HW + hw) * 256 + (ch - 256)];
                v[0] = vv.x; v[1] = vv.y; v[2] = vv.z; v[3] = vv.w;
            } else if (ch < 1016) {
                int ci = (ch - 512) >> 2;
                float sc = bnc[ci], sh = bnc[NCMP + ci];
                #pragma unroll
                for (int mm = 0; mm < 4; ++mm) {
                    float pv = Pc[(((size_t)(b * NCMP + ci)) * 16 + mm * 4 + t) * HW + hw];
                    v[mm] = fmaxf(fmaf(pv, sc, sh), 0.f);
                }
            } else {
                v[0] = v[1] = v[2] = v[3] = 0.f;
            }
            ushort4v ov;
            #pragma unroll
            for (int i = 0; i < 4; ++i) ov[i] = f2bf(v[i]);
            *(ushort4v*)&Ybf[ybase + ch] = ov;
        }
    }
}

// ---------------- K8: aggregate GEMM via MFMA ----------------
__global__ __launch_bounds__(256) void k_aggm(
    const unsigned short* __restrict__ Wab, const unsigned short* __restrict__ Ybf,
    float* __restrict__ Z) {
    __shared__ unsigned short Wt[16384] __attribute__((aligned(16)));
    const int p0 = blockIdx.x * 128;
    const int oc0 = blockIdx.y * 128;
    const int b = blockIdx.z;
    const int tid = threadIdx.x;
    const int wv = tid >> 6, lane = tid & 63;
    const int l15 = lane & 15, quad = lane >> 4;
    floatx4 acc[8][2];
    #pragma unroll
    for (int i = 0; i < 8; ++i)
        #pragma unroll
        for (int h = 0; h < 2; ++h) acc[i][h] = (floatx4){0.f, 0.f, 0.f, 0.f};
    for (int kc = 0; kc < 8; ++kc) {
        __syncthreads();
        for (int i = tid; i < 2048; i += 256) {
            int row = i >> 4, ch = i & 15;
            ushort8 v = *(const ushort8*)&Wab[(size_t)(oc0 + row) * 1024 + kc * 128 + ch * 8];
            *(ushort8*)&Wt[row * 128 + ((ch ^ (row & 7)) << 3)] = v;
        }
        __syncthreads();
        #pragma unroll
        for (int half = 0; half < 2; ++half) {
            int px = p0 + (wv * 2 + half) * 16 + l15;
            int pxc = min(px, THW - 1);
            const unsigned short* yrow = Ybf + ((size_t)b * THW + pxc) * 1024 + kc * 128;
            #pragma unroll
            for (int ks = 0; ks < 4; ++ks) {
                ushort8 bf = *(const ushort8*)&yrow[ks * 32 + quad * 8];
                #pragma unroll
                for (int oct = 0; oct < 8; ++oct) {
                    int row = oct * 16 + l15;
                    ushort8 af = *(const ushort8*)&Wt[row * 128 + ((((ks * 4 + quad) ^ (row & 7))) << 3)];
                    acc[oct][half] = __builtin_amdgcn_mfma_f32_16x16x32_bf16(
                        __builtin_bit_cast(bf16x8, af),
                        __builtin_bit_cast(bf16x8, bf), acc[oct][half], 0, 0, 0);
                }
            }
        }
    }
    #pragma unroll
    for (int half = 0; half < 2; ++half) {
        int px = p0 + (wv * 2 + half) * 16 + l15;
        if (px < THW) {
            #pragma unroll
            for (int oct = 0; oct < 8; ++oct) {
                int oc = oc0 + oct * 16 + quad * 4;
                #pragma unroll
                for (int r = 0; r < 4; ++r)
                    Z[((size_t)(b * Cch + oc + r)) * THW + px] = acc[oct][half][r];
            }
        }
    }
}

// ---------------- K9: BN stats for aggregate ----------------
__global__ __launch_bounds__(256) void k_stats_agg(
    const float* __restrict__ Z, const float* __restrict__ g_agg,
    const float* __restrict__ b_agg, float* __restrict__ bna) {
    const int c = blockIdx.x, tid = threadIdx.x;
    float s = 0.f, q = 0.f;
    for (int i = tid; i < 4 * THW; i += 256) {
        int bb = i / THW, p = i - bb * THW;
        float v = Z[((size_t)bb * Cch + c) * THW + p];
        s += v; q += v * v;
    }
    __shared__ float rs[256], rq[256];
    rs[tid] = s; rq[tid] = q;
    __syncthreads();
    for (int off = 128; off > 0; off >>= 1) {
        if (tid < off) { rs[tid] += rs[tid + off]; rq[tid] += rq[tid + off]; }
        __syncthreads();
    }
    if (tid == 0) {
        const float n = 4.f * THW;
        float mean = rs[0] / n;
        float var = rq[0] / n - mean * mean;
        float sc = g_agg[c] * rsqrtf(var + BN_EPS);
        bna[c] = sc;
        bna[Cch + c] = b_agg[c] - mean * sc;
    }
}

// ---------------- K10: out = relu(xp + BN(Z)) ----------------
__global__ __launch_bounds__(256) void k_final(const float* __restrict__ xp,
                                               const float* __restrict__ Z,
                                               const float* __restrict__ bna,
                                               float* __restrict__ out) {
    int idx = blockIdx.x * 256 + threadIdx.x;
    if (idx >= NPIX) return;
    int c = (idx / THW) & 511;
    out[idx] = fmaxf(fmaf(Z[idx], bna[c], bna[Cch + c]) + xp[idx], 0.f);
}

extern "C" void kernel_launch(void* const* d_in, const int* in_sizes, int n_in,
                              void* d_out, int out_size, void* d_ws, size_t ws_size,
                              hipStream_t stream) {
    const float* x     = (const float*)d_in[0];
    const float* Wq    = (const float*)d_in[1];
    const float* Wm    = (const float*)d_in[2];
    const float* Wv    = (const float*)d_in[3];
    const float* Wcat  = (const float*)d_in[4];
    const float* Wsub  = (const float*)d_in[5];
    const float* Wmul  = (const float*)d_in[6];
    const float* g_cat = (const float*)d_in[7];
    const float* b_cat = (const float*)d_in[8];
    const float* g_sub = (const float*)d_in[9];
    const float* b_sub = (const float*)d_in[10];
    const float* g_mul = (const float*)d_in[11];
    const float* b_mul = (const float*)d_in[12];
    const float* Wagg  = (const float*)d_in[13];
    const float* g_agg = (const float*)d_in[14];
    const float* b_agg = (const float*)d_in[15];
    float* out = (float*)d_out;
    float* ws  = (float*)d_ws;

    // workspace layout (float offsets); total 35,714,560 fl = 142.9 MB
    float* xp  = ws;                          // 7,872,512
    float* Vcl = xp + 7872512;                // 3,936,256  -> 11,808,768
    float* bnc = Vcl + 3936256;               // 512        -> 11,809,280
    float* bna = bnc + 512;                   // 1024       -> 11,810,304
    unsigned short* Wpk = (unsigned short*)(bna + 1024);   // 49,152 us = 24,576 fl
    unsigned short* Wab = Wpk + 49152;                     // 524,288 us = 262,144 fl
    float* bfreg = (float*)(Wab + 524288);    // 7,872,512 fl -> Qbf/Mbf/Vbf; later Ybf
    unsigned short* Qbf = (unsigned short*)bfreg;          // 3,936,256 us
    unsigned short* Mbf = Qbf + 3936256;                   // 3,936,256 us
    unsigned short* Vbf = Mbf + 3936256;                   // 4,194,304 us
    unsigned short* Ybf = (unsigned short*)bfreg;          // alias (Q/M/V dead)
    unsigned short* Rbf = (unsigned short*)(bfreg + 7872512);  // 15,745,024 us = 7,872,512 fl
    float* Pc = (float*)(Rbf + 15745024);     // 7,750,656 fl (+121,856 pad for Z tail)
    float* Z  = (float*)Rbf;                  // alias: Rbf+Pc dead after build_y
    // Xh/Xl (split-bf16 channel-last xp) alias the Rbf region: live only
    // between k_xpose and k_qmv_mfma; k_attn overwrites Rbf afterwards.
    unsigned short* Xh = Rbf;                 // 7,872,512 us
    unsigned short* Xl = Xh + 7872512;        // 7,872,512 us (fills Rbf region exactly)
    // Wh/Wl (pre-split Q/M/V weights, LDS-image layout) alias the Pc region:
    // live only from k_prep_w until k_qmv_mfma; k_cmp overwrites Pc afterwards.
    unsigned short* Wh = (unsigned short*)Pc;  // 393,216 us
    unsigned short* Wl = Wh + 393216;          // 393,216 us

    k_prep_w<<<dim3(4784), dim3(256), 0, stream>>>(Wq, Wm, Wv, Wcat, Wsub, Wmul,
                                                   Wagg, Wpk, Wab, Vbf, Wh, Wl);
    k_pool<<<dim3((NPIX + 255) / 256), dim3(256), 0, stream>>>(x, xp);
    k_xpose<<<dim3(61, 8, Bb), dim3(256), 0, stream>>>(xp, Xh, Xl);
    k_qmv_mfma<<<dim3(31, 6, Bb), dim3(256), 0, stream>>>(Xh, Xl, Wh, Wl,
                                                          Qbf, Mbf, Vcl, Vbf);
    k_attn_mfma<<<dim3(16, 61), dim3(256), 0, stream>>>(Qbf, Mbf, Vbf, Rbf);
    k_cmp<<<dim3(8, 16, 8), dim3(256), 0, stream>>>(Rbf, Vcl, Wpk, Pc);
    k_stats_cmp<<<dim3(NCMP), dim3(256), 0, stream>>>(Pc, g_cat, b_cat, g_sub, b_sub,
                                                      g_mul, b_mul, bnc);
    k_build_y<<<dim3(16, 4, Bb), dim3(256), 0, stream>>>(Rbf, Vcl, Pc, bnc, Ybf);
    k_aggm<<<dim3(31, 4, Bb), dim3(256), 0, stream>>>(Wab, Ybf, Z);
    k_stats_agg<<<dim3(Cch), dim3(256), 0, stream>>>(Z, g_agg, b_agg, bna);
    k_final<<<dim3((NPIX + 255) / 256), dim3(256), 0, stream>>>(xp, Z, bna, out);
}